// Round 2
// baseline (1653.633 us; speedup 1.0000x reference)
//
#include <hip/hip_runtime.h>
#include <hip/hip_bf16.h>

#define N_NODES 10000
#define N_EDGES 320000
#define E2_EDGES (N_EDGES + N_NODES)
#define DIN 512
#define H 256
#define NHEADS 4
#define DH 64
#define NG 64
#define OUT_DIM 512

typedef __hip_bfloat16 bf16;

// ---------- workspace layout (float offsets) ----------
static const size_t OFF_XRES  = 0;                          // N*H
static const size_t OFF_AGG   = 2560000;                    // N*H (reused as x2acc / x2)
static const size_t OFF_X1    = 5120000;                    // N*H
static const size_t OFF_XL    = 7680000;                    // N*H
static const size_t OFF_XR    = 10240000;                   // N*H
static const size_t OFF_LOGIT = 12800000;                   // E2*4
static const size_t OFF_MX    = 14120000;                   // N*4 (uint-encoded)
static const size_t OFF_DEN   = 14160000;                   // N*4
static const size_t OFF_G1    = 14200000;                   // N
static const size_t OFF_G2    = 14210000;                   // N
static const size_t OFF_W1    = 14220000;                   // N
static const size_t OFF_W2    = 14230000;                   // N
static const size_t OFF_GM1   = 14240000;                   // G (uint-encoded)
static const size_t OFF_GM2   = 14240064;                   // G
static const size_t OFF_GS1   = 14240128;                   // G
static const size_t OFF_GS2   = 14240192;                   // G
static const size_t OFF_CNT   = 14240256;                   // G
static const size_t OFF_FIN   = 14240320;                   // G*768
static const size_t OFF_FLAG  = 14289472;                   // 1 int (dtype flag)

// dual-dtype load: BF=true -> data is bf16; BF=false -> data is fp32
template<bool BF>
__device__ __forceinline__ float LD(const void* p, size_t i) {
    return BF ? __bfloat162float(((const bf16*)p)[i]) : ((const float*)p)[i];
}

__device__ __forceinline__ float gelu_f(float x) {
    return 0.5f * x * (1.0f + erff(x * 0.70710678118654752440f));
}
// order-preserving float<->uint encoding for atomicMax
__device__ __forceinline__ unsigned fenc(float f) {
    unsigned b = __float_as_uint(f);
    return (b & 0x80000000u) ? ~b : (b | 0x80000000u);
}
__device__ __forceinline__ float fdec(unsigned e) {
    unsigned b = (e & 0x80000000u) ? (e & 0x7FFFFFFFu) : ~e;
    return __uint_as_float(b);
}

__device__ __forceinline__ float blk_sum(float v, float* s) {
#pragma unroll
    for (int o = 32; o > 0; o >>= 1) v += __shfl_xor(v, o, 64);
    int lane = threadIdx.x & 63, w = threadIdx.x >> 6;
    __syncthreads();
    if (lane == 0) s[w] = v;
    __syncthreads();
    float t = 0.f;
    int nw = blockDim.x >> 6;
    for (int i = 0; i < nw; i++) t += s[i];
    return t;
}

// K0: detect input dtype. bf16 N(0,1) low-halves have exponent field ~[110,140];
// fp32 low-halves are uniform mantissa bits (~12% in range). Writes 1 if bf16.
__global__ void k_detect(const void* xv, int* flag) {
    const unsigned* w = (const unsigned*)xv;
    int lane = threadIdx.x;
    int good = 0;
    for (int i = lane; i < 2048; i += 64) {
        int e = (int)((w[i] >> 7) & 0xFF);
        if (e >= 110 && e <= 140) good++;
    }
#pragma unroll
    for (int o = 32; o > 0; o >>= 1) good += __shfl_xor(good, o, 64);
    if (lane == 0) *flag = (good > 1024) ? 1 : 0;
}

// K1: per node: LN(512) -> GEMV(512x256) -> GELU -> LN(256) -> x_res
template<bool BF>
__device__ __forceinline__ void input_body(const void* x, const void* g0, const void* b0,
                                           const void* Wp, const void* bp, const void* lg,
                                           const void* lb, float* xres, float* xn,
                                           float* red) {
    int n = blockIdx.x, tid = threadIdx.x;
    float v0 = LD<BF>(x, (size_t)n * DIN + tid);
    float v1 = LD<BF>(x, (size_t)n * DIN + 256 + tid);
    float m = blk_sum(v0 + v1, red) * (1.0f / DIN);
    float d0 = v0 - m, d1 = v1 - m;
    float var = blk_sum(d0 * d0 + d1 * d1, red) * (1.0f / DIN);
    float inv = rsqrtf(var + 1e-5f);
    xn[tid]       = d0 * inv * LD<BF>(g0, tid) + LD<BF>(b0, tid);
    xn[tid + 256] = d1 * inv * LD<BF>(g0, tid + 256) + LD<BF>(b0, tid + 256);
    __syncthreads();
    float acc = LD<BF>(bp, tid);
#pragma unroll 8
    for (int k = 0; k < DIN; k++) acc += xn[k] * LD<BF>(Wp, (size_t)k * H + tid);
    float p = gelu_f(acc);
    float sm = blk_sum(p, red) * (1.0f / H);
    float dd = p - sm;
    float vv = blk_sum(dd * dd, red) * (1.0f / H);
    inv = rsqrtf(vv + 1e-5f);
    xres[(size_t)n * H + tid] = dd * inv * LD<BF>(lg, tid) + LD<BF>(lb, tid);
}
__global__ void k_input(const int* __restrict__ flag, const void* x, const void* g0,
                        const void* b0, const void* Wp, const void* bp, const void* lg,
                        const void* lb, float* __restrict__ xres) {
    __shared__ float xn[DIN];
    __shared__ float red[8];
    if (*flag) input_body<true>(x, g0, b0, Wp, bp, lg, lb, xres, xn, red);
    else       input_body<false>(x, g0, b0, Wp, bp, lg, lb, xres, xn, red);
}

// K2: GraphConv scatter-add: agg[dst] += x_res[src], one wave per edge
__global__ void k_agg(const int* __restrict__ src, const int* __restrict__ dst,
                      const float* __restrict__ xres, float* __restrict__ agg) {
    int e = blockIdx.x * 4 + (threadIdx.x >> 6);
    if (e >= N_EDGES) return;
    int lane = threadIdx.x & 63;
    int s = src[e], d = dst[e];
#pragma unroll
    for (int i = 0; i < 4; i++) {
        int c = lane + i * 64;
        atomicAdd(&agg[(size_t)d * H + c], xres[(size_t)s * H + c]);
    }
}

// K3: x1 = LN(gelu(agg@Wrel + brel + x_res@Wroot)) + x_res
template<bool BF>
__device__ __forceinline__ void conv_body(const float* agg, const float* xres,
                                          const void* Wrel, const void* brel,
                                          const void* Wroot, const void* n1g,
                                          const void* n1b, float* x1, float* ar,
                                          float* xr_, float* red) {
    int n = blockIdx.x, tid = threadIdx.x;
    ar[tid]  = agg[(size_t)n * H + tid];
    xr_[tid] = xres[(size_t)n * H + tid];
    __syncthreads();
    float acc = LD<BF>(brel, tid);
#pragma unroll 8
    for (int k = 0; k < H; k++)
        acc += ar[k] * LD<BF>(Wrel, (size_t)k * H + tid) + xr_[k] * LD<BF>(Wroot, (size_t)k * H + tid);
    float p = gelu_f(acc);
    float sm = blk_sum(p, red) * (1.0f / H);
    float dd = p - sm;
    float vv = blk_sum(dd * dd, red) * (1.0f / H);
    float inv = rsqrtf(vv + 1e-5f);
    x1[(size_t)n * H + tid] = dd * inv * LD<BF>(n1g, tid) + LD<BF>(n1b, tid) + xr_[tid];
}
__global__ void k_conv(const int* __restrict__ flag, const float* __restrict__ agg,
                       const float* __restrict__ xres, const void* Wrel, const void* brel,
                       const void* Wroot, const void* n1g, const void* n1b,
                       float* __restrict__ x1) {
    __shared__ float ar[H];
    __shared__ float xr_[H];
    __shared__ float red[8];
    if (*flag) conv_body<true>(agg, xres, Wrel, brel, Wroot, n1g, n1b, x1, ar, xr_, red);
    else       conv_body<false>(agg, xres, Wrel, brel, Wroot, n1g, n1b, x1, ar, xr_, red);
}

// K4: xl = x1@Wl + bl ; xr = x1@Wr + br
template<bool BF>
__device__ __forceinline__ void lr_body(const float* x1, const void* Wl, const void* bl,
                                        const void* Wr, const void* br, float* xl,
                                        float* xr, float* xs) {
    int n = blockIdx.x, tid = threadIdx.x;
    xs[tid] = x1[(size_t)n * H + tid];
    __syncthreads();
    float aL = LD<BF>(bl, tid);
    float aR = LD<BF>(br, tid);
#pragma unroll 8
    for (int k = 0; k < H; k++) {
        float v = xs[k];
        aL += v * LD<BF>(Wl, (size_t)k * H + tid);
        aR += v * LD<BF>(Wr, (size_t)k * H + tid);
    }
    xl[(size_t)n * H + tid] = aL;
    xr[(size_t)n * H + tid] = aR;
}
__global__ void k_lr(const int* __restrict__ flag, const float* __restrict__ x1,
                     const void* Wl, const void* bl, const void* Wr, const void* br,
                     float* __restrict__ xl, float* __restrict__ xr) {
    __shared__ float xs[H];
    if (*flag) lr_body<true>(x1, Wl, bl, Wr, br, xl, xr, xs);
    else       lr_body<false>(x1, Wl, bl, Wr, br, xl, xr, xs);
}

// K5: per-edge GATv2 logits + segment max (self-loops appended)
template<bool BF>
__device__ __forceinline__ void logit_body(const int* src, const int* dst,
                                           const float* xl, const float* xr,
                                           const void* att, float* logit,
                                           unsigned* mxenc) {
    int e = blockIdx.x * 4 + (threadIdx.x >> 6);
    if (e >= E2_EDGES) return;
    int lane = threadIdx.x & 63;
    int s, d;
    if (e < N_EDGES) { s = src[e]; d = dst[e]; } else { s = d = e - N_EDGES; }
    float l[NHEADS];
#pragma unroll
    for (int h = 0; h < NHEADS; h++) {
        float a = xl[(size_t)s * H + h * DH + lane] + xr[(size_t)d * H + h * DH + lane];
        a = (a > 0.f) ? a : 0.2f * a;  // leaky relu 0.2
        l[h] = a * LD<BF>(att, h * DH + lane);
    }
#pragma unroll
    for (int o = 32; o > 0; o >>= 1) {
#pragma unroll
        for (int h = 0; h < NHEADS; h++) l[h] += __shfl_xor(l[h], o, 64);
    }
    if (lane < NHEADS) {
        logit[(size_t)e * NHEADS + lane] = l[lane];
        atomicMax(&mxenc[d * NHEADS + lane], fenc(l[lane]));
    }
}
__global__ void k_logit(const int* __restrict__ flag, const int* __restrict__ src,
                        const int* __restrict__ dst, const float* __restrict__ xl,
                        const float* __restrict__ xr, const void* att,
                        float* __restrict__ logit, unsigned* __restrict__ mxenc) {
    if (*flag) logit_body<true>(src, dst, xl, xr, att, logit, mxenc);
    else       logit_body<false>(src, dst, xl, xr, att, logit, mxenc);
}

// K6: a = exp(logit - max); den += a; x2acc[d] += a * xl[s]
__global__ void k_accum(const int* __restrict__ src, const int* __restrict__ dst,
                        const float* __restrict__ xl, const float* __restrict__ logit,
                        const unsigned* __restrict__ mxenc, float* __restrict__ den,
                        float* __restrict__ x2acc) {
    int e = blockIdx.x * 4 + (threadIdx.x >> 6);
    if (e >= E2_EDGES) return;
    int lane = threadIdx.x & 63;
    int s, d;
    if (e < N_EDGES) { s = src[e]; d = dst[e]; } else { s = d = e - N_EDGES; }
    float a[NHEADS];
#pragma unroll
    for (int h = 0; h < NHEADS; h++)
        a[h] = expf(logit[(size_t)e * NHEADS + h] - fdec(mxenc[d * NHEADS + h]));
    if (lane < NHEADS) atomicAdd(&den[d * NHEADS + lane], a[lane]);
#pragma unroll
    for (int h = 0; h < NHEADS; h++)
        atomicAdd(&x2acc[(size_t)d * H + h * DH + lane],
                  a[h] * xl[(size_t)s * H + h * DH + lane]);
}

// K7: x2 = LN(gelu(x2acc/den + gat_b)) + x1   (in place over x2acc)
template<bool BF>
__device__ __forceinline__ void x2_body(float* x2, const float* den, const void* gatb,
                                        const void* n2g, const void* n2b,
                                        const float* x1, float* red) {
    int n = blockIdx.x, tid = threadIdx.x;
    float dn = den[n * NHEADS + (tid >> 6)];
    float v = x2[(size_t)n * H + tid] / dn + LD<BF>(gatb, tid);
    float p = gelu_f(v);
    float sm = blk_sum(p, red) * (1.0f / H);
    float dd = p - sm;
    float vv = blk_sum(dd * dd, red) * (1.0f / H);
    float inv = rsqrtf(vv + 1e-5f);
    x2[(size_t)n * H + tid] = dd * inv * LD<BF>(n2g, tid) + LD<BF>(n2b, tid) + x1[(size_t)n * H + tid];
}
__global__ void k_x2(const int* __restrict__ flag, float* __restrict__ x2,
                     const float* __restrict__ den, const void* gatb, const void* n2g,
                     const void* n2b, const float* __restrict__ x1) {
    __shared__ float red[8];
    if (*flag) x2_body<true>(x2, den, gatb, n2g, n2b, x1, red);
    else       x2_body<false>(x2, den, gatb, n2g, n2b, x1, red);
}

// K8a: gate1 = tanh(x2@Wg1a+b)@Wg1b+b ; gate2 = tanh(x2@Wg2a+b)@Wg2b+b
template<bool BF>
__device__ __forceinline__ void gate_body(const float* x2, const void* Wg1a,
                                          const void* bg1a, const void* Wg1b,
                                          const void* bg1b, const void* Wg2a,
                                          const void* bg2a, const void* Wg2b,
                                          const void* bg2b, float* gate1, float* gate2,
                                          float* xs, float* red) {
    int n = blockIdx.x, tid = threadIdx.x;
    xs[tid] = x2[(size_t)n * H + tid];
    __syncthreads();
    float a2 = LD<BF>(bg2a, tid);
#pragma unroll 8
    for (int k = 0; k < H; k++) a2 += xs[k] * LD<BF>(Wg2a, (size_t)k * H + tid);
    float p2 = tanhf(a2) * LD<BF>(Wg2b, tid);
    float g2 = blk_sum(p2, red) + LD<BF>(bg2b, 0);
    float p1 = 0.f;
    if (tid < 128) {
        float a1 = LD<BF>(bg1a, tid);
#pragma unroll 8
        for (int k = 0; k < H; k++) a1 += xs[k] * LD<BF>(Wg1a, (size_t)k * 128 + tid);
        p1 = tanhf(a1) * LD<BF>(Wg1b, tid);
    }
    float g1 = blk_sum(p1, red) + LD<BF>(bg1b, 0);
    if (tid == 0) { gate1[n] = g1; gate2[n] = g2; }
}
__global__ void k_gate(const int* __restrict__ flag, const float* __restrict__ x2,
                       const void* Wg1a, const void* bg1a, const void* Wg1b,
                       const void* bg1b, const void* Wg2a, const void* bg2a,
                       const void* Wg2b, const void* bg2b, float* __restrict__ gate1,
                       float* __restrict__ gate2) {
    __shared__ float xs[H];
    __shared__ float red[8];
    if (*flag) gate_body<true>(x2, Wg1a, bg1a, Wg1b, bg1b, Wg2a, bg2a, Wg2b, bg2b,
                               gate1, gate2, xs, red);
    else       gate_body<false>(x2, Wg1a, bg1a, Wg1b, bg1b, Wg2a, bg2a, Wg2b, bg2b,
                               gate1, gate2, xs, red);
}

// K8b: per-group gate max
__global__ void k_gmax(const int* __restrict__ batch, const float* __restrict__ g1,
                       const float* __restrict__ g2, unsigned* __restrict__ m1,
                       unsigned* __restrict__ m2) {
    int i = blockIdx.x * blockDim.x + threadIdx.x;
    if (i >= N_NODES) return;
    int b = batch[i];
    atomicMax(&m1[b], fenc(g1[i]));
    atomicMax(&m2[b], fenc(g2[i]));
}

// K8c: softmax numerators + denominators + counts
__global__ void k_gw(const int* __restrict__ batch, const float* __restrict__ g1,
                     const float* __restrict__ g2, const unsigned* __restrict__ m1,
                     const unsigned* __restrict__ m2, float* __restrict__ w1,
                     float* __restrict__ w2, float* __restrict__ gs1,
                     float* __restrict__ gs2, float* __restrict__ cnt) {
    int i = blockIdx.x * blockDim.x + threadIdx.x;
    if (i >= N_NODES) return;
    int b = batch[i];
    float a1 = expf(g1[i] - fdec(m1[b]));
    float a2 = expf(g2[i] - fdec(m2[b]));
    w1[i] = a1; w2[i] = a2;
    atomicAdd(&gs1[b], a1);
    atomicAdd(&gs2[b], a2);
    atomicAdd(&cnt[b], 1.0f);
}

// K8d: pooled accumulation into fin = [emb1acc | emb2acc | gresacc] per group
__global__ void k_pool(const int* __restrict__ batch, const float* __restrict__ x2,
                       const float* __restrict__ xres, const float* __restrict__ w1,
                       const float* __restrict__ w2, float* __restrict__ fin) {
    int n = blockIdx.x, tid = threadIdx.x;
    int b = batch[n];
    float xv = x2[(size_t)n * H + tid];
    float rv = xres[(size_t)n * H + tid];
    float a1 = w1[n], a2 = w2[n];
    atomicAdd(&fin[(size_t)b * 768 + tid], a1 * xv);
    atomicAdd(&fin[(size_t)b * 768 + 256 + tid], a2 * xv);
    atomicAdd(&fin[(size_t)b * 768 + 512 + tid], rv);
}

// K9: out = gelu(fin @ Wo + bo) / sqrt(1+1e-5) * bn_g + bn_b
template<bool BF>
__device__ __forceinline__ void final_body(const float* finacc, const float* gs1,
                                           const float* gs2, const float* cnt,
                                           const void* Wo, const void* bo,
                                           const void* bng, const void* bnb, void* out,
                                           float* fl) {
    int g = blockIdx.x, tid = threadIdx.x;
    float s1 = gs1[g], s2 = gs2[g], c = fmaxf(cnt[g], 1.0f);
    fl[tid]       = (s1 > 0.f) ? finacc[(size_t)g * 768 + tid] / s1 : 0.f;
    fl[256 + tid] = (s2 > 0.f) ? finacc[(size_t)g * 768 + 256 + tid] / s2 : 0.f;
    fl[512 + tid] = finacc[(size_t)g * 768 + 512 + tid] / c;
    __syncthreads();
#pragma unroll
    for (int half = 0; half < 2; half++) {
        int o = tid + half * 256;
        float acc = LD<BF>(bo, o);
#pragma unroll 8
        for (int k = 0; k < 768; k++) acc += fl[k] * LD<BF>(Wo, (size_t)k * OUT_DIM + o);
        float val = gelu_f(acc);
        float r = val * 0.9999950000374997f * LD<BF>(bng, o) + LD<BF>(bnb, o);
        if (BF) ((bf16*)out)[(size_t)g * OUT_DIM + o] = __float2bfloat16(r);
        else    ((float*)out)[(size_t)g * OUT_DIM + o] = r;
    }
}
__global__ void k_final(const int* __restrict__ flag, const float* __restrict__ finacc,
                        const float* __restrict__ gs1, const float* __restrict__ gs2,
                        const float* __restrict__ cnt, const void* Wo, const void* bo,
                        const void* bng, const void* bnb, void* out) {
    __shared__ float fl[768];
    if (*flag) final_body<true>(finacc, gs1, gs2, cnt, Wo, bo, bng, bnb, out, fl);
    else       final_body<false>(finacc, gs1, gs2, cnt, Wo, bo, bng, bnb, out, fl);
}

extern "C" void kernel_launch(void* const* d_in, const int* in_sizes, int n_in,
                              void* d_out, int out_size, void* d_ws, size_t ws_size,
                              hipStream_t stream) {
    const void* x       = d_in[0];
    const int*  ei      = (const int*)d_in[1];
    const int*  batch   = (const int*)d_in[2];
    const void* ln_in_g = d_in[3];
    const void* ln_in_b = d_in[4];
    const void* Wp      = d_in[5];
    const void* bp      = d_in[6];
    const void* lnp_g   = d_in[7];
    const void* lnp_b   = d_in[8];
    const void* Wrel    = d_in[9];
    const void* brel    = d_in[10];
    const void* Wroot   = d_in[11];
    const void* n1_g    = d_in[12];
    const void* n1_b    = d_in[13];
    const void* Wl      = d_in[14];
    const void* bl      = d_in[15];
    const void* Wr      = d_in[16];
    const void* br      = d_in[17];
    const void* att     = d_in[18];
    const void* gat_b   = d_in[19];
    const void* n2_g    = d_in[20];
    const void* n2_b    = d_in[21];
    const void* Wg1a    = d_in[22];
    const void* bg1a    = d_in[23];
    const void* Wg1b    = d_in[24];
    const void* bg1b    = d_in[25];
    const void* Wg2a    = d_in[26];
    const void* bg2a    = d_in[27];
    const void* Wg2b    = d_in[28];
    const void* bg2b    = d_in[29];
    const void* Wo      = d_in[30];
    const void* bo      = d_in[31];
    const void* bn_g    = d_in[32];
    const void* bn_b    = d_in[33];

    float* ws = (float*)d_ws;
    const int* src = ei;
    const int* dst = ei + N_EDGES;
    int* flag = (int*)(ws + OFF_FLAG);

    // zero accumulators (ws is poisoned 0xAA before every launch)
    hipMemsetAsync(ws + OFF_AGG, 0, (size_t)N_NODES * H * sizeof(float), stream);
    hipMemsetAsync(ws + OFF_MX, 0, (size_t)N_NODES * NHEADS * 2 * sizeof(float), stream); // mx + den
    hipMemsetAsync(ws + OFF_GM1, 0, (5 * 64 + (size_t)NG * 768) * sizeof(float), stream);

    k_detect<<<1, 64, 0, stream>>>(x, flag);
    k_input<<<N_NODES, 256, 0, stream>>>(flag, x, ln_in_g, ln_in_b, Wp, bp, lnp_g,
                                         lnp_b, ws + OFF_XRES);
    k_agg<<<(N_EDGES + 3) / 4, 256, 0, stream>>>(src, dst, ws + OFF_XRES, ws + OFF_AGG);
    k_conv<<<N_NODES, 256, 0, stream>>>(flag, ws + OFF_AGG, ws + OFF_XRES, Wrel, brel,
                                        Wroot, n1_g, n1_b, ws + OFF_X1);
    k_lr<<<N_NODES, 256, 0, stream>>>(flag, ws + OFF_X1, Wl, bl, Wr, br, ws + OFF_XL,
                                      ws + OFF_XR);
    k_logit<<<(E2_EDGES + 3) / 4, 256, 0, stream>>>(flag, src, dst, ws + OFF_XL,
                                                    ws + OFF_XR, att, ws + OFF_LOGIT,
                                                    (unsigned*)(ws + OFF_MX));
    // re-zero x2 accumulator (reuses agg buffer, agg no longer needed)
    hipMemsetAsync(ws + OFF_AGG, 0, (size_t)N_NODES * H * sizeof(float), stream);
    k_accum<<<(E2_EDGES + 3) / 4, 256, 0, stream>>>(src, dst, ws + OFF_XL, ws + OFF_LOGIT,
                                                    (const unsigned*)(ws + OFF_MX),
                                                    ws + OFF_DEN, ws + OFF_AGG);
    k_x2<<<N_NODES, 256, 0, stream>>>(flag, ws + OFF_AGG, ws + OFF_DEN, gat_b, n2_g,
                                      n2_b, ws + OFF_X1);
    k_gate<<<N_NODES, 256, 0, stream>>>(flag, ws + OFF_AGG, Wg1a, bg1a, Wg1b, bg1b,
                                        Wg2a, bg2a, Wg2b, bg2b, ws + OFF_G1, ws + OFF_G2);
    k_gmax<<<(N_NODES + 255) / 256, 256, 0, stream>>>(batch, ws + OFF_G1, ws + OFF_G2,
                                                      (unsigned*)(ws + OFF_GM1),
                                                      (unsigned*)(ws + OFF_GM2));
    k_gw<<<(N_NODES + 255) / 256, 256, 0, stream>>>(batch, ws + OFF_G1, ws + OFF_G2,
                                                    (const unsigned*)(ws + OFF_GM1),
                                                    (const unsigned*)(ws + OFF_GM2),
                                                    ws + OFF_W1, ws + OFF_W2,
                                                    ws + OFF_GS1, ws + OFF_GS2,
                                                    ws + OFF_CNT);
    k_pool<<<N_NODES, 256, 0, stream>>>(batch, ws + OFF_AGG, ws + OFF_XRES, ws + OFF_W1,
                                        ws + OFF_W2, ws + OFF_FIN);
    k_final<<<NG, 256, 0, stream>>>(flag, ws + OFF_FIN, ws + OFF_GS1, ws + OFF_GS2,
                                    ws + OFF_CNT, Wo, bo, bn_g, bn_b, d_out);
}

// Round 3
// 1071.257 us; speedup vs baseline: 1.5436x; 1.5436x over previous
//
#include <hip/hip_runtime.h>
#include <hip/hip_bf16.h>

#define N_NODES 10000
#define N_EDGES 320000
#define DIN 512
#define H 256
#define NHEADS 4
#define DH 64
#define NG 64
#define OUT_DIM 512

typedef __hip_bfloat16 bf16;

// ---------- workspace layout (float offsets) ----------
static const size_t OFF_XRES = 0;           // N*H
static const size_t OFF_X1   = 2560000;     // N*H
static const size_t OFF_XL   = 5120000;     // N*H
static const size_t OFF_XR   = 7680000;     // N*H
static const size_t OFF_X2   = 10240000;    // N*H (msg, then x2 in place)
static const size_t OFF_G1   = 12800000;    // N
static const size_t OFF_G2   = 12810000;    // N
static const size_t OFF_FIN  = 12820000;    // G*768 (normalized)
static const size_t OFF_FLAG = 12869152;    // 1 int
// int region (index in int units into (int*)ws)
static const size_t IOFF_CUR = 12870000;    // N ints (deg, then cursor)
static const size_t IOFF_ROW = 12880000;    // N+1 ints
static const size_t IOFF_COL = 12890016;    // E ints

// dual-dtype load: BF=true -> data is bf16; BF=false -> data is fp32
template<bool BF>
__device__ __forceinline__ float LD(const void* p, size_t i) {
    return BF ? __bfloat162float(((const bf16*)p)[i]) : ((const float*)p)[i];
}

__device__ __forceinline__ float gelu_f(float x) {
    return 0.5f * x * (1.0f + erff(x * 0.70710678118654752440f));
}

__device__ __forceinline__ float blk_sum(float v, float* s) {
#pragma unroll
    for (int o = 32; o > 0; o >>= 1) v += __shfl_xor(v, o, 64);
    int lane = threadIdx.x & 63, w = threadIdx.x >> 6;
    __syncthreads();
    if (lane == 0) s[w] = v;
    __syncthreads();
    float t = 0.f;
    int nw = blockDim.x >> 6;
    for (int i = 0; i < nw; i++) t += s[i];
    return t;
}

__device__ __forceinline__ float blk_max(float v, float* s) {
#pragma unroll
    for (int o = 32; o > 0; o >>= 1) v = fmaxf(v, __shfl_xor(v, o, 64));
    int lane = threadIdx.x & 63, w = threadIdx.x >> 6;
    __syncthreads();
    if (lane == 0) s[w] = v;
    __syncthreads();
    float t = s[0];
    int nw = blockDim.x >> 6;
    for (int i = 1; i < nw; i++) t = fmaxf(t, s[i]);
    return t;
}

__device__ __forceinline__ int lowerb(const int* b, int n, int v) {
    int lo = 0, hi = n;
    while (lo < hi) { int mid = (lo + hi) >> 1; if (b[mid] < v) lo = mid + 1; else hi = mid; }
    return lo;
}

// K0: detect input dtype (bf16 vs fp32) from bit patterns of x
__global__ void k_detect(const void* xv, int* flag) {
    const unsigned* w = (const unsigned*)xv;
    int lane = threadIdx.x;
    int good = 0;
    for (int i = lane; i < 2048; i += 64) {
        int e = (int)((w[i] >> 7) & 0xFF);
        if (e >= 110 && e <= 140) good++;
    }
#pragma unroll
    for (int o = 32; o > 0; o >>= 1) good += __shfl_xor(good, o, 64);
    if (lane == 0) *flag = (good > 1024) ? 1 : 0;
}

// ---------- CSR build (by dst) ----------
__global__ void k_count(const int* __restrict__ dst, int* __restrict__ deg) {
    int e = blockIdx.x * blockDim.x + threadIdx.x;
    if (e < N_EDGES) atomicAdd(&deg[dst[e]], 1);
}

// single block, 1024 threads, chunk of 10 each: exclusive prefix -> row_ptr
__global__ void k_scan(const int* __restrict__ deg, int* __restrict__ row) {
    __shared__ int part[1024];
    int t = threadIdx.x;
    int base = t * 10;
    int v[10];
    int s = 0;
#pragma unroll
    for (int i = 0; i < 10; i++) {
        int idx = base + i;
        v[i] = (idx < N_NODES) ? deg[idx] : 0;
        s += v[i];
    }
    part[t] = s;
    __syncthreads();
    for (int off = 1; off < 1024; off <<= 1) {
        int x = (t >= off) ? part[t - off] : 0;
        __syncthreads();
        part[t] += x;
        __syncthreads();
    }
    int run = (t == 0) ? 0 : part[t - 1];
#pragma unroll
    for (int i = 0; i < 10; i++) {
        int idx = base + i;
        if (idx < N_NODES) row[idx] = run;
        run += v[i];
    }
    if (t == 1023) row[N_NODES] = part[1023];
}

__global__ void k_fill(const int* __restrict__ src, const int* __restrict__ dst,
                       const int* __restrict__ row, int* __restrict__ cur,
                       int* __restrict__ col) {
    int e = blockIdx.x * blockDim.x + threadIdx.x;
    if (e >= N_EDGES) return;
    int d = dst[e];
    int pos = atomicAdd(&cur[d], 1);
    col[row[d] + pos] = src[e];
}

// K1: per node: LN(512) -> GEMV(512x256) -> GELU -> LN(256) -> x_res
template<bool BF>
__device__ __forceinline__ void input_body(const void* x, const void* g0, const void* b0,
                                           const void* Wp, const void* bp, const void* lg,
                                           const void* lb, float* xres, float* xn,
                                           float* red) {
    int n = blockIdx.x, tid = threadIdx.x;
    float v0 = LD<BF>(x, (size_t)n * DIN + tid);
    float v1 = LD<BF>(x, (size_t)n * DIN + 256 + tid);
    float m = blk_sum(v0 + v1, red) * (1.0f / DIN);
    float d0 = v0 - m, d1 = v1 - m;
    float var = blk_sum(d0 * d0 + d1 * d1, red) * (1.0f / DIN);
    float inv = rsqrtf(var + 1e-5f);
    xn[tid]       = d0 * inv * LD<BF>(g0, tid) + LD<BF>(b0, tid);
    xn[tid + 256] = d1 * inv * LD<BF>(g0, tid + 256) + LD<BF>(b0, tid + 256);
    __syncthreads();
    float acc = LD<BF>(bp, tid);
#pragma unroll 8
    for (int k = 0; k < DIN; k++) acc += xn[k] * LD<BF>(Wp, (size_t)k * H + tid);
    float p = gelu_f(acc);
    float sm = blk_sum(p, red) * (1.0f / H);
    float dd = p - sm;
    float vv = blk_sum(dd * dd, red) * (1.0f / H);
    inv = rsqrtf(vv + 1e-5f);
    xres[(size_t)n * H + tid] = dd * inv * LD<BF>(lg, tid) + LD<BF>(lb, tid);
}
__global__ void k_input(const int* __restrict__ flag, const void* x, const void* g0,
                        const void* b0, const void* Wp, const void* bp, const void* lg,
                        const void* lb, float* __restrict__ xres) {
    __shared__ float xn[DIN];
    __shared__ float red[8];
    if (*flag) input_body<true>(x, g0, b0, Wp, bp, lg, lb, xres, xn, red);
    else       input_body<false>(x, g0, b0, Wp, bp, lg, lb, xres, xn, red);
}

// K3: gather agg + x1 = LN(gelu(agg@Wrel + brel + x_res@Wroot)) + x_res
template<bool BF>
__device__ __forceinline__ void conv_body(const int* row, const int* col,
                                          const float* xres, const void* Wrel,
                                          const void* brel, const void* Wroot,
                                          const void* n1g, const void* n1b, float* x1,
                                          float* ar, float* xr_, float* red) {
    int n = blockIdx.x, tid = threadIdx.x;
    int start = row[n], end = row[n + 1];
    float a = 0.f;
    for (int i = start; i < end; i++) {
        int s = col[i];
        a += xres[(size_t)s * H + tid];
    }
    ar[tid]  = a;
    xr_[tid] = xres[(size_t)n * H + tid];
    __syncthreads();
    float acc = LD<BF>(brel, tid);
#pragma unroll 8
    for (int k = 0; k < H; k++)
        acc += ar[k] * LD<BF>(Wrel, (size_t)k * H + tid) + xr_[k] * LD<BF>(Wroot, (size_t)k * H + tid);
    float p = gelu_f(acc);
    float sm = blk_sum(p, red) * (1.0f / H);
    float dd = p - sm;
    float vv = blk_sum(dd * dd, red) * (1.0f / H);
    float inv = rsqrtf(vv + 1e-5f);
    x1[(size_t)n * H + tid] = dd * inv * LD<BF>(n1g, tid) + LD<BF>(n1b, tid) + xr_[tid];
}
__global__ void k_conv(const int* __restrict__ flag, const int* __restrict__ row,
                       const int* __restrict__ col, const float* __restrict__ xres,
                       const void* Wrel, const void* brel, const void* Wroot,
                       const void* n1g, const void* n1b, float* __restrict__ x1) {
    __shared__ float ar[H];
    __shared__ float xr_[H];
    __shared__ float red[8];
    if (*flag) conv_body<true>(row, col, xres, Wrel, brel, Wroot, n1g, n1b, x1, ar, xr_, red);
    else       conv_body<false>(row, col, xres, Wrel, brel, Wroot, n1g, n1b, x1, ar, xr_, red);
}

// K4: xl = x1@Wl + bl ; xr = x1@Wr + br
template<bool BF>
__device__ __forceinline__ void lr_body(const float* x1, const void* Wl, const void* bl,
                                        const void* Wr, const void* br, float* xl,
                                        float* xr, float* xs) {
    int n = blockIdx.x, tid = threadIdx.x;
    xs[tid] = x1[(size_t)n * H + tid];
    __syncthreads();
    float aL = LD<BF>(bl, tid);
    float aR = LD<BF>(br, tid);
#pragma unroll 8
    for (int k = 0; k < H; k++) {
        float v = xs[k];
        aL += v * LD<BF>(Wl, (size_t)k * H + tid);
        aR += v * LD<BF>(Wr, (size_t)k * H + tid);
    }
    xl[(size_t)n * H + tid] = aL;
    xr[(size_t)n * H + tid] = aR;
}
__global__ void k_lr(const int* __restrict__ flag, const float* __restrict__ x1,
                     const void* Wl, const void* bl, const void* Wr, const void* br,
                     float* __restrict__ xl, float* __restrict__ xr) {
    __shared__ float xs[H];
    if (*flag) lr_body<true>(x1, Wl, bl, Wr, br, xl, xr, xs);
    else       lr_body<false>(x1, Wl, bl, Wr, br, xl, xr, xs);
}

// K5: fused GATv2 per destination node — online softmax over incoming edges.
// One wave per node (4 nodes per 256-thread block). Self-loop initializes state.
template<bool BF>
__device__ __forceinline__ void gat_body(const int* row, const int* col, const float* xl,
                                         const float* xr, const void* att, float* msg) {
    int n = blockIdx.x * 4 + (threadIdx.x >> 6);
    if (n >= N_NODES) return;
    int lane = threadIdx.x & 63;
    float attv[NHEADS], xrd[NHEADS], m[NHEADS], l[NHEADS], acc[NHEADS], v[NHEADS], lg[NHEADS];
#pragma unroll
    for (int h = 0; h < NHEADS; h++) {
        attv[h] = LD<BF>(att, h * DH + lane);
        xrd[h]  = xr[(size_t)n * H + h * DH + lane];
        v[h]    = xl[(size_t)n * H + h * DH + lane];
        float a = v[h] + xrd[h];
        a = (a > 0.f) ? a : 0.2f * a;
        lg[h] = a * attv[h];
    }
#pragma unroll
    for (int o = 32; o > 0; o >>= 1) {
#pragma unroll
        for (int h = 0; h < NHEADS; h++) lg[h] += __shfl_xor(lg[h], o, 64);
    }
#pragma unroll
    for (int h = 0; h < NHEADS; h++) { m[h] = lg[h]; l[h] = 1.f; acc[h] = v[h]; }
    int start = row[n], end = row[n + 1];
    for (int i = start; i < end; i++) {
        int s = col[i];
#pragma unroll
        for (int h = 0; h < NHEADS; h++) {
            v[h] = xl[(size_t)s * H + h * DH + lane];
            float a = v[h] + xrd[h];
            a = (a > 0.f) ? a : 0.2f * a;
            lg[h] = a * attv[h];
        }
#pragma unroll
        for (int o = 32; o > 0; o >>= 1) {
#pragma unroll
            for (int h = 0; h < NHEADS; h++) lg[h] += __shfl_xor(lg[h], o, 64);
        }
#pragma unroll
        for (int h = 0; h < NHEADS; h++) {
            float nm = fmaxf(m[h], lg[h]);
            float sc = __expf(m[h] - nm);
            float p  = __expf(lg[h] - nm);
            l[h]   = l[h] * sc + p;
            acc[h] = acc[h] * sc + p * v[h];
            m[h]   = nm;
        }
    }
#pragma unroll
    for (int h = 0; h < NHEADS; h++)
        msg[(size_t)n * H + h * DH + lane] = acc[h] / l[h];
}
__global__ void k_gat(const int* __restrict__ flag, const int* __restrict__ row,
                      const int* __restrict__ col, const float* __restrict__ xl,
                      const float* __restrict__ xr, const void* att,
                      float* __restrict__ msg) {
    if (*flag) gat_body<true>(row, col, xl, xr, att, msg);
    else       gat_body<false>(row, col, xl, xr, att, msg);
}

// K7: x2 = LN(gelu(msg + gat_b)) + x1   (in place over msg)
template<bool BF>
__device__ __forceinline__ void x2_body(float* x2, const void* gatb, const void* n2g,
                                        const void* n2b, const float* x1, float* red) {
    int n = blockIdx.x, tid = threadIdx.x;
    float v = x2[(size_t)n * H + tid] + LD<BF>(gatb, tid);
    float p = gelu_f(v);
    float sm = blk_sum(p, red) * (1.0f / H);
    float dd = p - sm;
    float vv = blk_sum(dd * dd, red) * (1.0f / H);
    float inv = rsqrtf(vv + 1e-5f);
    x2[(size_t)n * H + tid] = dd * inv * LD<BF>(n2g, tid) + LD<BF>(n2b, tid) + x1[(size_t)n * H + tid];
}
__global__ void k_x2(const int* __restrict__ flag, float* __restrict__ x2,
                     const void* gatb, const void* n2g, const void* n2b,
                     const float* __restrict__ x1) {
    __shared__ float red[8];
    if (*flag) x2_body<true>(x2, gatb, n2g, n2b, x1, red);
    else       x2_body<false>(x2, gatb, n2g, n2b, x1, red);
}

// K8a: gate1 = tanh(x2@Wg1a+b)@Wg1b+b ; gate2 = tanh(x2@Wg2a+b)@Wg2b+b
template<bool BF>
__device__ __forceinline__ void gate_body(const float* x2, const void* Wg1a,
                                          const void* bg1a, const void* Wg1b,
                                          const void* bg1b, const void* Wg2a,
                                          const void* bg2a, const void* Wg2b,
                                          const void* bg2b, float* gate1, float* gate2,
                                          float* xs, float* red) {
    int n = blockIdx.x, tid = threadIdx.x;
    xs[tid] = x2[(size_t)n * H + tid];
    __syncthreads();
    float a2 = LD<BF>(bg2a, tid);
#pragma unroll 8
    for (int k = 0; k < H; k++) a2 += xs[k] * LD<BF>(Wg2a, (size_t)k * H + tid);
    float p2 = tanhf(a2) * LD<BF>(Wg2b, tid);
    float g2 = blk_sum(p2, red) + LD<BF>(bg2b, 0);
    float p1 = 0.f;
    if (tid < 128) {
        float a1 = LD<BF>(bg1a, tid);
#pragma unroll 8
        for (int k = 0; k < H; k++) a1 += xs[k] * LD<BF>(Wg1a, (size_t)k * 128 + tid);
        p1 = tanhf(a1) * LD<BF>(Wg1b, tid);
    }
    float g1 = blk_sum(p1, red) + LD<BF>(bg1b, 0);
    if (tid == 0) { gate1[n] = g1; gate2[n] = g2; }
}
__global__ void k_gate(const int* __restrict__ flag, const float* __restrict__ x2,
                       const void* Wg1a, const void* bg1a, const void* Wg1b,
                       const void* bg1b, const void* Wg2a, const void* bg2a,
                       const void* Wg2b, const void* bg2b, float* __restrict__ gate1,
                       float* __restrict__ gate2) {
    __shared__ float xs[H];
    __shared__ float red[8];
    if (*flag) gate_body<true>(x2, Wg1a, bg1a, Wg1b, bg1b, Wg2a, bg2a, Wg2b, bg2b,
                               gate1, gate2, xs, red);
    else       gate_body<false>(x2, Wg1a, bg1a, Wg1b, bg1b, Wg2a, bg2a, Wg2b, bg2b,
                               gate1, gate2, xs, red);
}

// K8: per-group pooling (batch is sorted -> contiguous ranges). One block per group.
// Writes normalized fin = [emb1 | emb2 | gres].
__global__ void k_group(const int* __restrict__ batch, const float* __restrict__ x2,
                        const float* __restrict__ xres, const float* __restrict__ g1,
                        const float* __restrict__ g2, float* __restrict__ fin) {
    __shared__ float red[8];
    __shared__ int seb[2];
    int g = blockIdx.x, tid = threadIdx.x;
    if (tid == 0) {
        seb[0] = lowerb(batch, N_NODES, g);
        seb[1] = lowerb(batch, N_NODES, g + 1);
    }
    __syncthreads();
    int start = seb[0], end = seb[1];
    if (end <= start) {
        fin[(size_t)g * 768 + tid] = 0.f;
        fin[(size_t)g * 768 + 256 + tid] = 0.f;
        fin[(size_t)g * 768 + 512 + tid] = 0.f;
        return;
    }
    float m1 = -3.4e38f, m2 = -3.4e38f;
    for (int i = start + tid; i < end; i += 256) {
        m1 = fmaxf(m1, g1[i]);
        m2 = fmaxf(m2, g2[i]);
    }
    m1 = blk_max(m1, red);
    m2 = blk_max(m2, red);
    float s1 = 0.f, s2 = 0.f, e1 = 0.f, e2 = 0.f, gr = 0.f;
    for (int i = start; i < end; i++) {
        float w1 = __expf(g1[i] - m1);
        float w2 = __expf(g2[i] - m2);
        float xv = x2[(size_t)i * H + tid];
        float rv = xres[(size_t)i * H + tid];
        s1 += w1; s2 += w2;
        e1 += w1 * xv; e2 += w2 * xv; gr += rv;
    }
    float c = (float)(end - start);
    fin[(size_t)g * 768 + tid]       = e1 / s1;
    fin[(size_t)g * 768 + 256 + tid] = e2 / s2;
    fin[(size_t)g * 768 + 512 + tid] = gr / c;
}

// K9: out = gelu(fin @ Wo + bo) / sqrt(1+1e-5) * bn_g + bn_b
template<bool BF>
__device__ __forceinline__ void final_body(const float* fin, const void* Wo,
                                           const void* bo, const void* bng,
                                           const void* bnb, void* out, float* fl) {
    int g = blockIdx.x, tid = threadIdx.x;
    fl[tid]       = fin[(size_t)g * 768 + tid];
    fl[256 + tid] = fin[(size_t)g * 768 + 256 + tid];
    fl[512 + tid] = fin[(size_t)g * 768 + 512 + tid];
    __syncthreads();
#pragma unroll
    for (int half = 0; half < 2; half++) {
        int o = tid + half * 256;
        float acc = LD<BF>(bo, o);
#pragma unroll 8
        for (int k = 0; k < 768; k++) acc += fl[k] * LD<BF>(Wo, (size_t)k * OUT_DIM + o);
        float val = gelu_f(acc);
        float r = val * 0.9999950000374997f * LD<BF>(bng, o) + LD<BF>(bnb, o);
        if (BF) ((bf16*)out)[(size_t)g * OUT_DIM + o] = __float2bfloat16(r);
        else    ((float*)out)[(size_t)g * OUT_DIM + o] = r;
    }
}
__global__ void k_final(const int* __restrict__ flag, const float* __restrict__ fin,
                        const void* Wo, const void* bo, const void* bng,
                        const void* bnb, void* out) {
    __shared__ float fl[768];
    if (*flag) final_body<true>(fin, Wo, bo, bng, bnb, out, fl);
    else       final_body<false>(fin, Wo, bo, bng, bnb, out, fl);
}

extern "C" void kernel_launch(void* const* d_in, const int* in_sizes, int n_in,
                              void* d_out, int out_size, void* d_ws, size_t ws_size,
                              hipStream_t stream) {
    const void* x       = d_in[0];
    const int*  ei      = (const int*)d_in[1];
    const int*  batch   = (const int*)d_in[2];
    const void* ln_in_g = d_in[3];
    const void* ln_in_b = d_in[4];
    const void* Wp      = d_in[5];
    const void* bp      = d_in[6];
    const void* lnp_g   = d_in[7];
    const void* lnp_b   = d_in[8];
    const void* Wrel    = d_in[9];
    const void* brel    = d_in[10];
    const void* Wroot   = d_in[11];
    const void* n1_g    = d_in[12];
    const void* n1_b    = d_in[13];
    const void* Wl      = d_in[14];
    const void* bl      = d_in[15];
    const void* Wr      = d_in[16];
    const void* br      = d_in[17];
    const void* att     = d_in[18];
    const void* gat_b   = d_in[19];
    const void* n2_g    = d_in[20];
    const void* n2_b    = d_in[21];
    const void* Wg1a    = d_in[22];
    const void* bg1a    = d_in[23];
    const void* Wg1b    = d_in[24];
    const void* bg1b    = d_in[25];
    const void* Wg2a    = d_in[26];
    const void* bg2a    = d_in[27];
    const void* Wg2b    = d_in[28];
    const void* bg2b    = d_in[29];
    const void* Wo      = d_in[30];
    const void* bo      = d_in[31];
    const void* bn_g    = d_in[32];
    const void* bn_b    = d_in[33];

    float* ws = (float*)d_ws;
    int* wsi = (int*)d_ws;
    const int* src = ei;
    const int* dst = ei + N_EDGES;
    int* flag = (int*)(ws + OFF_FLAG);
    int* cur  = wsi + IOFF_CUR;
    int* row  = wsi + IOFF_ROW;
    int* col  = wsi + IOFF_COL;

    // ---- CSR build (deg -> scan -> fill) ----
    hipMemsetAsync(cur, 0, N_NODES * sizeof(int), stream);
    k_count<<<(N_EDGES + 255) / 256, 256, 0, stream>>>(dst, cur);
    k_scan<<<1, 1024, 0, stream>>>(cur, row);
    hipMemsetAsync(cur, 0, N_NODES * sizeof(int), stream);
    k_fill<<<(N_EDGES + 255) / 256, 256, 0, stream>>>(src, dst, row, cur, col);

    k_detect<<<1, 64, 0, stream>>>(x, flag);
    k_input<<<N_NODES, 256, 0, stream>>>(flag, x, ln_in_g, ln_in_b, Wp, bp, lnp_g,
                                         lnp_b, ws + OFF_XRES);
    k_conv<<<N_NODES, 256, 0, stream>>>(flag, row, col, ws + OFF_XRES, Wrel, brel,
                                        Wroot, n1_g, n1_b, ws + OFF_X1);
    k_lr<<<N_NODES, 256, 0, stream>>>(flag, ws + OFF_X1, Wl, bl, Wr, br, ws + OFF_XL,
                                      ws + OFF_XR);
    k_gat<<<(N_NODES + 3) / 4, 256, 0, stream>>>(flag, row, col, ws + OFF_XL,
                                                 ws + OFF_XR, att, ws + OFF_X2);
    k_x2<<<N_NODES, 256, 0, stream>>>(flag, ws + OFF_X2, gat_b, n2_g, n2_b,
                                      ws + OFF_X1);
    k_gate<<<N_NODES, 256, 0, stream>>>(flag, ws + OFF_X2, Wg1a, bg1a, Wg1b, bg1b,
                                        Wg2a, bg2a, Wg2b, bg2b, ws + OFF_G1, ws + OFF_G2);
    k_group<<<NG, 256, 0, stream>>>(batch, ws + OFF_X2, ws + OFF_XRES, ws + OFF_G1,
                                    ws + OFF_G2, ws + OFF_FIN);
    k_final<<<NG, 256, 0, stream>>>(flag, ws + OFF_FIN, Wo, bo, bn_g, bn_b, d_out);
}

// Round 4
// 837.865 us; speedup vs baseline: 1.9736x; 1.2786x over previous
//
#include <hip/hip_runtime.h>
#include <hip/hip_bf16.h>

#define N_NODES 10000
#define N_EDGES 320000
#define DIN 512
#define H 256
#define NHEADS 4
#define DH 64
#define NG 64
#define OUT_DIM 512

// ---------- workspace layout (float offsets) ----------
static const size_t OFF_XRES = 0;           // N*H
static const size_t OFF_AGG  = 2560000;     // N*H  (agg, later reused as msg/x2)
static const size_t OFF_X1   = 5120000;     // N*H
static const size_t OFF_XL   = 7680000;     // N*H
static const size_t OFF_XR   = 10240000;    // N*H
static const size_t OFF_MEAN = 12800000;    // N
static const size_t OFF_INVS = 12810000;    // N
static const size_t OFF_G1   = 12820000;    // N
static const size_t OFF_G2   = 12830000;    // N
static const size_t OFF_FIN  = 12840000;    // G*768
// int region (int offsets into (int*)ws)
static const size_t IOFF_CUR = 12900000;    // N ints
static const size_t IOFF_ROW = 12910016;    // N+1 ints
static const size_t IOFF_COL = 12920032;    // E ints

__device__ __forceinline__ float gelu_f(float x) {
    return 0.5f * x * (1.0f + erff(x * 0.70710678118654752440f));
}

__device__ __forceinline__ float wsum64(float v) {
#pragma unroll
    for (int o = 32; o > 0; o >>= 1) v += __shfl_xor(v, o, 64);
    return v;
}

__device__ __forceinline__ float blk_sum(float v, float* s) {
#pragma unroll
    for (int o = 32; o > 0; o >>= 1) v += __shfl_xor(v, o, 64);
    int lane = threadIdx.x & 63, w = threadIdx.x >> 6;
    __syncthreads();
    if (lane == 0) s[w] = v;
    __syncthreads();
    float t = 0.f;
    int nw = blockDim.x >> 6;
    for (int i = 0; i < nw; i++) t += s[i];
    return t;
}

__device__ __forceinline__ float blk_max(float v, float* s) {
#pragma unroll
    for (int o = 32; o > 0; o >>= 1) v = fmaxf(v, __shfl_xor(v, o, 64));
    int lane = threadIdx.x & 63, w = threadIdx.x >> 6;
    __syncthreads();
    if (lane == 0) s[w] = v;
    __syncthreads();
    float t = s[0];
    int nw = blockDim.x >> 6;
    for (int i = 1; i < nw; i++) t = fmaxf(t, s[i]);
    return t;
}

__device__ __forceinline__ int lowerb(const int* b, int n, int v) {
    int lo = 0, hi = n;
    while (lo < hi) { int mid = (lo + hi) >> 1; if (b[mid] < v) lo = mid + 1; else hi = mid; }
    return lo;
}

// ---------- CSR build (by dst) ----------
__global__ void k_count(const int* __restrict__ dst, int* __restrict__ deg) {
    int e = blockIdx.x * blockDim.x + threadIdx.x;
    if (e < N_EDGES) atomicAdd(&deg[dst[e]], 1);
}

__global__ void k_scan(const int* __restrict__ deg, int* __restrict__ row) {
    __shared__ int part[1024];
    int t = threadIdx.x;
    int base = t * 10;
    int v[10];
    int s = 0;
#pragma unroll
    for (int i = 0; i < 10; i++) {
        int idx = base + i;
        v[i] = (idx < N_NODES) ? deg[idx] : 0;
        s += v[i];
    }
    part[t] = s;
    __syncthreads();
    for (int off = 1; off < 1024; off <<= 1) {
        int x = (t >= off) ? part[t - off] : 0;
        __syncthreads();
        part[t] += x;
        __syncthreads();
    }
    int run = (t == 0) ? 0 : part[t - 1];
#pragma unroll
    for (int i = 0; i < 10; i++) {
        int idx = base + i;
        if (idx < N_NODES) row[idx] = run;
        run += v[i];
    }
    if (t == 1023) row[N_NODES] = part[1023];
}

__global__ void k_fill(const int* __restrict__ src, const int* __restrict__ dst,
                       const int* __restrict__ row, int* __restrict__ cur,
                       int* __restrict__ col) {
    int e = blockIdx.x * blockDim.x + threadIdx.x;
    if (e >= N_EDGES) return;
    int d = dst[e];
    int pos = atomicAdd(&cur[d], 1);
    col[row[d] + pos] = src[e];
}

// ---------- GEMM building blocks ----------
// Tile: 32 nodes x 256 (or 128) cols, K chunked by 32.
// Thread map: lane (tid&63) owns cols {lane, lane+64, lane+128, lane+192};
//             wave (tid>>6) owns nodes {wave*8 .. wave*8+7}.
// LDS: A chunk [32][36] (pad 4 -> conflict-free), W chunk [32][256].

__device__ __forceinline__ void stageW256(const float* __restrict__ W, int k0,
                                          float* __restrict__ ws_) {
    int t = threadIdx.x;
    const float4* Wg = (const float4*)(W + (size_t)k0 * 256);
    float4* wl = (float4*)ws_;
#pragma unroll
    for (int i = 0; i < 8; i++) wl[t + i * 256] = Wg[t + i * 256];
}

__device__ __forceinline__ void stageW128(const float* __restrict__ W, int k0,
                                          float* __restrict__ ws_) {
    int t = threadIdx.x;
    const float4* Wg = (const float4*)(W + (size_t)k0 * 128);
    float4* wl = (float4*)ws_;
#pragma unroll
    for (int i = 0; i < 4; i++) wl[t + i * 256] = Wg[t + i * 256];
}

__device__ __forceinline__ void stageA(const float* __restrict__ A, int nb, int k0,
                                       int kstride, float* __restrict__ as_) {
    int t = threadIdx.x;
    int r = t >> 3, q = t & 7;
    int n = nb + r;
    float4 v = make_float4(0.f, 0.f, 0.f, 0.f);
    if (n < N_NODES) v = *(const float4*)(A + (size_t)n * kstride + k0 + q * 4);
    *(float4*)(as_ + r * 36 + q * 4) = v;
}

// stage A chunk for k_proj: apply input LN on the fly from raw x
__device__ __forceinline__ void stageA_ln(const float* __restrict__ x,
                                          const float* __restrict__ mean,
                                          const float* __restrict__ invs,
                                          const float* __restrict__ g0,
                                          const float* __restrict__ b0, int nb, int k0,
                                          float* __restrict__ as_) {
    int t = threadIdx.x;
    int r = t >> 3, q = t & 7;
    int n = nb + r;
    float4 v = make_float4(0.f, 0.f, 0.f, 0.f);
    if (n < N_NODES) {
        float4 xv = *(const float4*)(x + (size_t)n * DIN + k0 + q * 4);
        float4 gv = *(const float4*)(g0 + k0 + q * 4);
        float4 bv = *(const float4*)(b0 + k0 + q * 4);
        float m = mean[n], is = invs[n];
        v.x = (xv.x - m) * is * gv.x + bv.x;
        v.y = (xv.y - m) * is * gv.y + bv.y;
        v.z = (xv.z - m) * is * gv.z + bv.z;
        v.w = (xv.w - m) * is * gv.w + bv.w;
    }
    *(float4*)(as_ + r * 36 + q * 4) = v;
}

__device__ __forceinline__ void mm256(const float* __restrict__ as_,
                                      const float* __restrict__ ws_,
                                      float (&acc)[8][4]) {
    int lane = threadIdx.x & 63, tn = threadIdx.x >> 6;
#pragma unroll
    for (int kk = 0; kk < 32; kk += 4) {
        float xq[8][4];
#pragma unroll
        for (int i = 0; i < 8; i++) {
            float4 v = *(const float4*)(as_ + (tn * 8 + i) * 36 + kk);
            xq[i][0] = v.x; xq[i][1] = v.y; xq[i][2] = v.z; xq[i][3] = v.w;
        }
#pragma unroll
        for (int t = 0; t < 4; t++) {
            const float* wr = ws_ + (kk + t) * 256 + lane;
            float w0 = wr[0], w1 = wr[64], w2 = wr[128], w3 = wr[192];
#pragma unroll
            for (int i = 0; i < 8; i++) {
                float a = xq[i][t];
                acc[i][0] += a * w0; acc[i][1] += a * w1;
                acc[i][2] += a * w2; acc[i][3] += a * w3;
            }
        }
    }
}

__device__ __forceinline__ void mm128(const float* __restrict__ as_,
                                      const float* __restrict__ ws_,
                                      float (&acc)[8][2]) {
    int lane = threadIdx.x & 63, tn = threadIdx.x >> 6;
#pragma unroll
    for (int kk = 0; kk < 32; kk += 4) {
        float xq[8][4];
#pragma unroll
        for (int i = 0; i < 8; i++) {
            float4 v = *(const float4*)(as_ + (tn * 8 + i) * 36 + kk);
            xq[i][0] = v.x; xq[i][1] = v.y; xq[i][2] = v.z; xq[i][3] = v.w;
        }
#pragma unroll
        for (int t = 0; t < 4; t++) {
            const float* wr = ws_ + (kk + t) * 128 + lane;
            float w0 = wr[0], w1 = wr[64];
#pragma unroll
            for (int i = 0; i < 8; i++) {
                float a = xq[i][t];
                acc[i][0] += a * w0; acc[i][1] += a * w1;
            }
        }
    }
}

// ---------- kernels ----------

// per-node mean / inv-std of x[n][0:512]
__global__ void k_lnstat(const float* __restrict__ x, float* __restrict__ mean,
                         float* __restrict__ invs) {
    __shared__ float red[8];
    int n = blockIdx.x, tid = threadIdx.x;
    float v0 = x[(size_t)n * DIN + tid];
    float v1 = x[(size_t)n * DIN + 256 + tid];
    float m = blk_sum(v0 + v1, red) * (1.0f / DIN);
    float d0 = v0 - m, d1 = v1 - m;
    float var = blk_sum(d0 * d0 + d1 * d1, red) * (1.0f / DIN);
    if (tid == 0) { mean[n] = m; invs[n] = rsqrtf(var + 1e-5f); }
}

// x_res = LN(gelu(LN_in(x) @ Wp + bp))
__global__ __launch_bounds__(256, 4) void k_proj(
        const float* __restrict__ x, const float* __restrict__ mean,
        const float* __restrict__ invs, const float* __restrict__ g0,
        const float* __restrict__ b0, const float* __restrict__ Wp,
        const float* __restrict__ bp, const float* __restrict__ lg,
        const float* __restrict__ lb, float* __restrict__ xres) {
    __shared__ float as_[32 * 36];
    __shared__ float ws_[32 * 256];
    int nb = blockIdx.x * 32;
    float acc[8][4] = {};
    for (int k0 = 0; k0 < DIN; k0 += 32) {
        stageA_ln(x, mean, invs, g0, b0, nb, k0, as_);
        stageW256(Wp, k0, ws_);
        __syncthreads();
        mm256(as_, ws_, acc);
        __syncthreads();
    }
    int lane = threadIdx.x & 63, tn = threadIdx.x >> 6;
    float bp4[4], lg4[4], lb4[4];
#pragma unroll
    for (int j = 0; j < 4; j++) {
        bp4[j] = bp[lane + j * 64];
        lg4[j] = lg[lane + j * 64];
        lb4[j] = lb[lane + j * 64];
    }
#pragma unroll
    for (int i = 0; i < 8; i++) {
        float v[4];
#pragma unroll
        for (int j = 0; j < 4; j++) v[j] = gelu_f(acc[i][j] + bp4[j]);
        float m = wsum64(v[0] + v[1] + v[2] + v[3]) * (1.0f / H);
        float d[4], q = 0.f;
#pragma unroll
        for (int j = 0; j < 4; j++) { d[j] = v[j] - m; q += d[j] * d[j]; }
        float inv = rsqrtf(wsum64(q) * (1.0f / H) + 1e-5f);
        int n = nb + tn * 8 + i;
        if (n < N_NODES) {
#pragma unroll
            for (int j = 0; j < 4; j++)
                xres[(size_t)n * H + lane + j * 64] = d[j] * inv * lg4[j] + lb4[j];
        }
    }
}

// agg[n] = sum_{s in nbrs(n)} xres[s]
__global__ void k_gather(const int* __restrict__ row, const int* __restrict__ col,
                         const float* __restrict__ xres, float* __restrict__ agg) {
    int n = blockIdx.x, tid = threadIdx.x;
    int s0 = row[n], e0 = row[n + 1];
    float a = 0.f;
    for (int i = s0; i < e0; i++) a += xres[(size_t)col[i] * H + tid];
    agg[(size_t)n * H + tid] = a;
}

// x1 = LN(gelu(agg@Wrel + brel + xres@Wroot)) + xres
__global__ __launch_bounds__(256, 4) void k_conv(
        const float* __restrict__ agg, const float* __restrict__ xres,
        const float* __restrict__ Wrel, const float* __restrict__ brel,
        const float* __restrict__ Wroot, const float* __restrict__ n1g,
        const float* __restrict__ n1b, float* __restrict__ x1) {
    __shared__ float as_[32 * 36];
    __shared__ float ws_[32 * 256];
    int nb = blockIdx.x * 32;
    float acc[8][4] = {};
    for (int k0 = 0; k0 < H; k0 += 32) {
        stageA(agg, nb, k0, H, as_);
        stageW256(Wrel, k0, ws_);
        __syncthreads();
        mm256(as_, ws_, acc);
        __syncthreads();
    }
    for (int k0 = 0; k0 < H; k0 += 32) {
        stageA(xres, nb, k0, H, as_);
        stageW256(Wroot, k0, ws_);
        __syncthreads();
        mm256(as_, ws_, acc);
        __syncthreads();
    }
    int lane = threadIdx.x & 63, tn = threadIdx.x >> 6;
    float bb[4], gg[4], nb4[4];
#pragma unroll
    for (int j = 0; j < 4; j++) {
        bb[j] = brel[lane + j * 64];
        gg[j] = n1g[lane + j * 64];
        nb4[j] = n1b[lane + j * 64];
    }
#pragma unroll
    for (int i = 0; i < 8; i++) {
        float v[4];
#pragma unroll
        for (int j = 0; j < 4; j++) v[j] = gelu_f(acc[i][j] + bb[j]);
        float m = wsum64(v[0] + v[1] + v[2] + v[3]) * (1.0f / H);
        float d[4], q = 0.f;
#pragma unroll
        for (int j = 0; j < 4; j++) { d[j] = v[j] - m; q += d[j] * d[j]; }
        float inv = rsqrtf(wsum64(q) * (1.0f / H) + 1e-5f);
        int n = nb + tn * 8 + i;
        if (n < N_NODES) {
#pragma unroll
            for (int j = 0; j < 4; j++) {
                size_t idx = (size_t)n * H + lane + j * 64;
                x1[idx] = d[j] * inv * gg[j] + nb4[j] + xres[idx];
            }
        }
    }
}

// out = A @ W + b  (A [N,256], W [256,256])
__global__ __launch_bounds__(256, 4) void k_lin(
        const float* __restrict__ A, const float* __restrict__ W,
        const float* __restrict__ b, float* __restrict__ out) {
    __shared__ float as_[32 * 36];
    __shared__ float ws_[32 * 256];
    int nb = blockIdx.x * 32;
    float acc[8][4] = {};
    for (int k0 = 0; k0 < H; k0 += 32) {
        stageA(A, nb, k0, H, as_);
        stageW256(W, k0, ws_);
        __syncthreads();
        mm256(as_, ws_, acc);
        __syncthreads();
    }
    int lane = threadIdx.x & 63, tn = threadIdx.x >> 6;
    float b4[4];
#pragma unroll
    for (int j = 0; j < 4; j++) b4[j] = b[lane + j * 64];
#pragma unroll
    for (int i = 0; i < 8; i++) {
        int n = nb + tn * 8 + i;
        if (n < N_NODES) {
#pragma unroll
            for (int j = 0; j < 4; j++)
                out[(size_t)n * H + lane + j * 64] = acc[i][j] + b4[j];
        }
    }
}

// fused GATv2 per destination node — online softmax over incoming edges
__global__ void k_gat(const int* __restrict__ row, const int* __restrict__ col,
                      const float* __restrict__ xl, const float* __restrict__ xr,
                      const float* __restrict__ att, float* __restrict__ msg) {
    int n = blockIdx.x * 4 + (threadIdx.x >> 6);
    if (n >= N_NODES) return;
    int lane = threadIdx.x & 63;
    float attv[NHEADS], xrd[NHEADS], m[NHEADS], l[NHEADS], acc[NHEADS], v[NHEADS], lg[NHEADS];
#pragma unroll
    for (int h = 0; h < NHEADS; h++) {
        attv[h] = att[h * DH + lane];
        xrd[h]  = xr[(size_t)n * H + h * DH + lane];
        v[h]    = xl[(size_t)n * H + h * DH + lane];
        float a = v[h] + xrd[h];
        a = (a > 0.f) ? a : 0.2f * a;
        lg[h] = a * attv[h];
    }
#pragma unroll
    for (int o = 32; o > 0; o >>= 1) {
#pragma unroll
        for (int h = 0; h < NHEADS; h++) lg[h] += __shfl_xor(lg[h], o, 64);
    }
#pragma unroll
    for (int h = 0; h < NHEADS; h++) { m[h] = lg[h]; l[h] = 1.f; acc[h] = v[h]; }
    int start = row[n], end = row[n + 1];
    for (int i = start; i < end; i++) {
        int s = col[i];
#pragma unroll
        for (int h = 0; h < NHEADS; h++) {
            v[h] = xl[(size_t)s * H + h * DH + lane];
            float a = v[h] + xrd[h];
            a = (a > 0.f) ? a : 0.2f * a;
            lg[h] = a * attv[h];
        }
#pragma unroll
        for (int o = 32; o > 0; o >>= 1) {
#pragma unroll
            for (int h = 0; h < NHEADS; h++) lg[h] += __shfl_xor(lg[h], o, 64);
        }
#pragma unroll
        for (int h = 0; h < NHEADS; h++) {
            float nm = fmaxf(m[h], lg[h]);
            float sc = __expf(m[h] - nm);
            float p  = __expf(lg[h] - nm);
            l[h]   = l[h] * sc + p;
            acc[h] = acc[h] * sc + p * v[h];
            m[h]   = nm;
        }
    }
#pragma unroll
    for (int h = 0; h < NHEADS; h++)
        msg[(size_t)n * H + h * DH + lane] = acc[h] / l[h];
}

// x2 = LN(gelu(msg + gat_b)) + x1   (in place over msg)
__global__ void k_x2(float* __restrict__ x2, const float* __restrict__ gatb,
                     const float* __restrict__ n2g, const float* __restrict__ n2b,
                     const float* __restrict__ x1) {
    __shared__ float red[8];
    int n = blockIdx.x, tid = threadIdx.x;
    float v = x2[(size_t)n * H + tid] + gatb[tid];
    float p = gelu_f(v);
    float sm = blk_sum(p, red) * (1.0f / H);
    float dd = p - sm;
    float vv = blk_sum(dd * dd, red) * (1.0f / H);
    float inv = rsqrtf(vv + 1e-5f);
    x2[(size_t)n * H + tid] = dd * inv * n2g[tid] + n2b[tid] + x1[(size_t)n * H + tid];
}

// gates: g2 = Wg2b . tanh(x2@Wg2a+bg2a) + bg2b ; g1 = Wg1b . tanh(x2@Wg1a+bg1a) + bg1b
__global__ __launch_bounds__(256, 4) void k_gates(
        const float* __restrict__ x2, const float* __restrict__ Wg1a,
        const float* __restrict__ bg1a, const float* __restrict__ Wg1b,
        const float* __restrict__ bg1b, const float* __restrict__ Wg2a,
        const float* __restrict__ bg2a, const float* __restrict__ Wg2b,
        const float* __restrict__ bg2b, float* __restrict__ gate1,
        float* __restrict__ gate2) {
    __shared__ float as_[32 * 36];
    __shared__ float ws_[32 * 256];
    int nb = blockIdx.x * 32;
    float acc2[8][4] = {};
    float acc1[8][2] = {};
    for (int k0 = 0; k0 < H; k0 += 32) {
        stageA(x2, nb, k0, H, as_);
        stageW256(Wg2a, k0, ws_);
        __syncthreads();
        mm256(as_, ws_, acc2);
        __syncthreads();
        stageW128(Wg1a, k0, ws_);
        __syncthreads();
        mm128(as_, ws_, acc1);
        __syncthreads();
    }
    int lane = threadIdx.x & 63, tn = threadIdx.x >> 6;
    float wb2[4], b2[4], wb1[2], b1[2];
#pragma unroll
    for (int j = 0; j < 4; j++) { wb2[j] = Wg2b[lane + j * 64]; b2[j] = bg2a[lane + j * 64]; }
#pragma unroll
    for (int j = 0; j < 2; j++) { wb1[j] = Wg1b[lane + j * 64]; b1[j] = bg1a[lane + j * 64]; }
    float c2 = bg2b[0], c1 = bg1b[0];
#pragma unroll
    for (int i = 0; i < 8; i++) {
        float s2 = 0.f;
#pragma unroll
        for (int j = 0; j < 4; j++) s2 += tanhf(acc2[i][j] + b2[j]) * wb2[j];
        s2 = wsum64(s2);
        float s1 = 0.f;
#pragma unroll
        for (int j = 0; j < 2; j++) s1 += tanhf(acc1[i][j] + b1[j]) * wb1[j];
        s1 = wsum64(s1);
        int n = nb + tn * 8 + i;
        if (lane == 0 && n < N_NODES) { gate2[n] = s2 + c2; gate1[n] = s1 + c1; }
    }
}

// per-group pooling (batch sorted -> contiguous ranges); fin = [emb1 | emb2 | gres]
__global__ void k_group(const int* __restrict__ batch, const float* __restrict__ x2,
                        const float* __restrict__ xres, const float* __restrict__ g1,
                        const float* __restrict__ g2, float* __restrict__ fin) {
    __shared__ float red[8];
    __shared__ int seb[2];
    int g = blockIdx.x, tid = threadIdx.x;
    if (tid == 0) {
        seb[0] = lowerb(batch, N_NODES, g);
        seb[1] = lowerb(batch, N_NODES, g + 1);
    }
    __syncthreads();
    int start = seb[0], end = seb[1];
    if (end <= start) {
        fin[(size_t)g * 768 + tid] = 0.f;
        fin[(size_t)g * 768 + 256 + tid] = 0.f;
        fin[(size_t)g * 768 + 512 + tid] = 0.f;
        return;
    }
    float m1 = -3.4e38f, m2 = -3.4e38f;
    for (int i = start + tid; i < end; i += 256) {
        m1 = fmaxf(m1, g1[i]);
        m2 = fmaxf(m2, g2[i]);
    }
    m1 = blk_max(m1, red);
    m2 = blk_max(m2, red);
    float s1 = 0.f, s2 = 0.f, e1 = 0.f, e2 = 0.f, gr = 0.f;
    for (int i = start; i < end; i++) {
        float w1 = __expf(g1[i] - m1);
        float w2 = __expf(g2[i] - m2);
        float xv = x2[(size_t)i * H + tid];
        float rv = xres[(size_t)i * H + tid];
        s1 += w1; s2 += w2;
        e1 += w1 * xv; e2 += w2 * xv; gr += rv;
    }
    float c = (float)(end - start);
    fin[(size_t)g * 768 + tid]       = e1 / s1;
    fin[(size_t)g * 768 + 256 + tid] = e2 / s2;
    fin[(size_t)g * 768 + 512 + tid] = gr / c;
}

// out = gelu(fin @ Wo + bo) / sqrt(1+1e-5) * bn_g + bn_b
__global__ void k_final(const float* __restrict__ fin, const float* __restrict__ Wo,
                        const float* __restrict__ bo, const float* __restrict__ bng,
                        const float* __restrict__ bnb, float* __restrict__ out) {
    __shared__ float fl[768];
    int g = blockIdx.x, tid = threadIdx.x;
    fl[tid]       = fin[(size_t)g * 768 + tid];
    fl[256 + tid] = fin[(size_t)g * 768 + 256 + tid];
    fl[512 + tid] = fin[(size_t)g * 768 + 512 + tid];
    __syncthreads();
#pragma unroll
    for (int half = 0; half < 2; half++) {
        int o = tid + half * 256;
        float acc = bo[o];
#pragma unroll 8
        for (int k = 0; k < 768; k++) acc += fl[k] * Wo[(size_t)k * OUT_DIM + o];
        float val = gelu_f(acc);
        out[(size_t)g * OUT_DIM + o] = val * 0.9999950000374997f * bng[o] + bnb[o];
    }
}

extern "C" void kernel_launch(void* const* d_in, const int* in_sizes, int n_in,
                              void* d_out, int out_size, void* d_ws, size_t ws_size,
                              hipStream_t stream) {
    const float* x     = (const float*)d_in[0];
    const int*   ei    = (const int*)d_in[1];
    const int*   batch = (const int*)d_in[2];
    const float* ln_in_g = (const float*)d_in[3];
    const float* ln_in_b = (const float*)d_in[4];
    const float* Wp    = (const float*)d_in[5];
    const float* bp    = (const float*)d_in[6];
    const float* lnp_g = (const float*)d_in[7];
    const float* lnp_b = (const float*)d_in[8];
    const float* Wrel  = (const float*)d_in[9];
    const float* brel  = (const float*)d_in[10];
    const float* Wroot = (const float*)d_in[11];
    const float* n1_g  = (const float*)d_in[12];
    const float* n1_b  = (const float*)d_in[13];
    const float* Wl    = (const float*)d_in[14];
    const float* bl    = (const float*)d_in[15];
    const float* Wr    = (const float*)d_in[16];
    const float* br    = (const float*)d_in[17];
    const float* att   = (const float*)d_in[18];
    const float* gat_b = (const float*)d_in[19];
    const float* n2_g  = (const float*)d_in[20];
    const float* n2_b  = (const float*)d_in[21];
    const float* Wg1a  = (const float*)d_in[22];
    const float* bg1a  = (const float*)d_in[23];
    const float* Wg1b  = (const float*)d_in[24];
    const float* bg1b  = (const float*)d_in[25];
    const float* Wg2a  = (const float*)d_in[26];
    const float* bg2a  = (const float*)d_in[27];
    const float* Wg2b  = (const float*)d_in[28];
    const float* bg2b  = (const float*)d_in[29];
    const float* Wo    = (const float*)d_in[30];
    const float* bo    = (const float*)d_in[31];
    const float* bn_g  = (const float*)d_in[32];
    const float* bn_b  = (const float*)d_in[33];

    float* ws = (float*)d_ws;
    int* wsi = (int*)d_ws;
    const int* src = ei;
    const int* dst = ei + N_EDGES;
    int* cur = wsi + IOFF_CUR;
    int* row = wsi + IOFF_ROW;
    int* col = wsi + IOFF_COL;
    const int GB = (N_NODES + 31) / 32;  // 313 GEMM blocks

    // ---- CSR build ----
    hipMemsetAsync(cur, 0, N_NODES * sizeof(int), stream);
    k_count<<<(N_EDGES + 255) / 256, 256, 0, stream>>>(dst, cur);
    k_scan<<<1, 1024, 0, stream>>>(cur, row);
    hipMemsetAsync(cur, 0, N_NODES * sizeof(int), stream);
    k_fill<<<(N_EDGES + 255) / 256, 256, 0, stream>>>(src, dst, row, cur, col);

    k_lnstat<<<N_NODES, 256, 0, stream>>>(x, ws + OFF_MEAN, ws + OFF_INVS);
    k_proj<<<GB, 256, 0, stream>>>(x, ws + OFF_MEAN, ws + OFF_INVS, ln_in_g, ln_in_b,
                                   Wp, bp, lnp_g, lnp_b, ws + OFF_XRES);
    k_gather<<<N_NODES, 256, 0, stream>>>(row, col, ws + OFF_XRES, ws + OFF_AGG);
    k_conv<<<GB, 256, 0, stream>>>(ws + OFF_AGG, ws + OFF_XRES, Wrel, brel, Wroot,
                                   n1_g, n1_b, ws + OFF_X1);
    k_lin<<<GB, 256, 0, stream>>>(ws + OFF_X1, Wl, bl, ws + OFF_XL);
    k_lin<<<GB, 256, 0, stream>>>(ws + OFF_X1, Wr, br, ws + OFF_XR);
    k_gat<<<(N_NODES + 3) / 4, 256, 0, stream>>>(row, col, ws + OFF_XL, ws + OFF_XR,
                                                 att, ws + OFF_AGG);
    k_x2<<<N_NODES, 256, 0, stream>>>(ws + OFF_AGG, gat_b, n2_g, n2_b, ws + OFF_X1);
    k_gates<<<GB, 256, 0, stream>>>(ws + OFF_AGG, Wg1a, bg1a, Wg1b, bg1b, Wg2a, bg2a,
                                    Wg2b, bg2b, ws + OFF_G1, ws + OFF_G2);
    k_group<<<NG, 256, 0, stream>>>(batch, ws + OFF_AGG, ws + OFF_XRES, ws + OFF_G1,
                                    ws + OFF_G2, ws + OFF_FIN);
    k_final<<<NG, 256, 0, stream>>>(ws + OFF_FIN, Wo, bo, bn_g, bn_b, (float*)d_out);
}

// Round 5
// 711.881 us; speedup vs baseline: 2.3229x; 1.1770x over previous
//
#include <hip/hip_runtime.h>
#include <hip/hip_bf16.h>

#define N_NODES 10000
#define N_EDGES 320000
#define DIN 512
#define H 256
#define NHEADS 4
#define DH 64
#define NG 64
#define OUT_DIM 512

// ---------- workspace layout (float offsets) ----------
static const size_t OFF_XRES = 0;           // N*H
static const size_t OFF_AGG  = 2560000;     // N*H  (agg, later reused as x2)
static const size_t OFF_X1   = 5120000;     // N*H
static const size_t OFF_XL   = 7680000;     // N*H
static const size_t OFF_XR   = 10240000;    // N*H
static const size_t OFF_MEAN = 12800000;    // N
static const size_t OFF_INVS = 12810000;    // N
static const size_t OFF_G1   = 12820000;    // N
static const size_t OFF_G2   = 12830000;    // N
static const size_t OFF_FIN  = 12840000;    // G*768
// int region (int offsets into (int*)ws)
static const size_t IOFF_CUR = 12900000;    // N ints
static const size_t IOFF_ROW = 12910016;    // N+1 ints
static const size_t IOFF_COL = 12920032;    // E ints

__device__ __forceinline__ float gelu_f(float x) {
    return 0.5f * x * (1.0f + erff(x * 0.70710678118654752440f));
}

__device__ __forceinline__ float wsum64(float v) {
#pragma unroll
    for (int o = 32; o > 0; o >>= 1) v += __shfl_xor(v, o, 64);
    return v;
}

__device__ __forceinline__ float blk_sum(float v, float* s) {
#pragma unroll
    for (int o = 32; o > 0; o >>= 1) v += __shfl_xor(v, o, 64);
    int lane = threadIdx.x & 63, w = threadIdx.x >> 6;
    __syncthreads();
    if (lane == 0) s[w] = v;
    __syncthreads();
    float t = 0.f;
    int nw = blockDim.x >> 6;
    for (int i = 0; i < nw; i++) t += s[i];
    return t;
}

__device__ __forceinline__ float blk_max(float v, float* s) {
#pragma unroll
    for (int o = 32; o > 0; o >>= 1) v = fmaxf(v, __shfl_xor(v, o, 64));
    int lane = threadIdx.x & 63, w = threadIdx.x >> 6;
    __syncthreads();
    if (lane == 0) s[w] = v;
    __syncthreads();
    float t = s[0];
    int nw = blockDim.x >> 6;
    for (int i = 1; i < nw; i++) t = fmaxf(t, s[i]);
    return t;
}

__device__ __forceinline__ int lowerb(const int* b, int n, int v) {
    int lo = 0, hi = n;
    while (lo < hi) { int mid = (lo + hi) >> 1; if (b[mid] < v) lo = mid + 1; else hi = mid; }
    return lo;
}

// ---------- CSR build (by dst) ----------
__global__ void k_count(const int* __restrict__ dst, int* __restrict__ deg) {
    int e = blockIdx.x * blockDim.x + threadIdx.x;
    if (e < N_EDGES) atomicAdd(&deg[dst[e]], 1);
}

__global__ void k_scan(const int* __restrict__ deg, int* __restrict__ row) {
    __shared__ int part[1024];
    int t = threadIdx.x;
    int base = t * 10;
    int v[10];
    int s = 0;
#pragma unroll
    for (int i = 0; i < 10; i++) {
        int idx = base + i;
        v[i] = (idx < N_NODES) ? deg[idx] : 0;
        s += v[i];
    }
    part[t] = s;
    __syncthreads();
    for (int off = 1; off < 1024; off <<= 1) {
        int x = (t >= off) ? part[t - off] : 0;
        __syncthreads();
        part[t] += x;
        __syncthreads();
    }
    int run = (t == 0) ? 0 : part[t - 1];
#pragma unroll
    for (int i = 0; i < 10; i++) {
        int idx = base + i;
        if (idx < N_NODES) row[idx] = run;
        run += v[i];
    }
    if (t == 1023) row[N_NODES] = part[1023];
}

__global__ void k_fill(const int* __restrict__ src, const int* __restrict__ dst,
                       const int* __restrict__ row, int* __restrict__ cur,
                       int* __restrict__ col) {
    int e = blockIdx.x * blockDim.x + threadIdx.x;
    if (e >= N_EDGES) return;
    int d = dst[e];
    int pos = atomicAdd(&cur[d], 1);
    col[row[d] + pos] = src[e];
}

// ---------- GEMM building blocks (16-node tiles, grid 626) ----------
// Thread map: lane owns cols {lane, lane+64, lane+128, lane+192};
//             wave tn owns nodes {tn*4 .. tn*4+3}.
// LDS: A chunk [16][36] (pad 4), W chunk [32][256] (or [32][128]).

__device__ __forceinline__ void stageW256(const float* __restrict__ W, int k0,
                                          float* __restrict__ ws_) {
    int t = threadIdx.x;
    const float4* Wg = (const float4*)(W + (size_t)k0 * 256);
    float4* wl = (float4*)ws_;
#pragma unroll
    for (int i = 0; i < 8; i++) wl[t + i * 256] = Wg[t + i * 256];
}

__device__ __forceinline__ void stageW128(const float* __restrict__ W, int k0,
                                          float* __restrict__ ws_) {
    int t = threadIdx.x;
    const float4* Wg = (const float4*)(W + (size_t)k0 * 128);
    float4* wl = (float4*)ws_;
#pragma unroll
    for (int i = 0; i < 4; i++) wl[t + i * 256] = Wg[t + i * 256];
}

__device__ __forceinline__ void stageA16(const float* __restrict__ A, int nb, int k0,
                                         int kstride, float* __restrict__ as_) {
    int t = threadIdx.x;
    if (t < 128) {
        int r = t >> 3, q = t & 7;
        int n = nb + r;
        float4 v = make_float4(0.f, 0.f, 0.f, 0.f);
        if (n < N_NODES) v = *(const float4*)(A + (size_t)n * kstride + k0 + q * 4);
        *(float4*)(as_ + r * 36 + q * 4) = v;
    }
}

__device__ __forceinline__ void stageA16_ln(const float* __restrict__ x,
                                            const float* __restrict__ mean,
                                            const float* __restrict__ invs,
                                            const float* __restrict__ g0,
                                            const float* __restrict__ b0, int nb, int k0,
                                            float* __restrict__ as_) {
    int t = threadIdx.x;
    if (t < 128) {
        int r = t >> 3, q = t & 7;
        int n = nb + r;
        float4 v = make_float4(0.f, 0.f, 0.f, 0.f);
        if (n < N_NODES) {
            float4 xv = *(const float4*)(x + (size_t)n * DIN + k0 + q * 4);
            float4 gv = *(const float4*)(g0 + k0 + q * 4);
            float4 bv = *(const float4*)(b0 + k0 + q * 4);
            float m = mean[n], is = invs[n];
            v.x = (xv.x - m) * is * gv.x + bv.x;
            v.y = (xv.y - m) * is * gv.y + bv.y;
            v.z = (xv.z - m) * is * gv.z + bv.z;
            v.w = (xv.w - m) * is * gv.w + bv.w;
        }
        *(float4*)(as_ + r * 36 + q * 4) = v;
    }
}

__device__ __forceinline__ void mm256_16(const float* __restrict__ as_,
                                         const float* __restrict__ ws_,
                                         float (&acc)[4][4]) {
    int lane = threadIdx.x & 63, tn = threadIdx.x >> 6;
#pragma unroll
    for (int kk = 0; kk < 32; kk += 4) {
        float xq[4][4];
#pragma unroll
        for (int i = 0; i < 4; i++) {
            float4 v = *(const float4*)(as_ + (tn * 4 + i) * 36 + kk);
            xq[i][0] = v.x; xq[i][1] = v.y; xq[i][2] = v.z; xq[i][3] = v.w;
        }
#pragma unroll
        for (int t = 0; t < 4; t++) {
            const float* wr = ws_ + (kk + t) * 256 + lane;
            float w0 = wr[0], w1 = wr[64], w2 = wr[128], w3 = wr[192];
#pragma unroll
            for (int i = 0; i < 4; i++) {
                float a = xq[i][t];
                acc[i][0] += a * w0; acc[i][1] += a * w1;
                acc[i][2] += a * w2; acc[i][3] += a * w3;
            }
        }
    }
}

__device__ __forceinline__ void mm128_16(const float* __restrict__ as_,
                                         const float* __restrict__ ws_,
                                         float (&acc)[4][2]) {
    int lane = threadIdx.x & 63, tn = threadIdx.x >> 6;
#pragma unroll
    for (int kk = 0; kk < 32; kk += 4) {
        float xq[4][4];
#pragma unroll
        for (int i = 0; i < 4; i++) {
            float4 v = *(const float4*)(as_ + (tn * 4 + i) * 36 + kk);
            xq[i][0] = v.x; xq[i][1] = v.y; xq[i][2] = v.z; xq[i][3] = v.w;
        }
#pragma unroll
        for (int t = 0; t < 4; t++) {
            const float* wr = ws_ + (kk + t) * 128 + lane;
            float w0 = wr[0], w1 = wr[64];
#pragma unroll
            for (int i = 0; i < 4; i++) {
                float a = xq[i][t];
                acc[i][0] += a * w0; acc[i][1] += a * w1;
            }
        }
    }
}

// ---------- kernels ----------

// per-node mean / inv-std of x[n][0:512]
__global__ void k_lnstat(const float* __restrict__ x, float* __restrict__ mean,
                         float* __restrict__ invs) {
    __shared__ float red[8];
    int n = blockIdx.x, tid = threadIdx.x;
    float v0 = x[(size_t)n * DIN + tid];
    float v1 = x[(size_t)n * DIN + 256 + tid];
    float m = blk_sum(v0 + v1, red) * (1.0f / DIN);
    float d0 = v0 - m, d1 = v1 - m;
    float var = blk_sum(d0 * d0 + d1 * d1, red) * (1.0f / DIN);
    if (tid == 0) { mean[n] = m; invs[n] = rsqrtf(var + 1e-5f); }
}

// x_res = LN(gelu(LN_in(x) @ Wp + bp))
__global__ __launch_bounds__(256, 4) void k_proj(
        const float* __restrict__ x, const float* __restrict__ mean,
        const float* __restrict__ invs, const float* __restrict__ g0,
        const float* __restrict__ b0, const float* __restrict__ Wp,
        const float* __restrict__ bp, const float* __restrict__ lg,
        const float* __restrict__ lb, float* __restrict__ xres) {
    __shared__ float as_[16 * 36];
    __shared__ float ws_[32 * 256];
    int nb = blockIdx.x * 16;
    float acc[4][4] = {};
    for (int k0 = 0; k0 < DIN; k0 += 32) {
        stageA16_ln(x, mean, invs, g0, b0, nb, k0, as_);
        stageW256(Wp, k0, ws_);
        __syncthreads();
        mm256_16(as_, ws_, acc);
        __syncthreads();
    }
    int lane = threadIdx.x & 63, tn = threadIdx.x >> 6;
    float bp4[4], lg4[4], lb4[4];
#pragma unroll
    for (int j = 0; j < 4; j++) {
        bp4[j] = bp[lane + j * 64];
        lg4[j] = lg[lane + j * 64];
        lb4[j] = lb[lane + j * 64];
    }
#pragma unroll
    for (int i = 0; i < 4; i++) {
        float v[4];
#pragma unroll
        for (int j = 0; j < 4; j++) v[j] = gelu_f(acc[i][j] + bp4[j]);
        float m = wsum64(v[0] + v[1] + v[2] + v[3]) * (1.0f / H);
        float d[4], q = 0.f;
#pragma unroll
        for (int j = 0; j < 4; j++) { d[j] = v[j] - m; q += d[j] * d[j]; }
        float inv = rsqrtf(wsum64(q) * (1.0f / H) + 1e-5f);
        int n = nb + tn * 4 + i;
        if (n < N_NODES) {
#pragma unroll
            for (int j = 0; j < 4; j++)
                xres[(size_t)n * H + lane + j * 64] = d[j] * inv * lg4[j] + lb4[j];
        }
    }
}

// agg[n] = sum_{s in nbrs(n)} xres[s]
__global__ void k_gather(const int* __restrict__ row, const int* __restrict__ col,
                         const float* __restrict__ xres, float* __restrict__ agg) {
    int n = blockIdx.x, tid = threadIdx.x;
    int s0 = row[n], e0 = row[n + 1];
    float a = 0.f;
    for (int i = s0; i < e0; i++) a += xres[(size_t)col[i] * H + tid];
    agg[(size_t)n * H + tid] = a;
}

// x1 = LN(gelu(agg@Wrel + brel + xres@Wroot)) + xres
__global__ __launch_bounds__(256, 4) void k_conv(
        const float* __restrict__ agg, const float* __restrict__ xres,
        const float* __restrict__ Wrel, const float* __restrict__ brel,
        const float* __restrict__ Wroot, const float* __restrict__ n1g,
        const float* __restrict__ n1b, float* __restrict__ x1) {
    __shared__ float as_[16 * 36];
    __shared__ float ws_[32 * 256];
    int nb = blockIdx.x * 16;
    float acc[4][4] = {};
    for (int k0 = 0; k0 < H; k0 += 32) {
        stageA16(agg, nb, k0, H, as_);
        stageW256(Wrel, k0, ws_);
        __syncthreads();
        mm256_16(as_, ws_, acc);
        __syncthreads();
    }
    for (int k0 = 0; k0 < H; k0 += 32) {
        stageA16(xres, nb, k0, H, as_);
        stageW256(Wroot, k0, ws_);
        __syncthreads();
        mm256_16(as_, ws_, acc);
        __syncthreads();
    }
    int lane = threadIdx.x & 63, tn = threadIdx.x >> 6;
    float bb[4], gg[4], nb4[4];
#pragma unroll
    for (int j = 0; j < 4; j++) {
        bb[j] = brel[lane + j * 64];
        gg[j] = n1g[lane + j * 64];
        nb4[j] = n1b[lane + j * 64];
    }
#pragma unroll
    for (int i = 0; i < 4; i++) {
        float v[4];
#pragma unroll
        for (int j = 0; j < 4; j++) v[j] = gelu_f(acc[i][j] + bb[j]);
        float m = wsum64(v[0] + v[1] + v[2] + v[3]) * (1.0f / H);
        float d[4], q = 0.f;
#pragma unroll
        for (int j = 0; j < 4; j++) { d[j] = v[j] - m; q += d[j] * d[j]; }
        float inv = rsqrtf(wsum64(q) * (1.0f / H) + 1e-5f);
        int n = nb + tn * 4 + i;
        if (n < N_NODES) {
#pragma unroll
            for (int j = 0; j < 4; j++) {
                size_t idx = (size_t)n * H + lane + j * 64;
                x1[idx] = d[j] * inv * gg[j] + nb4[j] + xres[idx];
            }
        }
    }
}

// xl = x1@Wl + bl ; xr = x1@Wr + br  (fused: stage A once per chunk)
__global__ __launch_bounds__(256, 4) void k_lin2(
        const float* __restrict__ x1, const float* __restrict__ Wl,
        const float* __restrict__ bl, const float* __restrict__ Wr,
        const float* __restrict__ br, float* __restrict__ xl,
        float* __restrict__ xr) {
    __shared__ float as_[16 * 36];
    __shared__ float ws_[32 * 256];
    int nb = blockIdx.x * 16;
    float accL[4][4] = {};
    float accR[4][4] = {};
    for (int k0 = 0; k0 < H; k0 += 32) {
        stageA16(x1, nb, k0, H, as_);
        stageW256(Wl, k0, ws_);
        __syncthreads();
        mm256_16(as_, ws_, accL);
        __syncthreads();
        stageW256(Wr, k0, ws_);
        __syncthreads();
        mm256_16(as_, ws_, accR);
        __syncthreads();
    }
    int lane = threadIdx.x & 63, tn = threadIdx.x >> 6;
    float bl4[4], br4[4];
#pragma unroll
    for (int j = 0; j < 4; j++) { bl4[j] = bl[lane + j * 64]; br4[j] = br[lane + j * 64]; }
#pragma unroll
    for (int i = 0; i < 4; i++) {
        int n = nb + tn * 4 + i;
        if (n < N_NODES) {
#pragma unroll
            for (int j = 0; j < 4; j++) {
                xl[(size_t)n * H + lane + j * 64] = accL[i][j] + bl4[j];
                xr[(size_t)n * H + lane + j * 64] = accR[i][j] + br4[j];
            }
        }
    }
}

// fused GATv2 + x2 epilogue. Block = node (4 waves = 4 heads).
// Online softmax over incoming edges, unrolled x4; then
// x2 = LN(gelu(msg + gat_b)) + x1 via block reduction.
__global__ __launch_bounds__(256, 8) void k_gat(
        const int* __restrict__ row, const int* __restrict__ col,
        const float* __restrict__ xl, const float* __restrict__ xr,
        const float* __restrict__ att, const float* __restrict__ gatb,
        const float* __restrict__ n2g, const float* __restrict__ n2b,
        const float* __restrict__ x1, float* __restrict__ x2) {
    __shared__ float red[8];
    int n = blockIdx.x;
    int lane = threadIdx.x & 63;
    int off = threadIdx.x;           // h*64 + lane, h = tid>>6
    float attv = att[off];
    float xrd = xr[(size_t)n * H + off];
    float v0 = xl[(size_t)n * H + off];
    float a0 = v0 + xrd; a0 = (a0 > 0.f) ? a0 : 0.2f * a0;
    float m = wsum64(a0 * attv);
    float l = 1.f, acc = v0;
    int i = row[n], end = row[n + 1];
    for (; i + 3 < end; i += 4) {
        int s0 = col[i], s1 = col[i + 1], s2 = col[i + 2], s3 = col[i + 3];
        float w0 = xl[(size_t)s0 * H + off];
        float w1 = xl[(size_t)s1 * H + off];
        float w2 = xl[(size_t)s2 * H + off];
        float w3 = xl[(size_t)s3 * H + off];
        float b0 = w0 + xrd; b0 = (b0 > 0.f) ? b0 : 0.2f * b0;
        float b1 = w1 + xrd; b1 = (b1 > 0.f) ? b1 : 0.2f * b1;
        float b2 = w2 + xrd; b2 = (b2 > 0.f) ? b2 : 0.2f * b2;
        float b3 = w3 + xrd; b3 = (b3 > 0.f) ? b3 : 0.2f * b3;
        b0 *= attv; b1 *= attv; b2 *= attv; b3 *= attv;
#pragma unroll
        for (int o = 32; o > 0; o >>= 1) {
            b0 += __shfl_xor(b0, o, 64);
            b1 += __shfl_xor(b1, o, 64);
            b2 += __shfl_xor(b2, o, 64);
            b3 += __shfl_xor(b3, o, 64);
        }
        float nm, sc, p;
        nm = fmaxf(m, b0); sc = __expf(m - nm); p = __expf(b0 - nm);
        l = l * sc + p; acc = acc * sc + p * w0; m = nm;
        nm = fmaxf(m, b1); sc = __expf(m - nm); p = __expf(b1 - nm);
        l = l * sc + p; acc = acc * sc + p * w1; m = nm;
        nm = fmaxf(m, b2); sc = __expf(m - nm); p = __expf(b2 - nm);
        l = l * sc + p; acc = acc * sc + p * w2; m = nm;
        nm = fmaxf(m, b3); sc = __expf(m - nm); p = __expf(b3 - nm);
        l = l * sc + p; acc = acc * sc + p * w3; m = nm;
    }
    for (; i < end; i++) {
        int s = col[i];
        float w = xl[(size_t)s * H + off];
        float b = w + xrd; b = (b > 0.f) ? b : 0.2f * b;
        b *= attv;
#pragma unroll
        for (int o = 32; o > 0; o >>= 1) b += __shfl_xor(b, o, 64);
        float nm = fmaxf(m, b);
        float sc = __expf(m - nm);
        float p = __expf(b - nm);
        l = l * sc + p; acc = acc * sc + p * w; m = nm;
    }
    // ---- fused x2 epilogue: LN(gelu(msg + gatb)) + x1 ----
    float msg = acc / l;
    float p = gelu_f(msg + gatb[off]);
    float sm = blk_sum(p, red) * (1.0f / H);
    float dd = p - sm;
    float vv = blk_sum(dd * dd, red) * (1.0f / H);
    float inv = rsqrtf(vv + 1e-5f);
    x2[(size_t)n * H + off] = dd * inv * n2g[off] + n2b[off] + x1[(size_t)n * H + off];
}

// gates: g2 = Wg2b . tanh(x2@Wg2a+bg2a) + bg2b ; g1 = Wg1b . tanh(x2@Wg1a+bg1a) + bg1b
__global__ __launch_bounds__(256, 4) void k_gates(
        const float* __restrict__ x2, const float* __restrict__ Wg1a,
        const float* __restrict__ bg1a, const float* __restrict__ Wg1b,
        const float* __restrict__ bg1b, const float* __restrict__ Wg2a,
        const float* __restrict__ bg2a, const float* __restrict__ Wg2b,
        const float* __restrict__ bg2b, float* __restrict__ gate1,
        float* __restrict__ gate2) {
    __shared__ float as_[16 * 36];
    __shared__ float ws_[32 * 256];
    int nb = blockIdx.x * 16;
    float acc2[4][4] = {};
    float acc1[4][2] = {};
    for (int k0 = 0; k0 < H; k0 += 32) {
        stageA16(x2, nb, k0, H, as_);
        stageW256(Wg2a, k0, ws_);
        __syncthreads();
        mm256_16(as_, ws_, acc2);
        __syncthreads();
        stageW128(Wg1a, k0, ws_);
        __syncthreads();
        mm128_16(as_, ws_, acc1);
        __syncthreads();
    }
    int lane = threadIdx.x & 63, tn = threadIdx.x >> 6;
    float wb2[4], b2[4], wb1[2], b1[2];
#pragma unroll
    for (int j = 0; j < 4; j++) { wb2[j] = Wg2b[lane + j * 64]; b2[j] = bg2a[lane + j * 64]; }
#pragma unroll
    for (int j = 0; j < 2; j++) { wb1[j] = Wg1b[lane + j * 64]; b1[j] = bg1a[lane + j * 64]; }
    float c2 = bg2b[0], c1 = bg1b[0];
#pragma unroll
    for (int i = 0; i < 4; i++) {
        float s2 = 0.f;
#pragma unroll
        for (int j = 0; j < 4; j++) s2 += tanhf(acc2[i][j] + b2[j]) * wb2[j];
        s2 = wsum64(s2);
        float s1 = 0.f;
#pragma unroll
        for (int j = 0; j < 2; j++) s1 += tanhf(acc1[i][j] + b1[j]) * wb1[j];
        s1 = wsum64(s1);
        int n = nb + tn * 4 + i;
        if (lane == 0 && n < N_NODES) { gate2[n] = s2 + c2; gate1[n] = s1 + c1; }
    }
}

// per-group pooling (batch sorted -> contiguous ranges); fin = [emb1 | emb2 | gres]
__global__ void k_group(const int* __restrict__ batch, const float* __restrict__ x2,
                        const float* __restrict__ xres, const float* __restrict__ g1,
                        const float* __restrict__ g2, float* __restrict__ fin) {
    __shared__ float red[8];
    __shared__ int seb[2];
    int g = blockIdx.x, tid = threadIdx.x;
    if (tid == 0) {
        seb[0] = lowerb(batch, N_NODES, g);
        seb[1] = lowerb(batch, N_NODES, g + 1);
    }
    __syncthreads();
    int start = seb[0], end = seb[1];
    if (end <= start) {
        fin[(size_t)g * 768 + tid] = 0.f;
        fin[(size_t)g * 768 + 256 + tid] = 0.f;
        fin[(size_t)g * 768 + 512 + tid] = 0.f;
        return;
    }
    float m1 = -3.4e38f, m2 = -3.4e38f;
    for (int i = start + tid; i < end; i += 256) {
        m1 = fmaxf(m1, g1[i]);
        m2 = fmaxf(m2, g2[i]);
    }
    m1 = blk_max(m1, red);
    m2 = blk_max(m2, red);
    float s1 = 0.f, s2 = 0.f, e1 = 0.f, e2 = 0.f, gr = 0.f;
    for (int i = start; i < end; i++) {
        float w1 = __expf(g1[i] - m1);
        float w2 = __expf(g2[i] - m2);
        float xv = x2[(size_t)i * H + tid];
        float rv = xres[(size_t)i * H + tid];
        s1 += w1; s2 += w2;
        e1 += w1 * xv; e2 += w2 * xv; gr += rv;
    }
    float c = (float)(end - start);
    fin[(size_t)g * 768 + tid]       = e1 / s1;
    fin[(size_t)g * 768 + 256 + tid] = e2 / s2;
    fin[(size_t)g * 768 + 512 + tid] = gr / c;
}

// out = gelu(fin @ Wo + bo) / sqrt(1+1e-5) * bn_g + bn_b
__global__ void k_final(const float* __restrict__ fin, const float* __restrict__ Wo,
                        const float* __restrict__ bo, const float* __restrict__ bng,
                        const float* __restrict__ bnb, float* __restrict__ out) {
    __shared__ float fl[768];
    int g = blockIdx.x, tid = threadIdx.x;
    fl[tid]       = fin[(size_t)g * 768 + tid];
    fl[256 + tid] = fin[(size_t)g * 768 + 256 + tid];
    fl[512 + tid] = fin[(size_t)g * 768 + 512 + tid];
    __syncthreads();
#pragma unroll
    for (int half = 0; half < 2; half++) {
        int o = tid + half * 256;
        float acc = bo[o];
#pragma unroll 8
        for (int k = 0; k < 768; k++) acc += fl[k] * Wo[(size_t)k * OUT_DIM + o];
        float val = gelu_f(acc);
        out[(size_t)g * OUT_DIM + o] = val * 0.9999950000374997f * bng[o] + bnb[o];
    }
}

extern "C" void kernel_launch(void* const* d_in, const int* in_sizes, int n_in,
                              void* d_out, int out_size, void* d_ws, size_t ws_size,
                              hipStream_t stream) {
    const float* x     = (const float*)d_in[0];
    const int*   ei    = (const int*)d_in[1];
    const int*   batch = (const int*)d_in[2];
    const float* ln_in_g = (const float*)d_in[3];
    const float* ln_in_b = (const float*)d_in[4];
    const float* Wp    = (const float*)d_in[5];
    const float* bp    = (const float*)d_in[6];
    const float* lnp_g = (const float*)d_in[7];
    const float* lnp_b = (const float*)d_in[8];
    const float* Wrel  = (const float*)d_in[9];
    const float* brel  = (const float*)d_in[10];
    const float* Wroot = (const float*)d_in[11];
    const float* n1_g  = (const float*)d_in[12];
    const float* n1_b  = (const float*)d_in[13];
    const float* Wl    = (const float*)d_in[14];
    const float* bl    = (const float*)d_in[15];
    const float* Wr    = (const float*)d_in[16];
    const float* br    = (const float*)d_in[17];
    const float* att   = (const float*)d_in[18];
    const float* gat_b = (const float*)d_in[19];
    const float* n2_g  = (const float*)d_in[20];
    const float* n2_b  = (const float*)d_in[21];
    const float* Wg1a  = (const float*)d_in[22];
    const float* bg1a  = (const float*)d_in[23];
    const float* Wg1b  = (const float*)d_in[24];
    const float* bg1b  = (const float*)d_in[25];
    const float* Wg2a  = (const float*)d_in[26];
    const float* bg2a  = (const float*)d_in[27];
    const float* Wg2b  = (const float*)d_in[28];
    const float* bg2b  = (const float*)d_in[29];
    const float* Wo    = (const float*)d_in[30];
    const float* bo    = (const float*)d_in[31];
    const float* bn_g  = (const float*)d_in[32];
    const float* bn_b  = (const float*)d_in[33];

    float* ws = (float*)d_ws;
    int* wsi = (int*)d_ws;
    const int* src = ei;
    const int* dst = ei + N_EDGES;
    int* cur = wsi + IOFF_CUR;
    int* row = wsi + IOFF_ROW;
    int* col = wsi + IOFF_COL;
    const int GB = (N_NODES + 15) / 16;  // 626 GEMM blocks

    // ---- CSR build ----
    hipMemsetAsync(cur, 0, N_NODES * sizeof(int), stream);
    k_count<<<(N_EDGES + 255) / 256, 256, 0, stream>>>(dst, cur);
    k_scan<<<1, 1024, 0, stream>>>(cur, row);
    hipMemsetAsync(cur, 0, N_NODES * sizeof(int), stream);
    k_fill<<<(N_EDGES + 255) / 256, 256, 0, stream>>>(src, dst, row, cur, col);

    k_lnstat<<<N_NODES, 256, 0, stream>>>(x, ws + OFF_MEAN, ws + OFF_INVS);
    k_proj<<<GB, 256, 0, stream>>>(x, ws + OFF_MEAN, ws + OFF_INVS, ln_in_g, ln_in_b,
                                   Wp, bp, lnp_g, lnp_b, ws + OFF_XRES);
    k_gather<<<N_NODES, 256, 0, stream>>>(row, col, ws + OFF_XRES, ws + OFF_AGG);
    k_conv<<<GB, 256, 0, stream>>>(ws + OFF_AGG, ws + OFF_XRES, Wrel, brel, Wroot,
                                   n1_g, n1_b, ws + OFF_X1);
    k_lin2<<<GB, 256, 0, stream>>>(ws + OFF_X1, Wl, bl, Wr, br, ws + OFF_XL,
                                   ws + OFF_XR);
    k_gat<<<N_NODES, 256, 0, stream>>>(row, col, ws + OFF_XL, ws + OFF_XR, att, gat_b,
                                       n2_g, n2_b, ws + OFF_X1, ws + OFF_AGG);
    k_gates<<<GB, 256, 0, stream>>>(ws + OFF_AGG, Wg1a, bg1a, Wg1b, bg1b, Wg2a, bg2a,
                                    Wg2b, bg2b, ws + OFF_G1, ws + OFF_G2);
    k_group<<<NG, 256, 0, stream>>>(batch, ws + OFF_AGG, ws + OFF_XRES, ws + OFF_G1,
                                    ws + OFF_G2, ws + OFF_FIN);
    k_final<<<NG, 256, 0, stream>>>(ws + OFF_FIN, Wo, bo, bn_g, bn_b, (float*)d_out);
}

// Round 6
// 638.742 us; speedup vs baseline: 2.5889x; 1.1145x over previous
//
#include <hip/hip_runtime.h>
#include <hip/hip_bf16.h>

#define N_NODES 10000
#define N_EDGES 320000
#define DIN 512
#define H 256
#define NHEADS 4
#define DH 64
#define NG 64
#define OUT_DIM 512

typedef __hip_bfloat16 bf16;

// ---------- workspace layout (float offsets) ----------
static const size_t OFF_XRES  = 0;           // N*H fp32
static const size_t OFF_AGG   = 2560000;     // N*H fp32 (agg, later reused as x2)
static const size_t OFF_X1    = 5120000;     // N*H fp32
static const size_t OFF_XLB   = 7680000;     // N*H bf16 (1.28M floats)
static const size_t OFF_XRB   = 8960000;     // N*H bf16
static const size_t OFF_XRESB = 10240000;    // N*H bf16
static const size_t OFF_G1    = 11520000;    // N
static const size_t OFF_G2    = 11530000;    // N
static const size_t OFF_GS1   = 11540000;    // 64
static const size_t OFF_GS2   = 11540064;    // 64
static const size_t OFF_FIN   = 11540128;    // G*768
// int region (int offsets into (int*)ws)
static const size_t IOFF_CUR  = 11600000;    // N ints
static const size_t IOFF_ROW  = 11610016;    // N+1 ints
static const size_t IOFF_COL  = 11620032;    // E ints

__device__ __forceinline__ float gelu_f(float x) {
    return 0.5f * x * (1.0f + erff(x * 0.70710678118654752440f));
}

__device__ __forceinline__ float wsum64(float v) {
#pragma unroll
    for (int o = 32; o > 0; o >>= 1) v += __shfl_xor(v, o, 64);
    return v;
}

__device__ __forceinline__ float blk_sum(float v, float* s) {
#pragma unroll
    for (int o = 32; o > 0; o >>= 1) v += __shfl_xor(v, o, 64);
    int lane = threadIdx.x & 63, w = threadIdx.x >> 6;
    __syncthreads();
    if (lane == 0) s[w] = v;
    __syncthreads();
    float t = 0.f;
    int nw = blockDim.x >> 6;
    for (int i = 0; i < nw; i++) t += s[i];
    return t;
}

__device__ __forceinline__ float blk_max(float v, float* s) {
#pragma unroll
    for (int o = 32; o > 0; o >>= 1) v = fmaxf(v, __shfl_xor(v, o, 64));
    int lane = threadIdx.x & 63, w = threadIdx.x >> 6;
    __syncthreads();
    if (lane == 0) s[w] = v;
    __syncthreads();
    float t = s[0];
    int nw = blockDim.x >> 6;
    for (int i = 1; i < nw; i++) t = fmaxf(t, s[i]);
    return t;
}

__device__ __forceinline__ int lowerb(const int* b, int n, int v) {
    int lo = 0, hi = n;
    while (lo < hi) { int mid = (lo + hi) >> 1; if (b[mid] < v) lo = mid + 1; else hi = mid; }
    return lo;
}

// ---------- CSR build (by dst) ----------
__global__ void k_count(const int* __restrict__ dst, int* __restrict__ deg) {
    int e = blockIdx.x * blockDim.x + threadIdx.x;
    if (e < N_EDGES) atomicAdd(&deg[dst[e]], 1);
}

__global__ void k_scan(const int* __restrict__ deg, int* __restrict__ row) {
    __shared__ int part[1024];
    int t = threadIdx.x;
    int base = t * 10;
    int v[10];
    int s = 0;
#pragma unroll
    for (int i = 0; i < 10; i++) {
        int idx = base + i;
        v[i] = (idx < N_NODES) ? deg[idx] : 0;
        s += v[i];
    }
    part[t] = s;
    __syncthreads();
    for (int off = 1; off < 1024; off <<= 1) {
        int x = (t >= off) ? part[t - off] : 0;
        __syncthreads();
        part[t] += x;
        __syncthreads();
    }
    int run = (t == 0) ? 0 : part[t - 1];
#pragma unroll
    for (int i = 0; i < 10; i++) {
        int idx = base + i;
        if (idx < N_NODES) row[idx] = run;
        run += v[i];
    }
    if (t == 1023) row[N_NODES] = part[1023];
}

__global__ void k_fill(const int* __restrict__ src, const int* __restrict__ dst,
                       const int* __restrict__ row, int* __restrict__ cur,
                       int* __restrict__ col) {
    int e = blockIdx.x * blockDim.x + threadIdx.x;
    if (e >= N_EDGES) return;
    int d = dst[e];
    int pos = atomicAdd(&cur[d], 1);
    col[row[d] + pos] = src[e];
}

// ---------- GEMM building blocks (16-node tiles) ----------
__device__ __forceinline__ void stageW256(const float* __restrict__ W, int k0,
                                          float* __restrict__ ws_) {
    int t = threadIdx.x;
    const float4* Wg = (const float4*)(W + (size_t)k0 * 256);
    float4* wl = (float4*)ws_;
#pragma unroll
    for (int i = 0; i < 8; i++) wl[t + i * 256] = Wg[t + i * 256];
}

__device__ __forceinline__ void stageW128(const float* __restrict__ W, int k0,
                                          float* __restrict__ ws_) {
    int t = threadIdx.x;
    const float4* Wg = (const float4*)(W + (size_t)k0 * 128);
    float4* wl = (float4*)ws_;
#pragma unroll
    for (int i = 0; i < 4; i++) wl[t + i * 256] = Wg[t + i * 256];
}

__device__ __forceinline__ void stageA16(const float* __restrict__ A, int nb, int k0,
                                         int kstride, float* __restrict__ as_) {
    int t = threadIdx.x;
    if (t < 128) {
        int r = t >> 3, q = t & 7;
        int n = nb + r;
        float4 v = make_float4(0.f, 0.f, 0.f, 0.f);
        if (n < N_NODES) v = *(const float4*)(A + (size_t)n * kstride + k0 + q * 4);
        *(float4*)(as_ + r * 36 + q * 4) = v;
    }
}

__device__ __forceinline__ void stageA16_ln(const float* __restrict__ x,
                                            const float* __restrict__ sm_mean,
                                            const float* __restrict__ sm_invs,
                                            const float* __restrict__ g0,
                                            const float* __restrict__ b0, int nb, int k0,
                                            float* __restrict__ as_) {
    int t = threadIdx.x;
    if (t < 128) {
        int r = t >> 3, q = t & 7;
        int n = nb + r;
        float4 v = make_float4(0.f, 0.f, 0.f, 0.f);
        if (n < N_NODES) {
            float4 xv = *(const float4*)(x + (size_t)n * DIN + k0 + q * 4);
            float4 gv = *(const float4*)(g0 + k0 + q * 4);
            float4 bv = *(const float4*)(b0 + k0 + q * 4);
            float m = sm_mean[r], is = sm_invs[r];
            v.x = (xv.x - m) * is * gv.x + bv.x;
            v.y = (xv.y - m) * is * gv.y + bv.y;
            v.z = (xv.z - m) * is * gv.z + bv.z;
            v.w = (xv.w - m) * is * gv.w + bv.w;
        }
        *(float4*)(as_ + r * 36 + q * 4) = v;
    }
}

__device__ __forceinline__ void mm256_16(const float* __restrict__ as_,
                                         const float* __restrict__ ws_,
                                         float (&acc)[4][4]) {
    int lane = threadIdx.x & 63, tn = threadIdx.x >> 6;
#pragma unroll
    for (int kk = 0; kk < 32; kk += 4) {
        float xq[4][4];
#pragma unroll
        for (int i = 0; i < 4; i++) {
            float4 v = *(const float4*)(as_ + (tn * 4 + i) * 36 + kk);
            xq[i][0] = v.x; xq[i][1] = v.y; xq[i][2] = v.z; xq[i][3] = v.w;
        }
#pragma unroll
        for (int t = 0; t < 4; t++) {
            const float* wr = ws_ + (kk + t) * 256 + lane;
            float w0 = wr[0], w1 = wr[64], w2 = wr[128], w3 = wr[192];
#pragma unroll
            for (int i = 0; i < 4; i++) {
                float a = xq[i][t];
                acc[i][0] += a * w0; acc[i][1] += a * w1;
                acc[i][2] += a * w2; acc[i][3] += a * w3;
            }
        }
    }
}

__device__ __forceinline__ void mm128_16(const float* __restrict__ as_,
                                         const float* __restrict__ ws_,
                                         float (&acc)[4][2]) {
    int lane = threadIdx.x & 63, tn = threadIdx.x >> 6;
#pragma unroll
    for (int kk = 0; kk < 32; kk += 4) {
        float xq[4][4];
#pragma unroll
        for (int i = 0; i < 4; i++) {
            float4 v = *(const float4*)(as_ + (tn * 4 + i) * 36 + kk);
            xq[i][0] = v.x; xq[i][1] = v.y; xq[i][2] = v.z; xq[i][3] = v.w;
        }
#pragma unroll
        for (int t = 0; t < 4; t++) {
            const float* wr = ws_ + (kk + t) * 128 + lane;
            float w0 = wr[0], w1 = wr[64];
#pragma unroll
            for (int i = 0; i < 4; i++) {
                float a = xq[i][t];
                acc[i][0] += a * w0; acc[i][1] += a * w1;
            }
        }
    }
}

// ---------- kernels ----------

// x_res = LN(gelu(LN_in(x) @ Wp + bp))  [LN stats computed in-kernel]
__global__ __launch_bounds__(256, 4) void k_proj(
        const float* __restrict__ x, const float* __restrict__ g0,
        const float* __restrict__ b0, const float* __restrict__ Wp,
        const float* __restrict__ bp, const float* __restrict__ lg,
        const float* __restrict__ lb, float* __restrict__ xres,
        bf16* __restrict__ xresb) {
    __shared__ float as_[16 * 36];
    __shared__ float ws_[32 * 256];
    __shared__ float sm_mean[16];
    __shared__ float sm_invs[16];
    int nb = blockIdx.x * 16;
    int lane = threadIdx.x & 63, tn = threadIdx.x >> 6;
    // per-node LN stats: wave tn handles nodes tn*4 .. tn*4+3
#pragma unroll
    for (int i = 0; i < 4; i++) {
        int n = nb + tn * 4 + i;
        float s = 0.f, q = 0.f;
        if (n < N_NODES) {
#pragma unroll
            for (int j = 0; j < 8; j++) {
                float v = x[(size_t)n * DIN + lane + j * 64];
                s += v; q += v * v;
            }
        }
        s = wsum64(s); q = wsum64(q);
        float m = s * (1.0f / DIN);
        float var = q * (1.0f / DIN) - m * m;
        if (lane == 0) { sm_mean[tn * 4 + i] = m; sm_invs[tn * 4 + i] = rsqrtf(var + 1e-5f); }
    }
    __syncthreads();
    float acc[4][4] = {};
    for (int k0 = 0; k0 < DIN; k0 += 32) {
        stageA16_ln(x, sm_mean, sm_invs, g0, b0, nb, k0, as_);
        stageW256(Wp, k0, ws_);
        __syncthreads();
        mm256_16(as_, ws_, acc);
        __syncthreads();
    }
    float bp4[4], lg4[4], lb4[4];
#pragma unroll
    for (int j = 0; j < 4; j++) {
        bp4[j] = bp[lane + j * 64];
        lg4[j] = lg[lane + j * 64];
        lb4[j] = lb[lane + j * 64];
    }
#pragma unroll
    for (int i = 0; i < 4; i++) {
        float v[4];
#pragma unroll
        for (int j = 0; j < 4; j++) v[j] = gelu_f(acc[i][j] + bp4[j]);
        float m = wsum64(v[0] + v[1] + v[2] + v[3]) * (1.0f / H);
        float d[4], q = 0.f;
#pragma unroll
        for (int j = 0; j < 4; j++) { d[j] = v[j] - m; q += d[j] * d[j]; }
        float inv = rsqrtf(wsum64(q) * (1.0f / H) + 1e-5f);
        int n = nb + tn * 4 + i;
        if (n < N_NODES) {
#pragma unroll
            for (int j = 0; j < 4; j++) {
                float r = d[j] * inv * lg4[j] + lb4[j];
                xres[(size_t)n * H + lane + j * 64] = r;
                xresb[(size_t)n * H + lane + j * 64] = __float2bfloat16(r);
            }
        }
    }
}

// agg[n] = sum_{s in nbrs(n)} xres[s]   (bf16 source, fp32 accumulate)
__global__ void k_gather(const int* __restrict__ row, const int* __restrict__ col,
                         const bf16* __restrict__ xresb, float* __restrict__ agg) {
    int n = blockIdx.x, tid = threadIdx.x;
    int i = row[n], e0 = row[n + 1];
    float a = 0.f;
    for (; i + 3 < e0; i += 4) {
        int c0 = col[i], c1 = col[i + 1], c2 = col[i + 2], c3 = col[i + 3];
        a += __bfloat162float(xresb[(size_t)c0 * H + tid])
           + __bfloat162float(xresb[(size_t)c1 * H + tid])
           + __bfloat162float(xresb[(size_t)c2 * H + tid])
           + __bfloat162float(xresb[(size_t)c3 * H + tid]);
    }
    for (; i < e0; i++) a += __bfloat162float(xresb[(size_t)col[i] * H + tid]);
    agg[(size_t)n * H + tid] = a;
}

// x1 = LN(gelu(agg@Wrel + brel + xres@Wroot)) + xres
__global__ __launch_bounds__(256, 4) void k_conv(
        const float* __restrict__ agg, const float* __restrict__ xres,
        const float* __restrict__ Wrel, const float* __restrict__ brel,
        const float* __restrict__ Wroot, const float* __restrict__ n1g,
        const float* __restrict__ n1b, float* __restrict__ x1) {
    __shared__ float as_[16 * 36];
    __shared__ float ws_[32 * 256];
    int nb = blockIdx.x * 16;
    float acc[4][4] = {};
    for (int k0 = 0; k0 < H; k0 += 32) {
        stageA16(agg, nb, k0, H, as_);
        stageW256(Wrel, k0, ws_);
        __syncthreads();
        mm256_16(as_, ws_, acc);
        __syncthreads();
    }
    for (int k0 = 0; k0 < H; k0 += 32) {
        stageA16(xres, nb, k0, H, as_);
        stageW256(Wroot, k0, ws_);
        __syncthreads();
        mm256_16(as_, ws_, acc);
        __syncthreads();
    }
    int lane = threadIdx.x & 63, tn = threadIdx.x >> 6;
    float bb[4], gg[4], nb4[4];
#pragma unroll
    for (int j = 0; j < 4; j++) {
        bb[j] = brel[lane + j * 64];
        gg[j] = n1g[lane + j * 64];
        nb4[j] = n1b[lane + j * 64];
    }
#pragma unroll
    for (int i = 0; i < 4; i++) {
        float v[4];
#pragma unroll
        for (int j = 0; j < 4; j++) v[j] = gelu_f(acc[i][j] + bb[j]);
        float m = wsum64(v[0] + v[1] + v[2] + v[3]) * (1.0f / H);
        float d[4], q = 0.f;
#pragma unroll
        for (int j = 0; j < 4; j++) { d[j] = v[j] - m; q += d[j] * d[j]; }
        float inv = rsqrtf(wsum64(q) * (1.0f / H) + 1e-5f);
        int n = nb + tn * 4 + i;
        if (n < N_NODES) {
#pragma unroll
            for (int j = 0; j < 4; j++) {
                size_t idx = (size_t)n * H + lane + j * 64;
                x1[idx] = d[j] * inv * gg[j] + nb4[j] + xres[idx];
            }
        }
    }
}

// xl = x1@Wl + bl ; xr = x1@Wr + br   (bf16 outputs for the gather phase)
__global__ __launch_bounds__(256, 4) void k_lin2(
        const float* __restrict__ x1, const float* __restrict__ Wl,
        const float* __restrict__ bl, const float* __restrict__ Wr,
        const float* __restrict__ br, bf16* __restrict__ xlb,
        bf16* __restrict__ xrb) {
    __shared__ float as_[16 * 36];
    __shared__ float ws_[32 * 256];
    int nb = blockIdx.x * 16;
    float accL[4][4] = {};
    float accR[4][4] = {};
    for (int k0 = 0; k0 < H; k0 += 32) {
        stageA16(x1, nb, k0, H, as_);
        stageW256(Wl, k0, ws_);
        __syncthreads();
        mm256_16(as_, ws_, accL);
        __syncthreads();
        stageW256(Wr, k0, ws_);
        __syncthreads();
        mm256_16(as_, ws_, accR);
        __syncthreads();
    }
    int lane = threadIdx.x & 63, tn = threadIdx.x >> 6;
    float bl4[4], br4[4];
#pragma unroll
    for (int j = 0; j < 4; j++) { bl4[j] = bl[lane + j * 64]; br4[j] = br[lane + j * 64]; }
#pragma unroll
    for (int i = 0; i < 4; i++) {
        int n = nb + tn * 4 + i;
        if (n < N_NODES) {
#pragma unroll
            for (int j = 0; j < 4; j++) {
                xlb[(size_t)n * H + lane + j * 64] = __float2bfloat16(accL[i][j] + bl4[j]);
                xrb[(size_t)n * H + lane + j * 64] = __float2bfloat16(accR[i][j] + br4[j]);
            }
        }
    }
}

// fused GATv2 + x2 epilogue; bf16 xl/xr, fp32 math
__global__ __launch_bounds__(256, 8) void k_gat(
        const int* __restrict__ row, const int* __restrict__ col,
        const bf16* __restrict__ xl, const bf16* __restrict__ xr,
        const float* __restrict__ att, const float* __restrict__ gatb,
        const float* __restrict__ n2g, const float* __restrict__ n2b,
        const float* __restrict__ x1, float* __restrict__ x2) {
    __shared__ float red[8];
    int n = blockIdx.x;
    int off = threadIdx.x;           // h*64 + lane
    float attv = att[off];
    float xrd = __bfloat162float(xr[(size_t)n * H + off]);
    float v0 = __bfloat162float(xl[(size_t)n * H + off]);
    float a0 = v0 + xrd; a0 = (a0 > 0.f) ? a0 : 0.2f * a0;
    float m = wsum64(a0 * attv);
    float l = 1.f, acc = v0;
    int i = row[n], end = row[n + 1];
    for (; i + 3 < end; i += 4) {
        int s0 = col[i], s1 = col[i + 1], s2 = col[i + 2], s3 = col[i + 3];
        float w0 = __bfloat162float(xl[(size_t)s0 * H + off]);
        float w1 = __bfloat162float(xl[(size_t)s1 * H + off]);
        float w2 = __bfloat162float(xl[(size_t)s2 * H + off]);
        float w3 = __bfloat162float(xl[(size_t)s3 * H + off]);
        float b0 = w0 + xrd; b0 = (b0 > 0.f) ? b0 : 0.2f * b0;
        float b1 = w1 + xrd; b1 = (b1 > 0.f) ? b1 : 0.2f * b1;
        float b2 = w2 + xrd; b2 = (b2 > 0.f) ? b2 : 0.2f * b2;
        float b3 = w3 + xrd; b3 = (b3 > 0.f) ? b3 : 0.2f * b3;
        b0 *= attv; b1 *= attv; b2 *= attv; b3 *= attv;
#pragma unroll
        for (int o = 32; o > 0; o >>= 1) {
            b0 += __shfl_xor(b0, o, 64);
            b1 += __shfl_xor(b1, o, 64);
            b2 += __shfl_xor(b2, o, 64);
            b3 += __shfl_xor(b3, o, 64);
        }
        float nm, sc, p;
        nm = fmaxf(m, b0); sc = __expf(m - nm); p = __expf(b0 - nm);
        l = l * sc + p; acc = acc * sc + p * w0; m = nm;
        nm = fmaxf(m, b1); sc = __expf(m - nm); p = __expf(b1 - nm);
        l = l * sc + p; acc = acc * sc + p * w1; m = nm;
        nm = fmaxf(m, b2); sc = __expf(m - nm); p = __expf(b2 - nm);
        l = l * sc + p; acc = acc * sc + p * w2; m = nm;
        nm = fmaxf(m, b3); sc = __expf(m - nm); p = __expf(b3 - nm);
        l = l * sc + p; acc = acc * sc + p * w3; m = nm;
    }
    for (; i < end; i++) {
        int s = col[i];
        float w = __bfloat162float(xl[(size_t)s * H + off]);
        float b = w + xrd; b = (b > 0.f) ? b : 0.2f * b;
        b *= attv;
#pragma unroll
        for (int o = 32; o > 0; o >>= 1) b += __shfl_xor(b, o, 64);
        float nm = fmaxf(m, b);
        float sc = __expf(m - nm);
        float p = __expf(b - nm);
        l = l * sc + p; acc = acc * sc + p * w; m = nm;
    }
    float msg = acc / l;
    float p = gelu_f(msg + gatb[off]);
    float sm = blk_sum(p, red) * (1.0f / H);
    float dd = p - sm;
    float vv = blk_sum(dd * dd, red) * (1.0f / H);
    float inv = rsqrtf(vv + 1e-5f);
    x2[(size_t)n * H + off] = dd * inv * n2g[off] + n2b[off] + x1[(size_t)n * H + off];
}

// gates
__global__ __launch_bounds__(256, 4) void k_gates(
        const float* __restrict__ x2, const float* __restrict__ Wg1a,
        const float* __restrict__ bg1a, const float* __restrict__ Wg1b,
        const float* __restrict__ bg1b, const float* __restrict__ Wg2a,
        const float* __restrict__ bg2a, const float* __restrict__ Wg2b,
        const float* __restrict__ bg2b, float* __restrict__ gate1,
        float* __restrict__ gate2) {
    __shared__ float as_[16 * 36];
    __shared__ float ws_[32 * 256];
    int nb = blockIdx.x * 16;
    float acc2[4][4] = {};
    float acc1[4][2] = {};
    for (int k0 = 0; k0 < H; k0 += 32) {
        stageA16(x2, nb, k0, H, as_);
        stageW256(Wg2a, k0, ws_);
        __syncthreads();
        mm256_16(as_, ws_, acc2);
        __syncthreads();
        stageW128(Wg1a, k0, ws_);
        __syncthreads();
        mm128_16(as_, ws_, acc1);
        __syncthreads();
    }
    int lane = threadIdx.x & 63, tn = threadIdx.x >> 6;
    float wb2[4], b2[4], wb1[2], b1[2];
#pragma unroll
    for (int j = 0; j < 4; j++) { wb2[j] = Wg2b[lane + j * 64]; b2[j] = bg2a[lane + j * 64]; }
#pragma unroll
    for (int j = 0; j < 2; j++) { wb1[j] = Wg1b[lane + j * 64]; b1[j] = bg1a[lane + j * 64]; }
    float c2 = bg2b[0], c1 = bg1b[0];
#pragma unroll
    for (int i = 0; i < 4; i++) {
        float s2 = 0.f;
#pragma unroll
        for (int j = 0; j < 4; j++) s2 += tanhf(acc2[i][j] + b2[j]) * wb2[j];
        s2 = wsum64(s2);
        float s1 = 0.f;
#pragma unroll
        for (int j = 0; j < 2; j++) s1 += tanhf(acc1[i][j] + b1[j]) * wb1[j];
        s1 = wsum64(s1);
        int n = nb + tn * 4 + i;
        if (lane == 0 && n < N_NODES) { gate2[n] = s2 + c2; gate1[n] = s1 + c1; }
    }
}

// per-group pooling, 4 blocks per group, partial sums via atomics
__global__ void k_group(const int* __restrict__ batch, const float* __restrict__ x2,
                        const float* __restrict__ xres, const float* __restrict__ g1,
                        const float* __restrict__ g2, float* __restrict__ gs1,
                        float* __restrict__ gs2, float* __restrict__ fin) {
    __shared__ float red[8];
    __shared__ int seb[2];
    int g = blockIdx.x >> 2, part = blockIdx.x & 3;
    int tid = threadIdx.x;
    if (tid == 0) {
        seb[0] = lowerb(batch, N_NODES, g);
        seb[1] = lowerb(batch, N_NODES, g + 1);
    }
    __syncthreads();
    int s = seb[0], e = seb[1];
    if (e <= s) return;
    float m1 = -3.4e38f, m2 = -3.4e38f;
    for (int i = s + tid; i < e; i += 256) {
        m1 = fmaxf(m1, g1[i]);
        m2 = fmaxf(m2, g2[i]);
    }
    m1 = blk_max(m1, red);
    m2 = blk_max(m2, red);
    int deg = e - s;
    int q0 = s + deg * part / 4, q1 = s + deg * (part + 1) / 4;
    float s1 = 0.f, s2 = 0.f, e1 = 0.f, e2 = 0.f, gr = 0.f;
    for (int i = q0; i < q1; i++) {
        float w1 = __expf(g1[i] - m1);
        float w2 = __expf(g2[i] - m2);
        float xv = x2[(size_t)i * H + tid];
        float rv = xres[(size_t)i * H + tid];
        s1 += w1; s2 += w2;
        e1 += w1 * xv; e2 += w2 * xv; gr += rv;
    }
    if (q1 > q0) {
        atomicAdd(&fin[(size_t)g * 768 + tid], e1);
        atomicAdd(&fin[(size_t)g * 768 + 256 + tid], e2);
        atomicAdd(&fin[(size_t)g * 768 + 512 + tid], gr);
        if (tid == 0) { atomicAdd(&gs1[g], s1); atomicAdd(&gs2[g], s2); }
    }
}

// out = gelu([emb1|emb2|gres] @ Wo + bo) / sqrt(1+1e-5) * bn_g + bn_b
__global__ void k_final(const int* __restrict__ batch, const float* __restrict__ fin,
                        const float* __restrict__ gs1, const float* __restrict__ gs2,
                        const float* __restrict__ Wo, const float* __restrict__ bo,
                        const float* __restrict__ bng, const float* __restrict__ bnb,
                        float* __restrict__ out) {
    __shared__ float fl[768];
    __shared__ int seb[2];
    int g = blockIdx.x, tid = threadIdx.x;
    if (tid == 0) {
        seb[0] = lowerb(batch, N_NODES, g);
        seb[1] = lowerb(batch, N_NODES, g + 1);
    }
    __syncthreads();
    float c = fmaxf((float)(seb[1] - seb[0]), 1.0f);
    float s1 = gs1[g], s2 = gs2[g];
    fl[tid]       = (s1 > 0.f) ? fin[(size_t)g * 768 + tid] / s1 : 0.f;
    fl[256 + tid] = (s2 > 0.f) ? fin[(size_t)g * 768 + 256 + tid] / s2 : 0.f;
    fl[512 + tid] = fin[(size_t)g * 768 + 512 + tid] / c;
    __syncthreads();
#pragma unroll
    for (int half = 0; half < 2; half++) {
        int o = tid + half * 256;
        float acc = bo[o];
#pragma unroll 8
        for (int k = 0; k < 768; k++) acc += fl[k] * Wo[(size_t)k * OUT_DIM + o];
        float val = gelu_f(acc);
        out[(size_t)g * OUT_DIM + o] = val * 0.9999950000374997f * bng[o] + bnb[o];
    }
}

extern "C" void kernel_launch(void* const* d_in, const int* in_sizes, int n_in,
                              void* d_out, int out_size, void* d_ws, size_t ws_size,
                              hipStream_t stream) {
    const float* x     = (const float*)d_in[0];
    const int*   ei    = (const int*)d_in[1];
    const int*   batch = (const int*)d_in[2];
    const float* ln_in_g = (const float*)d_in[3];
    const float* ln_in_b = (const float*)d_in[4];
    const float* Wp    = (const float*)d_in[5];
    const float* bp    = (const float*)d_in[6];
    const float* lnp_g = (const float*)d_in[7];
    const float* lnp_b = (const float*)d_in[8];
    const float* Wrel  = (const float*)d_in[9];
    const float* brel  = (const float*)d_in[10];
    const float* Wroot = (const float*)d_in[11];
    const float* n1_g  = (const float*)d_in[12];
    const float* n1_b  = (const float*)d_in[13];
    const float* Wl    = (const float*)d_in[14];
    const float* bl    = (const float*)d_in[15];
    const float* Wr    = (const float*)d_in[16];
    const float* br    = (const float*)d_in[17];
    const float* att   = (const float*)d_in[18];
    const float* gat_b = (const float*)d_in[19];
    const float* n2_g  = (const float*)d_in[20];
    const float* n2_b  = (const float*)d_in[21];
    const float* Wg1a  = (const float*)d_in[22];
    const float* bg1a  = (const float*)d_in[23];
    const float* Wg1b  = (const float*)d_in[24];
    const float* bg1b  = (const float*)d_in[25];
    const float* Wg2a  = (const float*)d_in[26];
    const float* bg2a  = (const float*)d_in[27];
    const float* Wg2b  = (const float*)d_in[28];
    const float* bg2b  = (const float*)d_in[29];
    const float* Wo    = (const float*)d_in[30];
    const float* bo    = (const float*)d_in[31];
    const float* bn_g  = (const float*)d_in[32];
    const float* bn_b  = (const float*)d_in[33];

    float* ws = (float*)d_ws;
    int* wsi = (int*)d_ws;
    const int* src = ei;
    const int* dst = ei + N_EDGES;
    int* cur = wsi + IOFF_CUR;
    int* row = wsi + IOFF_ROW;
    int* col = wsi + IOFF_COL;
    bf16* xlb   = (bf16*)(ws + OFF_XLB);
    bf16* xrb   = (bf16*)(ws + OFF_XRB);
    bf16* xresb = (bf16*)(ws + OFF_XRESB);
    const int GB = (N_NODES + 15) / 16;  // 625

    // ---- CSR build ----
    hipMemsetAsync(cur, 0, N_NODES * sizeof(int), stream);
    hipMemsetAsync(ws + OFF_GS1, 0, (128 + (size_t)NG * 768) * sizeof(float), stream);
    k_count<<<(N_EDGES + 255) / 256, 256, 0, stream>>>(dst, cur);
    k_scan<<<1, 1024, 0, stream>>>(cur, row);
    hipMemsetAsync(cur, 0, N_NODES * sizeof(int), stream);
    k_fill<<<(N_EDGES + 255) / 256, 256, 0, stream>>>(src, dst, row, cur, col);

    k_proj<<<GB, 256, 0, stream>>>(x, ln_in_g, ln_in_b, Wp, bp, lnp_g, lnp_b,
                                   ws + OFF_XRES, xresb);
    k_gather<<<N_NODES, 256, 0, stream>>>(row, col, xresb, ws + OFF_AGG);
    k_conv<<<GB, 256, 0, stream>>>(ws + OFF_AGG, ws + OFF_XRES, Wrel, brel, Wroot,
                                   n1_g, n1_b, ws + OFF_X1);
    k_lin2<<<GB, 256, 0, stream>>>(ws + OFF_X1, Wl, bl, Wr, br, xlb, xrb);
    k_gat<<<N_NODES, 256, 0, stream>>>(row, col, xlb, xrb, att, gat_b, n2_g, n2_b,
                                       ws + OFF_X1, ws + OFF_AGG);
    k_gates<<<GB, 256, 0, stream>>>(ws + OFF_AGG, Wg1a, bg1a, Wg1b, bg1b, Wg2a, bg2a,
                                    Wg2b, bg2b, ws + OFF_G1, ws + OFF_G2);
    k_group<<<NG * 4, 256, 0, stream>>>(batch, ws + OFF_AGG, ws + OFF_XRES,
                                        ws + OFF_G1, ws + OFF_G2, ws + OFF_GS1,
                                        ws + OFF_GS2, ws + OFF_FIN);
    k_final<<<NG, 256, 0, stream>>>(batch, ws + OFF_FIN, ws + OFF_GS1, ws + OFF_GS2,
                                    Wo, bo, bn_g, bn_b, (float*)d_out);
}

// Round 7
// 638.077 us; speedup vs baseline: 2.5916x; 1.0010x over previous
//
#include <hip/hip_runtime.h>
#include <hip/hip_bf16.h>

#define N_NODES 10000
#define N_EDGES 320000
#define DIN 512
#define H 256
#define NHEADS 4
#define DH 64
#define NG 64
#define OUT_DIM 512

typedef __hip_bfloat16 bf16;

// ---------- workspace layout (float offsets) ----------
static const size_t OFF_XRES  = 0;           // N*H fp32
static const size_t OFF_AGG   = 2560000;     // N*H fp32 (agg, later reused as x2)
static const size_t OFF_X1    = 5120000;     // N*H fp32
static const size_t OFF_XLB   = 7680000;     // N*H bf16 (1.28M floats)
static const size_t OFF_XRB   = 8960000;     // N*H bf16
static const size_t OFF_XRESB = 10240000;    // N*H bf16
static const size_t OFF_G1    = 11520000;    // N
static const size_t OFF_G2    = 11530000;    // N
static const size_t OFF_GS1   = 11540000;    // 64
static const size_t OFF_GS2   = 11540064;    // 64
static const size_t OFF_FIN   = 11540128;    // G*768
// int region (int offsets into (int*)ws)
static const size_t IOFF_CUR  = 11600000;    // N ints
static const size_t IOFF_ROW  = 11610016;    // N+1 ints
static const size_t IOFF_COL  = 11620032;    // E ints

__device__ __forceinline__ float gelu_f(float x) {
    return 0.5f * x * (1.0f + erff(x * 0.70710678118654752440f));
}

__device__ __forceinline__ float wsum64(float v) {
#pragma unroll
    for (int o = 32; o > 0; o >>= 1) v += __shfl_xor(v, o, 64);
    return v;
}

__device__ __forceinline__ float blk_sum(float v, float* s) {
#pragma unroll
    for (int o = 32; o > 0; o >>= 1) v += __shfl_xor(v, o, 64);
    int lane = threadIdx.x & 63, w = threadIdx.x >> 6;
    __syncthreads();
    if (lane == 0) s[w] = v;
    __syncthreads();
    float t = 0.f;
    int nw = blockDim.x >> 6;
    for (int i = 0; i < nw; i++) t += s[i];
    return t;
}

__device__ __forceinline__ float blk_max(float v, float* s) {
#pragma unroll
    for (int o = 32; o > 0; o >>= 1) v = fmaxf(v, __shfl_xor(v, o, 64));
    int lane = threadIdx.x & 63, w = threadIdx.x >> 6;
    __syncthreads();
    if (lane == 0) s[w] = v;
    __syncthreads();
    float t = s[0];
    int nw = blockDim.x >> 6;
    for (int i = 1; i < nw; i++) t = fmaxf(t, s[i]);
    return t;
}

__device__ __forceinline__ int lowerb(const int* b, int n, int v) {
    int lo = 0, hi = n;
    while (lo < hi) { int mid = (lo + hi) >> 1; if (b[mid] < v) lo = mid + 1; else hi = mid; }
    return lo;
}

// ---------- CSR build (by dst) ----------
__global__ void k_count(const int* __restrict__ dst, int* __restrict__ deg) {
    int e = blockIdx.x * blockDim.x + threadIdx.x;
    if (e < N_EDGES) atomicAdd(&deg[dst[e]], 1);
}

__global__ void k_scan(const int* __restrict__ deg, int* __restrict__ row) {
    __shared__ int part[1024];
    int t = threadIdx.x;
    int base = t * 10;
    int v[10];
    int s = 0;
#pragma unroll
    for (int i = 0; i < 10; i++) {
        int idx = base + i;
        v[i] = (idx < N_NODES) ? deg[idx] : 0;
        s += v[i];
    }
    part[t] = s;
    __syncthreads();
    for (int off = 1; off < 1024; off <<= 1) {
        int x = (t >= off) ? part[t - off] : 0;
        __syncthreads();
        part[t] += x;
        __syncthreads();
    }
    int run = (t == 0) ? 0 : part[t - 1];
#pragma unroll
    for (int i = 0; i < 10; i++) {
        int idx = base + i;
        if (idx < N_NODES) row[idx] = run;
        run += v[i];
    }
    if (t == 1023) row[N_NODES] = part[1023];
}

__global__ void k_fill(const int* __restrict__ src, const int* __restrict__ dst,
                       const int* __restrict__ row, int* __restrict__ cur,
                       int* __restrict__ col) {
    int e = blockIdx.x * blockDim.x + threadIdx.x;
    if (e >= N_EDGES) return;
    int d = dst[e];
    int pos = atomicAdd(&cur[d], 1);
    col[row[d] + pos] = src[e];
}

// ---------- GEMM building blocks (16-node tiles) ----------
__device__ __forceinline__ void stageW256(const float* __restrict__ W, int k0,
                                          float* __restrict__ ws_) {
    int t = threadIdx.x;
    const float4* Wg = (const float4*)(W + (size_t)k0 * 256);
    float4* wl = (float4*)ws_;
#pragma unroll
    for (int i = 0; i < 8; i++) wl[t + i * 256] = Wg[t + i * 256];
}

__device__ __forceinline__ void stageW128(const float* __restrict__ W, int k0,
                                          float* __restrict__ ws_) {
    int t = threadIdx.x;
    const float4* Wg = (const float4*)(W + (size_t)k0 * 128);
    float4* wl = (float4*)ws_;
#pragma unroll
    for (int i = 0; i < 4; i++) wl[t + i * 256] = Wg[t + i * 256];
}

__device__ __forceinline__ void stageA16(const float* __restrict__ A, int nb, int k0,
                                         int kstride, float* __restrict__ as_) {
    int t = threadIdx.x;
    if (t < 128) {
        int r = t >> 3, q = t & 7;
        int n = nb + r;
        float4 v = make_float4(0.f, 0.f, 0.f, 0.f);
        if (n < N_NODES) v = *(const float4*)(A + (size_t)n * kstride + k0 + q * 4);
        *(float4*)(as_ + r * 36 + q * 4) = v;
    }
}

__device__ __forceinline__ void stageA16_ln(const float* __restrict__ x,
                                            const float* __restrict__ sm_mean,
                                            const float* __restrict__ sm_invs,
                                            const float* __restrict__ g0,
                                            const float* __restrict__ b0, int nb, int k0,
                                            float* __restrict__ as_) {
    int t = threadIdx.x;
    if (t < 128) {
        int r = t >> 3, q = t & 7;
        int n = nb + r;
        float4 v = make_float4(0.f, 0.f, 0.f, 0.f);
        if (n < N_NODES) {
            float4 xv = *(const float4*)(x + (size_t)n * DIN + k0 + q * 4);
            float4 gv = *(const float4*)(g0 + k0 + q * 4);
            float4 bv = *(const float4*)(b0 + k0 + q * 4);
            float m = sm_mean[r], is = sm_invs[r];
            v.x = (xv.x - m) * is * gv.x + bv.x;
            v.y = (xv.y - m) * is * gv.y + bv.y;
            v.z = (xv.z - m) * is * gv.z + bv.z;
            v.w = (xv.w - m) * is * gv.w + bv.w;
        }
        *(float4*)(as_ + r * 36 + q * 4) = v;
    }
}

__device__ __forceinline__ void mm256_16(const float* __restrict__ as_,
                                         const float* __restrict__ ws_,
                                         float (&acc)[4][4]) {
    int lane = threadIdx.x & 63, tn = threadIdx.x >> 6;
#pragma unroll
    for (int kk = 0; kk < 32; kk += 4) {
        float xq[4][4];
#pragma unroll
        for (int i = 0; i < 4; i++) {
            float4 v = *(const float4*)(as_ + (tn * 4 + i) * 36 + kk);
            xq[i][0] = v.x; xq[i][1] = v.y; xq[i][2] = v.z; xq[i][3] = v.w;
        }
#pragma unroll
        for (int t = 0; t < 4; t++) {
            const float* wr = ws_ + (kk + t) * 256 + lane;
            float w0 = wr[0], w1 = wr[64], w2 = wr[128], w3 = wr[192];
#pragma unroll
            for (int i = 0; i < 4; i++) {
                float a = xq[i][t];
                acc[i][0] += a * w0; acc[i][1] += a * w1;
                acc[i][2] += a * w2; acc[i][3] += a * w3;
            }
        }
    }
}

__device__ __forceinline__ void mm128_16(const float* __restrict__ as_,
                                         const float* __restrict__ ws_,
                                         float (&acc)[4][2]) {
    int lane = threadIdx.x & 63, tn = threadIdx.x >> 6;
#pragma unroll
    for (int kk = 0; kk < 32; kk += 4) {
        float xq[4][4];
#pragma unroll
        for (int i = 0; i < 4; i++) {
            float4 v = *(const float4*)(as_ + (tn * 4 + i) * 36 + kk);
            xq[i][0] = v.x; xq[i][1] = v.y; xq[i][2] = v.z; xq[i][3] = v.w;
        }
#pragma unroll
        for (int t = 0; t < 4; t++) {
            const float* wr = ws_ + (kk + t) * 128 + lane;
            float w0 = wr[0], w1 = wr[64];
#pragma unroll
            for (int i = 0; i < 4; i++) {
                float a = xq[i][t];
                acc[i][0] += a * w0; acc[i][1] += a * w1;
            }
        }
    }
}

// ---------- kernels ----------

// x_res = LN(gelu(LN_in(x) @ Wp + bp))  [LN stats computed in-kernel]
__global__ __launch_bounds__(256, 4) void k_proj(
        const float* __restrict__ x, const float* __restrict__ g0,
        const float* __restrict__ b0, const float* __restrict__ Wp,
        const float* __restrict__ bp, const float* __restrict__ lg,
        const float* __restrict__ lb, float* __restrict__ xres,
        bf16* __restrict__ xresb) {
    __shared__ float as_[16 * 36];
    __shared__ float ws_[32 * 256];
    __shared__ float sm_mean[16];
    __shared__ float sm_invs[16];
    int nb = blockIdx.x * 16;
    int lane = threadIdx.x & 63, tn = threadIdx.x >> 6;
#pragma unroll
    for (int i = 0; i < 4; i++) {
        int n = nb + tn * 4 + i;
        float s = 0.f, q = 0.f;
        if (n < N_NODES) {
#pragma unroll
            for (int j = 0; j < 8; j++) {
                float v = x[(size_t)n * DIN + lane + j * 64];
                s += v; q += v * v;
            }
        }
        s = wsum64(s); q = wsum64(q);
        float m = s * (1.0f / DIN);
        float var = q * (1.0f / DIN) - m * m;
        if (lane == 0) { sm_mean[tn * 4 + i] = m; sm_invs[tn * 4 + i] = rsqrtf(var + 1e-5f); }
    }
    __syncthreads();
    float acc[4][4] = {};
    for (int k0 = 0; k0 < DIN; k0 += 32) {
        stageA16_ln(x, sm_mean, sm_invs, g0, b0, nb, k0, as_);
        stageW256(Wp, k0, ws_);
        __syncthreads();
        mm256_16(as_, ws_, acc);
        __syncthreads();
    }
    float bp4[4], lg4[4], lb4[4];
#pragma unroll
    for (int j = 0; j < 4; j++) {
        bp4[j] = bp[lane + j * 64];
        lg4[j] = lg[lane + j * 64];
        lb4[j] = lb[lane + j * 64];
    }
#pragma unroll
    for (int i = 0; i < 4; i++) {
        float v[4];
#pragma unroll
        for (int j = 0; j < 4; j++) v[j] = gelu_f(acc[i][j] + bp4[j]);
        float m = wsum64(v[0] + v[1] + v[2] + v[3]) * (1.0f / H);
        float d[4], q = 0.f;
#pragma unroll
        for (int j = 0; j < 4; j++) { d[j] = v[j] - m; q += d[j] * d[j]; }
        float inv = rsqrtf(wsum64(q) * (1.0f / H) + 1e-5f);
        int n = nb + tn * 4 + i;
        if (n < N_NODES) {
#pragma unroll
            for (int j = 0; j < 4; j++) {
                float r = d[j] * inv * lg4[j] + lb4[j];
                xres[(size_t)n * H + lane + j * 64] = r;
                xresb[(size_t)n * H + lane + j * 64] = __float2bfloat16(r);
            }
        }
    }
}

// agg[n] = sum_{s in nbrs(n)} xres[s]   (bf16 source, fp32 accumulate, x8 unroll)
__global__ void k_gather(const int* __restrict__ row, const int* __restrict__ col,
                         const bf16* __restrict__ xresb, float* __restrict__ agg) {
    int n = blockIdx.x, tid = threadIdx.x;
    int i = row[n], e0 = row[n + 1];
    float a = 0.f;
    for (; i + 7 < e0; i += 8) {
        int c0 = col[i], c1 = col[i + 1], c2 = col[i + 2], c3 = col[i + 3];
        int c4 = col[i + 4], c5 = col[i + 5], c6 = col[i + 6], c7 = col[i + 7];
        a += __bfloat162float(xresb[(size_t)c0 * H + tid])
           + __bfloat162float(xresb[(size_t)c1 * H + tid])
           + __bfloat162float(xresb[(size_t)c2 * H + tid])
           + __bfloat162float(xresb[(size_t)c3 * H + tid])
           + __bfloat162float(xresb[(size_t)c4 * H + tid])
           + __bfloat162float(xresb[(size_t)c5 * H + tid])
           + __bfloat162float(xresb[(size_t)c6 * H + tid])
           + __bfloat162float(xresb[(size_t)c7 * H + tid]);
    }
    for (; i < e0; i++) a += __bfloat162float(xresb[(size_t)col[i] * H + tid]);
    agg[(size_t)n * H + tid] = a;
}

// x1 = LN(gelu(agg@Wrel + brel + xres@Wroot)) + xres
__global__ __launch_bounds__(256, 4) void k_conv(
        const float* __restrict__ agg, const float* __restrict__ xres,
        const float* __restrict__ Wrel, const float* __restrict__ brel,
        const float* __restrict__ Wroot, const float* __restrict__ n1g,
        const float* __restrict__ n1b, float* __restrict__ x1) {
    __shared__ float as_[16 * 36];
    __shared__ float ws_[32 * 256];
    int nb = blockIdx.x * 16;
    float acc[4][4] = {};
    for (int k0 = 0; k0 < H; k0 += 32) {
        stageA16(agg, nb, k0, H, as_);
        stageW256(Wrel, k0, ws_);
        __syncthreads();
        mm256_16(as_, ws_, acc);
        __syncthreads();
    }
    for (int k0 = 0; k0 < H; k0 += 32) {
        stageA16(xres, nb, k0, H, as_);
        stageW256(Wroot, k0, ws_);
        __syncthreads();
        mm256_16(as_, ws_, acc);
        __syncthreads();
    }
    int lane = threadIdx.x & 63, tn = threadIdx.x >> 6;
    float bb[4], gg[4], nb4[4];
#pragma unroll
    for (int j = 0; j < 4; j++) {
        bb[j] = brel[lane + j * 64];
        gg[j] = n1g[lane + j * 64];
        nb4[j] = n1b[lane + j * 64];
    }
#pragma unroll
    for (int i = 0; i < 4; i++) {
        float v[4];
#pragma unroll
        for (int j = 0; j < 4; j++) v[j] = gelu_f(acc[i][j] + bb[j]);
        float m = wsum64(v[0] + v[1] + v[2] + v[3]) * (1.0f / H);
        float d[4], q = 0.f;
#pragma unroll
        for (int j = 0; j < 4; j++) { d[j] = v[j] - m; q += d[j] * d[j]; }
        float inv = rsqrtf(wsum64(q) * (1.0f / H) + 1e-5f);
        int n = nb + tn * 4 + i;
        if (n < N_NODES) {
#pragma unroll
            for (int j = 0; j < 4; j++) {
                size_t idx = (size_t)n * H + lane + j * 64;
                x1[idx] = d[j] * inv * gg[j] + nb4[j] + xres[idx];
            }
        }
    }
}

// xl = x1@Wl + bl ; xr = x1@Wr + br   (bf16 outputs for the gather phase)
__global__ __launch_bounds__(256, 4) void k_lin2(
        const float* __restrict__ x1, const float* __restrict__ Wl,
        const float* __restrict__ bl, const float* __restrict__ Wr,
        const float* __restrict__ br, bf16* __restrict__ xlb,
        bf16* __restrict__ xrb) {
    __shared__ float as_[16 * 36];
    __shared__ float ws_[32 * 256];
    int nb = blockIdx.x * 16;
    float accL[4][4] = {};
    float accR[4][4] = {};
    for (int k0 = 0; k0 < H; k0 += 32) {
        stageA16(x1, nb, k0, H, as_);
        stageW256(Wl, k0, ws_);
        __syncthreads();
        mm256_16(as_, ws_, accL);
        __syncthreads();
        stageW256(Wr, k0, ws_);
        __syncthreads();
        mm256_16(as_, ws_, accR);
        __syncthreads();
    }
    int lane = threadIdx.x & 63, tn = threadIdx.x >> 6;
    float bl4[4], br4[4];
#pragma unroll
    for (int j = 0; j < 4; j++) { bl4[j] = bl[lane + j * 64]; br4[j] = br[lane + j * 64]; }
#pragma unroll
    for (int i = 0; i < 4; i++) {
        int n = nb + tn * 4 + i;
        if (n < N_NODES) {
#pragma unroll
            for (int j = 0; j < 4; j++) {
                xlb[(size_t)n * H + lane + j * 64] = __float2bfloat16(accL[i][j] + bl4[j]);
                xrb[(size_t)n * H + lane + j * 64] = __float2bfloat16(accR[i][j] + br4[j]);
            }
        }
    }
}

// fused GATv2 + x2 epilogue — two-pass chunked softmax, no per-edge 64-lane reduce.
// Block = node; wave = head. Pass1: lane=(edge,dchunk) computes logits (2-shfl
// reduce) into wave-private LDS. Pass2: lane=dim accumulates alpha-weighted xl.
__global__ __launch_bounds__(256, 6) void k_gat(
        const int* __restrict__ row, const int* __restrict__ col,
        const bf16* __restrict__ xl, const bf16* __restrict__ xr,
        const float* __restrict__ att, const float* __restrict__ gatb,
        const float* __restrict__ n2g, const float* __restrict__ n2b,
        const float* __restrict__ x1, float* __restrict__ x2) {
    __shared__ float slog[NHEADS * 128];
    __shared__ float red[8];
    int n = blockIdx.x;
    int tid = threadIdx.x;
    int h = tid >> 6, lane = tid & 63;
    int dc = lane & 3;
    // pass1 per-lane constants: 16 dims of xr[n] and att for this head
    float xr16[16], att16[16];
    {
        const bf16* xrrow = xr + (size_t)n * H + h * DH + dc * 16;
        const float* attrow = att + h * DH + dc * 16;
#pragma unroll
        for (int j = 0; j < 16; j++) {
            xr16[j] = __bfloat162float(xrrow[j]);
            att16[j] = attrow[j];
        }
    }
    int rs = row[n];
    int ec = row[n + 1] - rs + 1;   // extended: index 0 = self-loop
    float m = -3.4e38f, l = 0.f, acc = 0.f;
    float* myslog = slog + h * 128;
    for (int c0 = 0; c0 < ec; c0 += 128) {
        int cnt = min(128, ec - c0);
        // ---- pass 1: chunk logits ----
        for (int base = 0; base < cnt; base += 16) {
            int ei = base + (lane >> 2);
            bool valid = ei < cnt;
            int g = c0 + ei;
            int s = (valid && g > 0) ? col[rs + g - 1] : n;
            const unsigned* xlr = (const unsigned*)(xl + (size_t)s * H + h * DH + dc * 16);
            float p = 0.f;
#pragma unroll
            for (int jj = 0; jj < 8; jj++) {
                unsigned u = xlr[jj];
                float v0 = __uint_as_float((u & 0xffffu) << 16);
                float v1 = __uint_as_float(u & 0xffff0000u);
                float a0 = v0 + xr16[2 * jj];
                float a1 = v1 + xr16[2 * jj + 1];
                a0 = (a0 > 0.f) ? a0 : 0.2f * a0;
                a1 = (a1 > 0.f) ? a1 : 0.2f * a1;
                p += a0 * att16[2 * jj] + a1 * att16[2 * jj + 1];
            }
            p += __shfl_xor(p, 1, 64);
            p += __shfl_xor(p, 2, 64);
            if (valid && dc == 0) myslog[ei] = p;
        }
        // ---- chunk max (wave-local) ----
        float cm = -3.4e38f;
        for (int i = lane; i < cnt; i += 64) cm = fmaxf(cm, myslog[i]);
#pragma unroll
        for (int o = 32; o > 0; o >>= 1) cm = fmaxf(cm, __shfl_xor(cm, o, 64));
        float nm = fmaxf(m, cm);
        float sc = __expf(m - nm);
        l *= sc; acc *= sc; m = nm;
        // ---- pass 2: alpha-weighted accumulation (lane = dim) ----
        for (int i = 0; i < cnt; i += 4) {
#pragma unroll
            for (int k = 0; k < 4; k++) {
                int gi = i + k;
                if (gi < cnt) {
                    float a = __expf(myslog[gi] - m);
                    int g = c0 + gi;
                    int s = (g > 0) ? col[rs + g - 1] : n;
                    float w = __bfloat162float(xl[(size_t)s * H + h * DH + lane]);
                    l += a;
                    acc += a * w;
                }
            }
        }
    }
    // ---- fused x2 epilogue: LN(gelu(msg + gatb)) + x1 ----
    float msg = acc / l;
    int off = tid;
    float p = gelu_f(msg + gatb[off]);
    float sm = blk_sum(p, red) * (1.0f / H);
    float dd = p - sm;
    float vv = blk_sum(dd * dd, red) * (1.0f / H);
    float inv = rsqrtf(vv + 1e-5f);
    x2[(size_t)n * H + off] = dd * inv * n2g[off] + n2b[off] + x1[(size_t)n * H + off];
}

// gates
__global__ __launch_bounds__(256, 4) void k_gates(
        const float* __restrict__ x2, const float* __restrict__ Wg1a,
        const float* __restrict__ bg1a, const float* __restrict__ Wg1b,
        const float* __restrict__ bg1b, const float* __restrict__ Wg2a,
        const float* __restrict__ bg2a, const float* __restrict__ Wg2b,
        const float* __restrict__ bg2b, float* __restrict__ gate1,
        float* __restrict__ gate2) {
    __shared__ float as_[16 * 36];
    __shared__ float ws_[32 * 256];
    int nb = blockIdx.x * 16;
    float acc2[4][4] = {};
    float acc1[4][2] = {};
    for (int k0 = 0; k0 < H; k0 += 32) {
        stageA16(x2, nb, k0, H, as_);
        stageW256(Wg2a, k0, ws_);
        __syncthreads();
        mm256_16(as_, ws_, acc2);
        __syncthreads();
        stageW128(Wg1a, k0, ws_);
        __syncthreads();
        mm128_16(as_, ws_, acc1);
        __syncthreads();
    }
    int lane = threadIdx.x & 63, tn = threadIdx.x >> 6;
    float wb2[4], b2[4], wb1[2], b1[2];
#pragma unroll
    for (int j = 0; j < 4; j++) { wb2[j] = Wg2b[lane + j * 64]; b2[j] = bg2a[lane + j * 64]; }
#pragma unroll
    for (int j = 0; j < 2; j++) { wb1[j] = Wg1b[lane + j * 64]; b1[j] = bg1a[lane + j * 64]; }
    float c2 = bg2b[0], c1 = bg1b[0];
#pragma unroll
    for (int i = 0; i < 4; i++) {
        float s2 = 0.f;
#pragma unroll
        for (int j = 0; j < 4; j++) s2 += tanhf(acc2[i][j] + b2[j]) * wb2[j];
        s2 = wsum64(s2);
        float s1 = 0.f;
#pragma unroll
        for (int j = 0; j < 2; j++) s1 += tanhf(acc1[i][j] + b1[j]) * wb1[j];
        s1 = wsum64(s1);
        int n = nb + tn * 4 + i;
        if (lane == 0 && n < N_NODES) { gate2[n] = s2 + c2; gate1[n] = s1 + c1; }
    }
}

// per-group pooling, 4 blocks per group, partial sums via atomics
__global__ void k_group(const int* __restrict__ batch, const float* __restrict__ x2,
                        const float* __restrict__ xres, const float* __restrict__ g1,
                        const float* __restrict__ g2, float* __restrict__ gs1,
                        float* __restrict__ gs2, float* __restrict__ fin) {
    __shared__ float red[8];
    __shared__ int seb[2];
    int g = blockIdx.x >> 2, part = blockIdx.x & 3;
    int tid = threadIdx.x;
    if (tid == 0) {
        seb[0] = lowerb(batch, N_NODES, g);
        seb[1] = lowerb(batch, N_NODES, g + 1);
    }
    __syncthreads();
    int s = seb[0], e = seb[1];
    if (e <= s) return;
    float m1 = -3.4e38f, m2 = -3.4e38f;
    for (int i = s + tid; i < e; i += 256) {
        m1 = fmaxf(m1, g1[i]);
        m2 = fmaxf(m2, g2[i]);
    }
    m1 = blk_max(m1, red);
    m2 = blk_max(m2, red);
    int deg = e - s;
    int q0 = s + deg * part / 4, q1 = s + deg * (part + 1) / 4;
    float s1 = 0.f, s2 = 0.f, e1 = 0.f, e2 = 0.f, gr = 0.f;
    for (int i = q0; i < q1; i++) {
        float w1 = __expf(g1[i] - m1);
        float w2 = __expf(g2[i] - m2);
        float xv = x2[(size_t)i * H + tid];
        float rv = xres[(size_t)i * H + tid];
        s1 += w1; s2 += w2;
        e1 += w1 * xv; e2 += w2 * xv; gr += rv;
    }
    if (q1 > q0) {
        atomicAdd(&fin[(size_t)g * 768 + tid], e1);
        atomicAdd(&fin[(size_t)g * 768 + 256 + tid], e2);
        atomicAdd(&fin[(size_t)g * 768 + 512 + tid], gr);
        if (tid == 0) { atomicAdd(&gs1[g], s1); atomicAdd(&gs2[g], s2); }
    }
}

// out = gelu([emb1|emb2|gres] @ Wo + bo) / sqrt(1+1e-5) * bn_g + bn_b
__global__ void k_final(const int* __restrict__ batch, const float* __restrict__ fin,
                        const float* __restrict__ gs1, const float* __restrict__ gs2,
                        const float* __restrict__ Wo, const float* __restrict__ bo,
                        const float* __restrict__ bng, const float* __restrict__ bnb,
                        float* __restrict__ out) {
    __shared__ float fl[768];
    __shared__ int seb[2];
    int g = blockIdx.x, tid = threadIdx.x;
    if (tid == 0) {
        seb[0] = lowerb(batch, N_NODES, g);
        seb[1] = lowerb(batch, N_NODES, g + 1);
    }
    __syncthreads();
    float c = fmaxf((float)(seb[1] - seb[0]), 1.0f);
    float s1 = gs1[g], s2 = gs2[g];
    fl[tid]       = (s1 > 0.f) ? fin[(size_t)g * 768 + tid] / s1 : 0.f;
    fl[256 + tid] = (s2 > 0.f) ? fin[(size_t)g * 768 + 256 + tid] / s2 : 0.f;
    fl[512 + tid] = fin[(size_t)g * 768 + 512 + tid] / c;
    __syncthreads();
#pragma unroll
    for (int half = 0; half < 2; half++) {
        int o = tid + half * 256;
        float acc = bo[o];
#pragma unroll 8
        for (int k = 0; k < 768; k++) acc += fl[k] * Wo[(size_t)k * OUT_DIM + o];
        float val = gelu_f(acc);
        out[(size_t)g * OUT_DIM + o] = val * 0.9999950000374997f * bng[o] + bnb[o];
    }
}

extern "C" void kernel_launch(void* const* d_in, const int* in_sizes, int n_in,
                              void* d_out, int out_size, void* d_ws, size_t ws_size,
                              hipStream_t stream) {
    const float* x     = (const float*)d_in[0];
    const int*   ei    = (const int*)d_in[1];
    const int*   batch = (const int*)d_in[2];
    const float* ln_in_g = (const float*)d_in[3];
    const float* ln_in_b = (const float*)d_in[4];
    const float* Wp    = (const float*)d_in[5];
    const float* bp    = (const float*)d_in[6];
    const float* lnp_g = (const float*)d_in[7];
    const float* lnp_b = (const float*)d_in[8];
    const float* Wrel  = (const float*)d_in[9];
    const float* brel  = (const float*)d_in[10];
    const float* Wroot = (const float*)d_in[11];
    const float* n1_g  = (const float*)d_in[12];
    const float* n1_b  = (const float*)d_in[13];
    const float* Wl    = (const float*)d_in[14];
    const float* bl    = (const float*)d_in[15];
    const float* Wr    = (const float*)d_in[16];
    const float* br    = (const float*)d_in[17];
    const float* att   = (const float*)d_in[18];
    const float* gat_b = (const float*)d_in[19];
    const float* n2_g  = (const float*)d_in[20];
    const float* n2_b  = (const float*)d_in[21];
    const float* Wg1a  = (const float*)d_in[22];
    const float* bg1a  = (const float*)d_in[23];
    const float* Wg1b  = (const float*)d_in[24];
    const float* bg1b  = (const float*)d_in[25];
    const float* Wg2a  = (const float*)d_in[26];
    const float* bg2a  = (const float*)d_in[27];
    const float* Wg2b  = (const float*)d_in[28];
    const float* bg2b  = (const float*)d_in[29];
    const float* Wo    = (const float*)d_in[30];
    const float* bo    = (const float*)d_in[31];
    const float* bn_g  = (const float*)d_in[32];
    const float* bn_b  = (const float*)d_in[33];

    float* ws = (float*)d_ws;
    int* wsi = (int*)d_ws;
    const int* src = ei;
    const int* dst = ei + N_EDGES;
    int* cur = wsi + IOFF_CUR;
    int* row = wsi + IOFF_ROW;
    int* col = wsi + IOFF_COL;
    bf16* xlb   = (bf16*)(ws + OFF_XLB);
    bf16* xrb   = (bf16*)(ws + OFF_XRB);
    bf16* xresb = (bf16*)(ws + OFF_XRESB);
    const int GB = (N_NODES + 15) / 16;  // 625

    // ---- CSR build ----
    hipMemsetAsync(cur, 0, N_NODES * sizeof(int), stream);
    hipMemsetAsync(ws + OFF_GS1, 0, (128 + (size_t)NG * 768) * sizeof(float), stream);
    k_count<<<(N_EDGES + 255) / 256, 256, 0, stream>>>(dst, cur);
    k_scan<<<1, 1024, 0, stream>>>(cur, row);
    hipMemsetAsync(cur, 0, N_NODES * sizeof(int), stream);
    k_fill<<<(N_EDGES + 255) / 256, 256, 0, stream>>>(src, dst, row, cur, col);

    k_proj<<<GB, 256, 0, stream>>>(x, ln_in_g, ln_in_b, Wp, bp, lnp_g, lnp_b,
                                   ws + OFF_XRES, xresb);
    k_gather<<<N_NODES, 256, 0, stream>>>(row, col, xresb, ws + OFF_AGG);
    k_conv<<<GB, 256, 0, stream>>>(ws + OFF_AGG, ws + OFF_XRES, Wrel, brel, Wroot,
                                   n1_g, n1_b, ws + OFF_X1);
    k_lin2<<<GB, 256, 0, stream>>>(ws + OFF_X1, Wl, bl, Wr, br, xlb, xrb);
    k_gat<<<N_NODES, 256, 0, stream>>>(row, col, xlb, xrb, att, gat_b, n2_g, n2_b,
                                       ws + OFF_X1, ws + OFF_AGG);
    k_gates<<<GB, 256, 0, stream>>>(ws + OFF_AGG, Wg1a, bg1a, Wg1b, bg1b, Wg2a, bg2a,
                                    Wg2b, bg2b, ws + OFF_G1, ws + OFF_G2);
    k_group<<<NG * 4, 256, 0, stream>>>(batch, ws + OFF_AGG, ws + OFF_XRES,
                                        ws + OFF_G1, ws + OFF_G2, ws + OFF_GS1,
                                        ws + OFF_GS2, ws + OFF_FIN);
    k_final<<<NG, 256, 0, stream>>>(batch, ws + OFF_FIN, ws + OFF_GS1, ws + OFF_GS2,
                                    Wo, bo, bn_g, bn_b, (float*)d_out);
}

// Round 8
// 498.305 us; speedup vs baseline: 3.3185x; 1.2805x over previous
//
#include <hip/hip_runtime.h>
#include <hip/hip_bf16.h>

#define N_NODES 10000
#define N_EDGES 320000
#define DIN 512
#define H 256
#define NHEADS 4
#define DH 64
#define NG 64
#define OUT_DIM 512

typedef __hip_bfloat16 bf16;
typedef __attribute__((ext_vector_type(8))) short s8v;
typedef __attribute__((ext_vector_type(4))) float f4v;

// ---------- workspace layout (float offsets) ----------
static const size_t OFF_XRES  = 0;           // N*H fp32
static const size_t OFF_X1    = 2560000;     // N*H fp32
static const size_t OFF_XLB   = 5120000;     // N*H bf16
static const size_t OFF_XRB   = 6400000;     // N*H bf16
static const size_t OFF_XRESB = 7680000;     // N*H bf16
static const size_t OFF_AGGB  = 8960000;     // N*H bf16
static const size_t OFF_X1B   = 10240000;    // N*H bf16
static const size_t OFF_X2B   = 11520000;    // N*H bf16
static const size_t OFF_WPT   = 12800000;    // 512x256 bf16 (tiled)
static const size_t OFF_WRELT = 12865536;
static const size_t OFF_WROOTT= 12898304;
static const size_t OFF_WLT   = 12931072;
static const size_t OFF_WRT   = 12963840;
static const size_t OFF_WG2AT = 12996608;
static const size_t OFF_WG1AT = 13029376;    // 256x128 bf16 (tiled)
static const size_t OFF_G1    = 13045760;    // N
static const size_t OFF_G2    = 13055760;    // N
static const size_t OFF_GS1   = 13065760;    // 64
static const size_t OFF_GS2   = 13065824;    // 64
static const size_t OFF_FIN   = 13065888;    // G*768
// int offsets into (int*)ws
static const size_t IOFF_CUR  = 13120000;    // N
static const size_t IOFF_ROW  = 13130016;    // N+1
static const size_t IOFF_COL  = 13140032;    // E

__device__ __forceinline__ float gelu_f(float x) {
    return 0.5f * x * (1.0f + erff(x * 0.70710678118654752440f));
}
__device__ __forceinline__ short f2bf(float f) {
    union { float f; unsigned u; } v; v.f = f;
    unsigned r = v.u + 0x7fffu + ((v.u >> 16) & 1u);
    return (short)(r >> 16);
}
__device__ __forceinline__ float wsum64(float v) {
#pragma unroll
    for (int o = 32; o > 0; o >>= 1) v += __shfl_xor(v, o, 64);
    return v;
}
__device__ __forceinline__ float blk_sum(float v, float* s) {
#pragma unroll
    for (int o = 32; o > 0; o >>= 1) v += __shfl_xor(v, o, 64);
    int lane = threadIdx.x & 63, w = threadIdx.x >> 6;
    __syncthreads();
    if (lane == 0) s[w] = v;
    __syncthreads();
    float t = 0.f;
    int nw = blockDim.x >> 6;
    for (int i = 0; i < nw; i++) t += s[i];
    return t;
}
__device__ __forceinline__ float blk_max(float v, float* s) {
#pragma unroll
    for (int o = 32; o > 0; o >>= 1) v = fmaxf(v, __shfl_xor(v, o, 64));
    int lane = threadIdx.x & 63, w = threadIdx.x >> 6;
    __syncthreads();
    if (lane == 0) s[w] = v;
    __syncthreads();
    float t = s[0];
    int nw = blockDim.x >> 6;
    for (int i = 1; i < nw; i++) t = fmaxf(t, s[i]);
    return t;
}
__device__ __forceinline__ int lowerb(const int* b, int n, int v) {
    int lo = 0, hi = n;
    while (lo < hi) { int mid = (lo + hi) >> 1; if (b[mid] < v) lo = mid + 1; else hi = mid; }
    return lo;
}

// ---------- CSR build ----------
__global__ void k_count(const int* __restrict__ dst, int* __restrict__ deg) {
    int e = blockIdx.x * blockDim.x + threadIdx.x;
    if (e < N_EDGES) atomicAdd(&deg[dst[e]], 1);
}
__global__ void k_scan(const int* __restrict__ deg, int* __restrict__ row) {
    __shared__ int part[1024];
    int t = threadIdx.x;
    int base = t * 10;
    int v[10];
    int s = 0;
#pragma unroll
    for (int i = 0; i < 10; i++) {
        int idx = base + i;
        v[i] = (idx < N_NODES) ? deg[idx] : 0;
        s += v[i];
    }
    part[t] = s;
    __syncthreads();
    for (int off = 1; off < 1024; off <<= 1) {
        int x = (t >= off) ? part[t - off] : 0;
        __syncthreads();
        part[t] += x;
        __syncthreads();
    }
    int run = (t == 0) ? 0 : part[t - 1];
#pragma unroll
    for (int i = 0; i < 10; i++) {
        int idx = base + i;
        if (idx < N_NODES) row[idx] = run;
        run += v[i];
    }
    if (t == 1023) row[N_NODES] = part[1023];
}
__global__ void k_fill(const int* __restrict__ src, const int* __restrict__ dst,
                       const int* __restrict__ row, int* __restrict__ cur,
                       int* __restrict__ col) {
    int e = blockIdx.x * blockDim.x + threadIdx.x;
    if (e >= N_EDGES) return;
    int d = dst[e];
    int pos = atomicAdd(&cur[d], 1);
    col[row[d] + pos] = src[e];
}

// ---------- weight transpose+cast: W[K][N] fp32 -> Wt tiled [K/32][N][32] bf16 ----------
__global__ void k_twall(const float* Wp, const float* Wrel, const float* Wroot,
                        const float* Wl, const float* Wr, const float* Wg2a,
                        const float* Wg1a, short* WpT, short* WrelT, short* WrootT,
                        short* WlT, short* WrT, short* Wg2aT, short* Wg1aT) {
    const float* W; short* out; int K, N;
    switch (blockIdx.z) {
        case 0: W = Wp;   out = WpT;   K = 512; N = 256; break;
        case 1: W = Wrel; out = WrelT; K = 256; N = 256; break;
        case 2: W = Wroot;out = WrootT;K = 256; N = 256; break;
        case 3: W = Wl;   out = WlT;   K = 256; N = 256; break;
        case 4: W = Wr;   out = WrT;   K = 256; N = 256; break;
        case 5: W = Wg2a; out = Wg2aT; K = 256; N = 256; break;
        default:W = Wg1a; out = Wg1aT; K = 256; N = 128; break;
    }
    int c = blockIdx.x, nb = blockIdx.y * 64;
    if (c * 32 >= K || nb >= N) return;
    __shared__ float t[32][65];
    int tid = threadIdx.x;
    int col = tid & 63, kr = tid >> 6;
#pragma unroll
    for (int i = 0; i < 8; i++) {
        int kk = kr * 8 + i;
        t[kk][col] = W[(size_t)(c * 32 + kk) * N + nb + col];
    }
    __syncthreads();
#pragma unroll
    for (int i = 0; i < 8; i++) {
        int idx = tid + i * 256;
        int nn = idx >> 5, kk = idx & 31;
        out[(size_t)c * N * 32 + (size_t)(nb + nn) * 32 + kk] = f2bf(t[kk][nn]);
    }
}

// ---------- MFMA GEMM building blocks ----------
// block = 32 rows x 256 cols, 4 waves, each wave: 2 row-tiles x 4 col-tiles (16x16x32)
// LDS rows padded to 40 bf16.
__device__ __forceinline__ void stage_a(const short* __restrict__ A, int nb, int c,
                                        short* sA) {
    int t = threadIdx.x;
    if (t < 128) {
        int r = t >> 2, part = t & 3;
        int n = nb + r;
        s8v v = {};
        if (n < N_NODES) v = *(const s8v*)(A + (size_t)n * 256 + c * 32 + part * 8);
        *(s8v*)(sA + r * 40 + part * 8) = v;
    }
}
__device__ __forceinline__ void stage_wt(const short* __restrict__ Wt, int c, short* sW) {
    int t = threadIdx.x;
    const s8v* src = (const s8v*)(Wt + (size_t)c * 8192);
#pragma unroll
    for (int i = 0; i < 4; i++) {
        int u = t + i * 256;
        *(s8v*)(sW + (u >> 2) * 40 + (u & 3) * 8) = src[u];
    }
}
__device__ __forceinline__ void stage_wt128(const short* __restrict__ Wt, int c, short* sW) {
    int t = threadIdx.x;
    const s8v* src = (const s8v*)(Wt + (size_t)c * 4096);
#pragma unroll
    for (int i = 0; i < 2; i++) {
        int u = t + i * 256;
        *(s8v*)(sW + (u >> 2) * 40 + (u & 3) * 8) = src[u];
    }
}
__device__ __forceinline__ void mfma_step(const short* sA, const short* sW,
                                          f4v (&acc)[2][4]) {
    int lane = threadIdx.x & 63, wv = threadIdx.x >> 6;
    int m = lane & 15, quad = lane >> 4;
    s8v af0 = *(const s8v*)(sA + m * 40 + quad * 8);
    s8v af1 = *(const s8v*)(sA + (16 + m) * 40 + quad * 8);
#pragma unroll
    for (int ctl = 0; ctl < 4; ctl++) {
        s8v bf = *(const s8v*)(sW + (wv * 64 + ctl * 16 + m) * 40 + quad * 8);
        acc[0][ctl] = __builtin_amdgcn_mfma_f32_16x16x32_bf16(af0, bf, acc[0][ctl], 0, 0, 0);
        acc[1][ctl] = __builtin_amdgcn_mfma_f32_16x16x32_bf16(af1, bf, acc[1][ctl], 0, 0, 0);
    }
}
__device__ __forceinline__ void mfma_step128(const short* sA, const short* sW,
                                             f4v (&acc)[2][2]) {
    int lane = threadIdx.x & 63, wv = threadIdx.x >> 6;
    int m = lane & 15, quad = lane >> 4;
    s8v af0 = *(const s8v*)(sA + m * 40 + quad * 8);
    s8v af1 = *(const s8v*)(sA + (16 + m) * 40 + quad * 8);
#pragma unroll
    for (int ctl = 0; ctl < 2; ctl++) {
        s8v bf = *(const s8v*)(sW + (wv * 32 + ctl * 16 + m) * 40 + quad * 8);
        acc[0][ctl] = __builtin_amdgcn_mfma_f32_16x16x32_bf16(af0, bf, acc[0][ctl], 0, 0, 0);
        acc[1][ctl] = __builtin_amdgcn_mfma_f32_16x16x32_bf16(af1, bf, acc[1][ctl], 0, 0, 0);
    }
}
__device__ __forceinline__ void dump_c(const f4v (&acc)[2][4], float* C) {
    int lane = threadIdx.x & 63, wv = threadIdx.x >> 6;
    int m = lane & 15, quad = lane >> 4;
#pragma unroll
    for (int r = 0; r < 2; r++)
#pragma unroll
        for (int ctl = 0; ctl < 4; ctl++)
#pragma unroll
            for (int reg = 0; reg < 4; reg++)
                C[(r * 16 + quad * 4 + reg) * 264 + wv * 64 + ctl * 16 + m] = acc[r][ctl][reg];
}
__device__ __forceinline__ void dump_c128(const f4v (&acc)[2][2], float* C) {
    int lane = threadIdx.x & 63, wv = threadIdx.x >> 6;
    int m = lane & 15, quad = lane >> 4;
#pragma unroll
    for (int r = 0; r < 2; r++)
#pragma unroll
        for (int ctl = 0; ctl < 2; ctl++)
#pragma unroll
            for (int reg = 0; reg < 4; reg++)
                C[(r * 16 + quad * 4 + reg) * 136 + wv * 32 + ctl * 16 + m] = acc[r][ctl][reg];
}

// ---------- kernels ----------

// x_res = LN(gelu(LN_in(x) @ Wp + bp))
__global__ __launch_bounds__(256) void k_proj(
        const float* __restrict__ x, const float* __restrict__ g0,
        const float* __restrict__ b0, const short* __restrict__ WpT,
        const float* __restrict__ bp, const float* __restrict__ lg,
        const float* __restrict__ lb, float* __restrict__ xres,
        bf16* __restrict__ xresb) {
    __shared__ short sA[32 * 40];
    __shared__ float uC[32 * 264];      // union: sW (20 KB) overlays C (33 KB)
    short* sW = (short*)uC;
    __shared__ float sm_mean[32], sm_invs[32];
    __shared__ float red8[8];
    (void)red8;
    int nb = blockIdx.x * 32;
    int lane = threadIdx.x & 63, tn = threadIdx.x >> 6;
#pragma unroll
    for (int i = 0; i < 8; i++) {
        int r = tn * 8 + i;
        int n = nb + r;
        float s = 0.f, q = 0.f;
        if (n < N_NODES) {
#pragma unroll
            for (int j = 0; j < 8; j++) {
                float v = x[(size_t)n * DIN + lane + j * 64];
                s += v; q += v * v;
            }
        }
        s = wsum64(s); q = wsum64(q);
        float m = s * (1.0f / DIN);
        float var = q * (1.0f / DIN) - m * m;
        if (lane == 0) { sm_mean[r] = m; sm_invs[r] = rsqrtf(var + 1e-5f); }
    }
    __syncthreads();
    f4v acc[2][4] = {};
    for (int c = 0; c < 16; c++) {
        int t = threadIdx.x;
        if (t < 128) {
            int r = t >> 2, part = t & 3;
            int n = nb + r;
            short tmp[8];
            if (n < N_NODES) {
                int k = c * 32 + part * 8;
                float mm = sm_mean[r], is = sm_invs[r];
#pragma unroll
                for (int jj = 0; jj < 8; jj++) {
                    float v = (x[(size_t)n * DIN + k + jj] - mm) * is * g0[k + jj] + b0[k + jj];
                    tmp[jj] = f2bf(v);
                }
            } else {
#pragma unroll
                for (int jj = 0; jj < 8; jj++) tmp[jj] = 0;
            }
            *(s8v*)(sA + r * 40 + part * 8) = *(s8v*)tmp;
        }
        stage_wt(WpT, c, sW);
        __syncthreads();
        mfma_step(sA, sW, acc);
        __syncthreads();
    }
    dump_c(acc, uC);
    __syncthreads();
    float bp4[4], lg4[4], lb4[4];
#pragma unroll
    for (int j = 0; j < 4; j++) {
        bp4[j] = bp[lane + j * 64];
        lg4[j] = lg[lane + j * 64];
        lb4[j] = lb[lane + j * 64];
    }
#pragma unroll
    for (int i = 0; i < 8; i++) {
        int row = tn * 8 + i;
        float v[4];
#pragma unroll
        for (int j = 0; j < 4; j++) v[j] = gelu_f(uC[row * 264 + lane + j * 64] + bp4[j]);
        float m = wsum64(v[0] + v[1] + v[2] + v[3]) * (1.0f / H);
        float d[4], q = 0.f;
#pragma unroll
        for (int j = 0; j < 4; j++) { d[j] = v[j] - m; q += d[j] * d[j]; }
        float inv = rsqrtf(wsum64(q) * (1.0f / H) + 1e-5f);
        int n = nb + row;
        if (n < N_NODES) {
#pragma unroll
            for (int j = 0; j < 4; j++) {
                float r = d[j] * inv * lg4[j] + lb4[j];
                xres[(size_t)n * H + lane + j * 64] = r;
                xresb[(size_t)n * H + lane + j * 64] = __float2bfloat16(r);
            }
        }
    }
}

// aggb[n] = bf16( sum_{s in nbrs(n)} xresb[s] )
__global__ void k_gather(const int* __restrict__ row, const int* __restrict__ col,
                         const bf16* __restrict__ xresb, bf16* __restrict__ aggb) {
    int n = blockIdx.x, tid = threadIdx.x;
    int i = row[n], e0 = row[n + 1];
    float a = 0.f;
    for (; i + 7 < e0; i += 8) {
        int c0 = col[i], c1 = col[i + 1], c2 = col[i + 2], c3 = col[i + 3];
        int c4 = col[i + 4], c5 = col[i + 5], c6 = col[i + 6], c7 = col[i + 7];
        a += __bfloat162float(xresb[(size_t)c0 * H + tid])
           + __bfloat162float(xresb[(size_t)c1 * H + tid])
           + __bfloat162float(xresb[(size_t)c2 * H + tid])
           + __bfloat162float(xresb[(size_t)c3 * H + tid])
           + __bfloat162float(xresb[(size_t)c4 * H + tid])
           + __bfloat162float(xresb[(size_t)c5 * H + tid])
           + __bfloat162float(xresb[(size_t)c6 * H + tid])
           + __bfloat162float(xresb[(size_t)c7 * H + tid]);
    }
    for (; i < e0; i++) a += __bfloat162float(xresb[(size_t)col[i] * H + tid]);
    aggb[(size_t)n * H + tid] = __float2bfloat16(a);
}

// x1 = LN(gelu(agg@Wrel + xres@Wroot + brel)) + xres ; also x1b bf16
__global__ __launch_bounds__(256) void k_conv(
        const short* __restrict__ aggb, const short* __restrict__ xresbS,
        const float* __restrict__ xres, const short* __restrict__ WrelT,
        const short* __restrict__ WrootT, const float* __restrict__ brel,
        const float* __restrict__ n1g, const float* __restrict__ n1b,
        float* __restrict__ x1, bf16* __restrict__ x1b) {
    __shared__ short sA1[32 * 40];
    __shared__ short sA2[32 * 40];
    __shared__ float uC[32 * 264 + 2048];   // union: sW1+sW2 (40960 B) / C (33792 B)
    short* sW1 = (short*)uC;
    short* sW2 = sW1 + 10240;
    int nb = blockIdx.x * 32;
    int lane = threadIdx.x & 63, tn = threadIdx.x >> 6;
    f4v acc[2][4] = {};
    for (int c = 0; c < 8; c++) {
        stage_a(aggb, nb, c, sA1);
        stage_a(xresbS, nb, c, sA2);
        stage_wt(WrelT, c, sW1);
        stage_wt(WrootT, c, sW2);
        __syncthreads();
        mfma_step(sA1, sW1, acc);
        mfma_step(sA2, sW2, acc);
        __syncthreads();
    }
    dump_c(acc, uC);
    __syncthreads();
    float bb[4], gg[4], nb4[4];
#pragma unroll
    for (int j = 0; j < 4; j++) {
        bb[j] = brel[lane + j * 64];
        gg[j] = n1g[lane + j * 64];
        nb4[j] = n1b[lane + j * 64];
    }
#pragma unroll
    for (int i = 0; i < 8; i++) {
        int row = tn * 8 + i;
        float v[4];
#pragma unroll
        for (int j = 0; j < 4; j++) v[j] = gelu_f(uC[row * 264 + lane + j * 64] + bb[j]);
        float m = wsum64(v[0] + v[1] + v[2] + v[3]) * (1.0f / H);
        float d[4], q = 0.f;
#pragma unroll
        for (int j = 0; j < 4; j++) { d[j] = v[j] - m; q += d[j] * d[j]; }
        float inv = rsqrtf(wsum64(q) * (1.0f / H) + 1e-5f);
        int n = nb + row;
        if (n < N_NODES) {
#pragma unroll
            for (int j = 0; j < 4; j++) {
                size_t idx = (size_t)n * H + lane + j * 64;
                float r = d[j] * inv * gg[j] + nb4[j] + xres[idx];
                x1[idx] = r;
                x1b[idx] = __float2bfloat16(r);
            }
        }
    }
}

// xl = x1@Wl + bl ; xr = x1@Wr + br  (bf16 outs, direct frag stores)
__global__ __launch_bounds__(256) void k_lin2(
        const short* __restrict__ x1b, const short* __restrict__ WlT,
        const short* __restrict__ WrT, const float* __restrict__ bl,
        const float* __restrict__ br, bf16* __restrict__ xlb,
        bf16* __restrict__ xrb) {
    __shared__ short sA[32 * 40];
    __shared__ short sW1[256 * 40];
    __shared__ short sW2[256 * 40];
    int nb = blockIdx.x * 32;
    f4v accL[2][4] = {};
    f4v accR[2][4] = {};
    for (int c = 0; c < 8; c++) {
        stage_a(x1b, nb, c, sA);
        stage_wt(WlT, c, sW1);
        stage_wt(WrT, c, sW2);
        __syncthreads();
        mfma_step(sA, sW1, accL);
        mfma_step(sA, sW2, accR);
        __syncthreads();
    }
    int lane = threadIdx.x & 63, wv = threadIdx.x >> 6;
    int m = lane & 15, quad = lane >> 4;
#pragma unroll
    for (int ctl = 0; ctl < 4; ctl++) {
        int colx = wv * 64 + ctl * 16 + m;
        float blv = bl[colx], brv = br[colx];
#pragma unroll
        for (int r = 0; r < 2; r++)
#pragma unroll
            for (int reg = 0; reg < 4; reg++) {
                int n = nb + r * 16 + quad * 4 + reg;
                if (n < N_NODES) {
                    xlb[(size_t)n * H + colx] = __float2bfloat16(accL[r][ctl][reg] + blv);
                    xrb[(size_t)n * H + colx] = __float2bfloat16(accR[r][ctl][reg] + brv);
                }
            }
    }
}

// fused GATv2 + x2 epilogue (unchanged math; writes bf16 x2b)
__global__ __launch_bounds__(256, 6) void k_gat(
        const int* __restrict__ row, const int* __restrict__ col,
        const bf16* __restrict__ xl, const bf16* __restrict__ xr,
        const float* __restrict__ att, const float* __restrict__ gatb,
        const float* __restrict__ n2g, const float* __restrict__ n2b,
        const float* __restrict__ x1, bf16* __restrict__ x2b) {
    __shared__ float slog[NHEADS * 128];
    __shared__ float red[8];
    int n = blockIdx.x;
    int tid = threadIdx.x;
    int h = tid >> 6, lane = tid & 63;
    int dc = lane & 3;
    float xr16[16], att16[16];
    {
        const bf16* xrrow = xr + (size_t)n * H + h * DH + dc * 16;
        const float* attrow = att + h * DH + dc * 16;
#pragma unroll
        for (int j = 0; j < 16; j++) {
            xr16[j] = __bfloat162float(xrrow[j]);
            att16[j] = attrow[j];
        }
    }
    int rs = row[n];
    int ec = row[n + 1] - rs + 1;
    float m = -3.4e38f, l = 0.f, acc = 0.f;
    float* myslog = slog + h * 128;
    for (int c0 = 0; c0 < ec; c0 += 128) {
        int cnt = min(128, ec - c0);
        for (int base = 0; base < cnt; base += 16) {
            int ei = base + (lane >> 2);
            bool valid = ei < cnt;
            int g = c0 + ei;
            int s = (valid && g > 0) ? col[rs + g - 1] : n;
            const unsigned* xlr = (const unsigned*)(xl + (size_t)s * H + h * DH + dc * 16);
            float p = 0.f;
#pragma unroll
            for (int jj = 0; jj < 8; jj++) {
                unsigned u = xlr[jj];
                float v0 = __uint_as_float((u & 0xffffu) << 16);
                float v1 = __uint_as_float(u & 0xffff0000u);
                float a0 = v0 + xr16[2 * jj];
                float a1 = v1 + xr16[2 * jj + 1];
                a0 = (a0 > 0.f) ? a0 : 0.2f * a0;
                a1 = (a1 > 0.f) ? a1 : 0.2f * a1;
                p += a0 * att16[2 * jj] + a1 * att16[2 * jj + 1];
            }
            p += __shfl_xor(p, 1, 64);
            p += __shfl_xor(p, 2, 64);
            if (valid && dc == 0) myslog[ei] = p;
        }
        float cm = -3.4e38f;
        for (int i = lane; i < cnt; i += 64) cm = fmaxf(cm, myslog[i]);
#pragma unroll
        for (int o = 32; o > 0; o >>= 1) cm = fmaxf(cm, __shfl_xor(cm, o, 64));
        float nm = fmaxf(m, cm);
        float sc = __expf(m - nm);
        l *= sc; acc *= sc; m = nm;
        for (int i = 0; i < cnt; i += 4) {
#pragma unroll
            for (int k = 0; k < 4; k++) {
                int gi = i + k;
                if (gi < cnt) {
                    float a = __expf(myslog[gi] - m);
                    int g = c0 + gi;
                    int s = (g > 0) ? col[rs + g - 1] : n;
                    float w = __bfloat162float(xl[(size_t)s * H + h * DH + lane]);
                    l += a;
                    acc += a * w;
                }
            }
        }
    }
    float msg = acc / l;
    int off = tid;
    float p = gelu_f(msg + gatb[off]);
    float sm = blk_sum(p, red) * (1.0f / H);
    float dd = p - sm;
    float vv = blk_sum(dd * dd, red) * (1.0f / H);
    float inv = rsqrtf(vv + 1e-5f);
    float r = dd * inv * n2g[off] + n2b[off] + x1[(size_t)n * H + off];
    x2b[(size_t)n * H + off] = __float2bfloat16(r);
}

// gates via MFMA
__global__ __launch_bounds__(256) void k_gates(
        const short* __restrict__ x2b, const short* __restrict__ Wg2aT,
        const short* __restrict__ Wg1aT, const float* __restrict__ bg2a,
        const float* __restrict__ Wg2b, const float* __restrict__ bg2b,
        const float* __restrict__ bg1a, const float* __restrict__ Wg1b,
        const float* __restrict__ bg1b, float* __restrict__ gate1,
        float* __restrict__ gate2) {
    __shared__ short sA[32 * 40];
    __shared__ float u[12800];   // union: sW2g(20480B)+sW1g(10240B) / C2(33792B)+C1(17408B)
    short* sW2g = (short*)u;
    short* sW1g = sW2g + 10240;
    float* C2 = u;
    float* C1 = u + 8448;
    int nb = blockIdx.x * 32;
    int lane = threadIdx.x & 63, tn = threadIdx.x >> 6;
    f4v acc2[2][4] = {};
    f4v acc1[2][2] = {};
    for (int c = 0; c < 8; c++) {
        stage_a(x2b, nb, c, sA);
        stage_wt(Wg2aT, c, sW2g);
        stage_wt128(Wg1aT, c, sW1g);
        __syncthreads();
        mfma_step(sA, sW2g, acc2);
        mfma_step128(sA, sW1g, acc1);
        __syncthreads();
    }
    dump_c(acc2, C2);
    dump_c128(acc1, C1);
    __syncthreads();
    float wb2[4], b2[4], wb1[2], b1[2];
#pragma unroll
    for (int j = 0; j < 4; j++) { wb2[j] = Wg2b[lane + j * 64]; b2[j] = bg2a[lane + j * 64]; }
#pragma unroll
    for (int j = 0; j < 2; j++) { wb1[j] = Wg1b[lane + j * 64]; b1[j] = bg1a[lane + j * 64]; }
    float c2c = bg2b[0], c1c = bg1b[0];
#pragma unroll
    for (int i = 0; i < 8; i++) {
        int rowi = tn * 8 + i;
        float s2 = 0.f;
#pragma unroll
        for (int j = 0; j < 4; j++) s2 += tanhf(C2[rowi * 264 + lane + j * 64] + b2[j]) * wb2[j];
        s2 = wsum64(s2);
        float s1 = 0.f;
#pragma unroll
        for (int j = 0; j < 2; j++) s1 += tanhf(C1[rowi * 136 + lane + j * 64] + b1[j]) * wb1[j];
        s1 = wsum64(s1);
        int n = nb + rowi;
        if (lane == 0 && n < N_NODES) { gate2[n] = s2 + c2c; gate1[n] = s1 + c1c; }
    }
}

// per-group pooling (x2 read as bf16)
__global__ void k_group(const int* __restrict__ batch, const bf16* __restrict__ x2b,
                        const float* __restrict__ xres, const float* __restrict__ g1,
                        const float* __restrict__ g2, float* __restrict__ gs1,
                        float* __restrict__ gs2, float* __restrict__ fin) {
    __shared__ float red[8];
    __shared__ int seb[2];
    int g = blockIdx.x >> 2, part = blockIdx.x & 3;
    int tid = threadIdx.x;
    if (tid == 0) {
        seb[0] = lowerb(batch, N_NODES, g);
        seb[1] = lowerb(batch, N_NODES, g + 1);
    }
    __syncthreads();
    int s = seb[0], e = seb[1];
    if (e <= s) return;
    float m1 = -3.4e38f, m2 = -3.4e38f;
    for (int i = s + tid; i < e; i += 256) {
        m1 = fmaxf(m1, g1[i]);
        m2 = fmaxf(m2, g2[i]);
    }
    m1 = blk_max(m1, red);
    m2 = blk_max(m2, red);
    int deg = e - s;
    int q0 = s + deg * part / 4, q1 = s + deg * (part + 1) / 4;
    float s1 = 0.f, s2 = 0.f, e1 = 0.f, e2 = 0.f, gr = 0.f;
    for (int i = q0; i < q1; i++) {
        float w1 = __expf(g1[i] - m1);
        float w2 = __expf(g2[i] - m2);
        float xv = __bfloat162float(x2b[(size_t)i * H + tid]);
        float rv = xres[(size_t)i * H + tid];
        s1 += w1; s2 += w2;
        e1 += w1 * xv; e2 += w2 * xv; gr += rv;
    }
    if (q1 > q0) {
        atomicAdd(&fin[(size_t)g * 768 + tid], e1);
        atomicAdd(&fin[(size_t)g * 768 + 256 + tid], e2);
        atomicAdd(&fin[(size_t)g * 768 + 512 + tid], gr);
        if (tid == 0) { atomicAdd(&gs1[g], s1); atomicAdd(&gs2[g], s2); }
    }
}

// out = gelu([emb1|emb2|gres] @ Wo + bo) / sqrt(1+1e-5) * bn_g + bn_b  (fp32)
__global__ void k_final(const int* __restrict__ batch, const float* __restrict__ fin,
                        const float* __restrict__ gs1, const float* __restrict__ gs2,
                        const float* __restrict__ Wo, const float* __restrict__ bo,
                        const float* __restrict__ bng, const float* __restrict__ bnb,
                        float* __restrict__ out) {
    __shared__ float fl[768];
    __shared__ int seb[2];
    int g = blockIdx.x, tid = threadIdx.x;
    if (tid == 0) {
        seb[0] = lowerb(batch, N_NODES, g);
        seb[1] = lowerb(batch, N_NODES, g + 1);
    }
    __syncthreads();
    float c = fmaxf((float)(seb[1] - seb[0]), 1.0f);
    float s1 = gs1[g], s2 = gs2[g];
    fl[tid]       = (s1 > 0.f) ? fin[(size_t)g * 768 + tid] / s1 : 0.f;
    fl[256 + tid] = (s2 > 0.f) ? fin[(size_t)g * 768 + 256 + tid] / s2 : 0.f;
    fl[512 + tid] = fin[(size_t)g * 768 + 512 + tid] / c;
    __syncthreads();
#pragma unroll
    for (int half = 0; half < 2; half++) {
        int o = tid + half * 256;
        float acc = bo[o];
#pragma unroll 8
        for (int k = 0; k < 768; k++) acc += fl[k] * Wo[(size_t)k * OUT_DIM + o];
        float val = gelu_f(acc);
        out[(size_t)g * OUT_DIM + o] = val * 0.9999950000374997f * bng[o] + bnb[o];
    }
}

extern "C" void kernel_launch(void* const* d_in, const int* in_sizes, int n_in,
                              void* d_out, int out_size, void* d_ws, size_t ws_size,
                              hipStream_t stream) {
    const float* x     = (const float*)d_in[0];
    const int*   ei    = (const int*)d_in[1];
    const int*   batch = (const int*)d_in[2];
    const float* ln_in_g = (const float*)d_in[3];
    const float* ln_in_b = (const float*)d_in[4];
    const float* Wp    = (const float*)d_in[5];
    const float* bp    = (const float*)d_in[6];
    const float* lnp_g = (const float*)d_in[7];
    const float* lnp_b = (const float*)d_in[8];
    const float* Wrel  = (const float*)d_in[9];
    const float* brel  = (const float*)d_in[10];
    const float* Wroot = (const float*)d_in[11];
    const float* n1_g  = (const float*)d_in[12];
    const float* n1_b  = (const float*)d_in[13];
    const float* Wl    = (const float*)d_in[14];
    const float* bl    = (const float*)d_in[15];
    const float* Wr    = (const float*)d_in[16];
    const float* br    = (const float*)d_in[17];
    const float* att   = (const float*)d_in[18];
    const float* gat_b = (const float*)d_in[19];
    const float* n2_g  = (const float*)d_in[20];
    const float* n2_b  = (const float*)d_in[21];
    const float* Wg1a  = (const float*)d_in[22];
    const float* bg1a  = (const float*)d_in[23];
    const float* Wg1b  = (const float*)d_in[24];
    const float* bg1b  = (const float*)d_in[25];
    const float* Wg2a  = (const float*)d_in[26];
    const float* bg2a  = (const float*)d_in[27];
    const float* Wg2b  = (const float*)d_in[28];
    const float* bg2b  = (const float*)d_in[29];
    const float* Wo    = (const float*)d_in[30];
    const float* bo    = (const float*)d_in[31];
    const float* bn_g  = (const float*)d_in[32];
    const float* bn_b  = (const float*)d_in[33];

    float* ws = (float*)d_ws;
    int* wsi = (int*)d_ws;
    const int* src = ei;
    const int* dst = ei + N_EDGES;
    int* cur = wsi + IOFF_CUR;
    int* row = wsi + IOFF_ROW;
    int* col = wsi + IOFF_COL;
    short* WpT    = (short*)(ws + OFF_WPT);
    short* WrelT  = (short*)(ws + OFF_WRELT);
    short* WrootT = (short*)(ws + OFF_WROOTT);
    short* WlT    = (short*)(ws + OFF_WLT);
    short* WrT    = (short*)(ws + OFF_WRT);
    short* Wg2aT  = (short*)(ws + OFF_WG2AT);
    short* Wg1aT  = (short*)(ws + OFF_WG1AT);
    bf16* xlb   = (bf16*)(ws + OFF_XLB);
    bf16* xrb   = (bf16*)(ws + OFF_XRB);
    bf16* xresb = (bf16*)(ws + OFF_XRESB);
    bf16* aggb  = (bf16*)(ws + OFF_AGGB);
    bf16* x1b   = (bf16*)(ws + OFF_X1B);
    bf16* x2b   = (bf16*)(ws + OFF_X2B);
    const int GB32 = (N_NODES + 31) / 32;  // 313

    hipMemsetAsync(cur, 0, N_NODES * sizeof(int), stream);
    hipMemsetAsync(ws + OFF_GS1, 0, (128 + (size_t)NG * 768) * sizeof(float), stream);
    k_count<<<(N_EDGES + 255) / 256, 256, 0, stream>>>(dst, cur);
    k_scan<<<1, 1024, 0, stream>>>(cur, row);
    hipMemsetAsync(cur, 0, N_NODES * sizeof(int), stream);
    k_fill<<<(N_EDGES + 255) / 256, 256, 0, stream>>>(src, dst, row, cur, col);

    k_twall<<<dim3(16, 4, 7), 256, 0, stream>>>(Wp, Wrel, Wroot, Wl, Wr, Wg2a, Wg1a,
                                                WpT, WrelT, WrootT, WlT, WrT, Wg2aT,
                                                Wg1aT);
    k_proj<<<GB32, 256, 0, stream>>>(x, ln_in_g, ln_in_b, WpT, bp, lnp_g, lnp_b,
                                     ws + OFF_XRES, xresb);
    k_gather<<<N_NODES, 256, 0, stream>>>(row, col, xresb, aggb);
    k_conv<<<GB32, 256, 0, stream>>>((const short*)aggb, (const short*)xresb,
                                     ws + OFF_XRES, WrelT, WrootT, brel, n1_g, n1_b,
                                     ws + OFF_X1, x1b);
    k_lin2<<<GB32, 256, 0, stream>>>((const short*)x1b, WlT, WrT, bl, br, xlb, xrb);
    k_gat<<<N_NODES, 256, 0, stream>>>(row, col, xlb, xrb, att, gat_b, n2_g, n2_b,
                                       ws + OFF_X1, x2b);
    k_gates<<<GB32, 256, 0, stream>>>((const short*)x2b, Wg2aT, Wg1aT, bg2a, Wg2b,
                                      bg2b, bg1a, Wg1b, bg1b, ws + OFF_G1, ws + OFF_G2);
    k_group<<<NG * 4, 256, 0, stream>>>(batch, x2b, ws + OFF_XRES, ws + OFF_G1,
                                        ws + OFF_G2, ws + OFF_GS1, ws + OFF_GS2,
                                        ws + OFF_FIN);
    k_final<<<NG, 256, 0, stream>>>(batch, ws + OFF_FIN, ws + OFF_GS1, ws + OFF_GS2,
                                    Wo, bo, bn_g, bn_b, (float*)d_out);
}

// Round 9
// 423.730 us; speedup vs baseline: 3.9026x; 1.1760x over previous
//
#include <hip/hip_runtime.h>
#include <hip/hip_bf16.h>

#define N_NODES 10000
#define N_EDGES 320000
#define DIN 512
#define H 256
#define NHEADS 4
#define DH 64
#define NG 64
#define OUT_DIM 512

typedef __hip_bfloat16 bf16;
typedef __attribute__((ext_vector_type(8))) short s8v;
typedef __attribute__((ext_vector_type(4))) float f4v;

// ---------- workspace layout (float offsets) ----------
static const size_t OFF_XRES  = 0;           // N*H fp32
static const size_t OFF_X1    = 2560000;     // N*H fp32
static const size_t OFF_XLB   = 5120000;     // N*H bf16
static const size_t OFF_XRB   = 6400000;     // N*H bf16
static const size_t OFF_XRESB = 7680000;     // N*H bf16
static const size_t OFF_AGGB  = 8960000;     // N*H bf16
static const size_t OFF_X1B   = 10240000;    // N*H bf16
static const size_t OFF_X2B   = 11520000;    // N*H bf16
static const size_t OFF_WPT   = 12800000;    // 512x256 bf16 (tiled)
static const size_t OFF_WRELT = 12865536;
static const size_t OFF_WROOTT= 12898304;
static const size_t OFF_WLT   = 12931072;
static const size_t OFF_WRT   = 12963840;
static const size_t OFF_WG2AT = 12996608;
static const size_t OFF_WG1AT = 13029376;    // 256x128 bf16 (tiled)
static const size_t OFF_G1    = 13045760;    // N
static const size_t OFF_G2    = 13055760;    // N
static const size_t OFF_GS1   = 13065760;    // 64
static const size_t OFF_GS2   = 13065824;    // 64
static const size_t OFF_FIN   = 13065888;    // G*768
// int offsets into (int*)ws
static const size_t IOFF_CUR  = 13120000;    // N
static const size_t IOFF_ROW  = 13130016;    // N+1
static const size_t IOFF_COL  = 13140032;    // E

__device__ __forceinline__ float gelu_f(float x) {
    return 0.5f * x * (1.0f + erff(x * 0.70710678118654752440f));
}
__device__ __forceinline__ short f2bf(float f) {
    union { float f; unsigned u; } v; v.f = f;
    unsigned r = v.u + 0x7fffu + ((v.u >> 16) & 1u);
    return (short)(r >> 16);
}
__device__ __forceinline__ float wsum64(float v) {
#pragma unroll
    for (int o = 32; o > 0; o >>= 1) v += __shfl_xor(v, o, 64);
    return v;
}
__device__ __forceinline__ float blk_sum(float v, float* s) {
#pragma unroll
    for (int o = 32; o > 0; o >>= 1) v += __shfl_xor(v, o, 64);
    int lane = threadIdx.x & 63, w = threadIdx.x >> 6;
    __syncthreads();
    if (lane == 0) s[w] = v;
    __syncthreads();
    float t = 0.f;
    int nw = blockDim.x >> 6;
    for (int i = 0; i < nw; i++) t += s[i];
    return t;
}
__device__ __forceinline__ float blk_max(float v, float* s) {
#pragma unroll
    for (int o = 32; o > 0; o >>= 1) v = fmaxf(v, __shfl_xor(v, o, 64));
    int lane = threadIdx.x & 63, w = threadIdx.x >> 6;
    __syncthreads();
    if (lane == 0) s[w] = v;
    __syncthreads();
    float t = s[0];
    int nw = blockDim.x >> 6;
    for (int i = 1; i < nw; i++) t = fmaxf(t, s[i]);
    return t;
}
__device__ __forceinline__ int lowerb(const int* b, int n, int v) {
    int lo = 0, hi = n;
    while (lo < hi) { int mid = (lo + hi) >> 1; if (b[mid] < v) lo = mid + 1; else hi = mid; }
    return lo;
}

// ---------- CSR build ----------
__global__ void k_count(const int* __restrict__ dst, int* __restrict__ deg) {
    int e = blockIdx.x * blockDim.x + threadIdx.x;
    if (e < N_EDGES) atomicAdd(&deg[dst[e]], 1);
}
__global__ void k_scan(const int* __restrict__ deg, int* __restrict__ row) {
    __shared__ int part[1024];
    int t = threadIdx.x;
    int base = t * 10;
    int v[10];
    int s = 0;
#pragma unroll
    for (int i = 0; i < 10; i++) {
        int idx = base + i;
        v[i] = (idx < N_NODES) ? deg[idx] : 0;
        s += v[i];
    }
    part[t] = s;
    __syncthreads();
    for (int off = 1; off < 1024; off <<= 1) {
        int x = (t >= off) ? part[t - off] : 0;
        __syncthreads();
        part[t] += x;
        __syncthreads();
    }
    int run = (t == 0) ? 0 : part[t - 1];
#pragma unroll
    for (int i = 0; i < 10; i++) {
        int idx = base + i;
        if (idx < N_NODES) row[idx] = run;
        run += v[i];
    }
    if (t == 1023) row[N_NODES] = part[1023];
}
__global__ void k_fill(const int* __restrict__ src, const int* __restrict__ dst,
                       const int* __restrict__ row, int* __restrict__ cur,
                       int* __restrict__ col) {
    int e = blockIdx.x * blockDim.x + threadIdx.x;
    if (e >= N_EDGES) return;
    int d = dst[e];
    int pos = atomicAdd(&cur[d], 1);
    col[row[d] + pos] = src[e];
}

// ---------- weight transpose+cast: W[K][N] fp32 -> Wt tiled [K/32][N][32] bf16 ----------
__global__ void k_twall(const float* Wp, const float* Wrel, const float* Wroot,
                        const float* Wl, const float* Wr, const float* Wg2a,
                        const float* Wg1a, short* WpT, short* WrelT, short* WrootT,
                        short* WlT, short* WrT, short* Wg2aT, short* Wg1aT) {
    const float* W; short* out; int K, N;
    switch (blockIdx.z) {
        case 0: W = Wp;   out = WpT;   K = 512; N = 256; break;
        case 1: W = Wrel; out = WrelT; K = 256; N = 256; break;
        case 2: W = Wroot;out = WrootT;K = 256; N = 256; break;
        case 3: W = Wl;   out = WlT;   K = 256; N = 256; break;
        case 4: W = Wr;   out = WrT;   K = 256; N = 256; break;
        case 5: W = Wg2a; out = Wg2aT; K = 256; N = 256; break;
        default:W = Wg1a; out = Wg1aT; K = 256; N = 128; break;
    }
    int c = blockIdx.x, nb = blockIdx.y * 64;
    if (c * 32 >= K || nb >= N) return;
    __shared__ float t[32][65];
    int tid = threadIdx.x;
    int col = tid & 63, kr = tid >> 6;
#pragma unroll
    for (int i = 0; i < 8; i++) {
        int kk = kr * 8 + i;
        t[kk][col] = W[(size_t)(c * 32 + kk) * N + nb + col];
    }
    __syncthreads();
#pragma unroll
    for (int i = 0; i < 8; i++) {
        int idx = tid + i * 256;
        int nn = idx >> 5, kk = idx & 31;
        out[(size_t)c * N * 32 + (size_t)(nb + nn) * 32 + kk] = f2bf(t[kk][nn]);
    }
}

// ---------- MFMA GEMM building blocks ----------
__device__ __forceinline__ void stage_a(const short* __restrict__ A, int nb, int c,
                                        short* sA) {
    int t = threadIdx.x;
    if (t < 128) {
        int r = t >> 2, part = t & 3;
        int n = nb + r;
        s8v v = {};
        if (n < N_NODES) v = *(const s8v*)(A + (size_t)n * 256 + c * 32 + part * 8);
        *(s8v*)(sA + r * 40 + part * 8) = v;
    }
}
__device__ __forceinline__ void stage_wt(const short* __restrict__ Wt, int c, short* sW) {
    int t = threadIdx.x;
    const s8v* src = (const s8v*)(Wt + (size_t)c * 8192);
#pragma unroll
    for (int i = 0; i < 4; i++) {
        int u = t + i * 256;
        *(s8v*)(sW + (u >> 2) * 40 + (u & 3) * 8) = src[u];
    }
}
__device__ __forceinline__ void stage_wt128(const short* __restrict__ Wt, int c, short* sW) {
    int t = threadIdx.x;
    const s8v* src = (const s8v*)(Wt + (size_t)c * 4096);
#pragma unroll
    for (int i = 0; i < 2; i++) {
        int u = t + i * 256;
        *(s8v*)(sW + (u >> 2) * 40 + (u & 3) * 8) = src[u];
    }
}
__device__ __forceinline__ void mfma_step(const short* sA, const short* sW,
                                          f4v (&acc)[2][4]) {
    int lane = threadIdx.x & 63, wv = threadIdx.x >> 6;
    int m = lane & 15, quad = lane >> 4;
    s8v af0 = *(const s8v*)(sA + m * 40 + quad * 8);
    s8v af1 = *(const s8v*)(sA + (16 + m) * 40 + quad * 8);
#pragma unroll
    for (int ctl = 0; ctl < 4; ctl++) {
        s8v bf = *(const s8v*)(sW + (wv * 64 + ctl * 16 + m) * 40 + quad * 8);
        acc[0][ctl] = __builtin_amdgcn_mfma_f32_16x16x32_bf16(af0, bf, acc[0][ctl], 0, 0, 0);
        acc[1][ctl] = __builtin_amdgcn_mfma_f32_16x16x32_bf16(af1, bf, acc[1][ctl], 0, 0, 0);
    }
}
__device__ __forceinline__ void mfma_step128(const short* sA, const short* sW,
                                             f4v (&acc)[2][2]) {
    int lane = threadIdx.x & 63, wv = threadIdx.x >> 6;
    int m = lane & 15, quad = lane >> 4;
    s8v af0 = *(const s8v*)(sA + m * 40 + quad * 8);
    s8v af1 = *(const s8v*)(sA + (16 + m) * 40 + quad * 8);
#pragma unroll
    for (int ctl = 0; ctl < 2; ctl++) {
        s8v bf = *(const s8v*)(sW + (wv * 32 + ctl * 16 + m) * 40 + quad * 8);
        acc[0][ctl] = __builtin_amdgcn_mfma_f32_16x16x32_bf16(af0, bf, acc[0][ctl], 0, 0, 0);
        acc[1][ctl] = __builtin_amdgcn_mfma_f32_16x16x32_bf16(af1, bf, acc[1][ctl], 0, 0, 0);
    }
}
__device__ __forceinline__ void dump_c(const f4v (&acc)[2][4], float* C) {
    int lane = threadIdx.x & 63, wv = threadIdx.x >> 6;
    int m = lane & 15, quad = lane >> 4;
#pragma unroll
    for (int r = 0; r < 2; r++)
#pragma unroll
        for (int ctl = 0; ctl < 4; ctl++)
#pragma unroll
            for (int reg = 0; reg < 4; reg++)
                C[(r * 16 + quad * 4 + reg) * 264 + wv * 64 + ctl * 16 + m] = acc[r][ctl][reg];
}
__device__ __forceinline__ void dump_c128(const f4v (&acc)[2][2], float* C) {
    int lane = threadIdx.x & 63, wv = threadIdx.x >> 6;
    int m = lane & 15, quad = lane >> 4;
#pragma unroll
    for (int r = 0; r < 2; r++)
#pragma unroll
        for (int ctl = 0; ctl < 2; ctl++)
#pragma unroll
            for (int reg = 0; reg < 4; reg++)
                C[(r * 16 + quad * 4 + reg) * 136 + wv * 32 + ctl * 16 + m] = acc[r][ctl][reg];
}

// ---------- kernels ----------

// x_res = LN(gelu(LN_in(x) @ Wp + bp))
__global__ __launch_bounds__(256) void k_proj(
        const float* __restrict__ x, const float* __restrict__ g0,
        const float* __restrict__ b0, const short* __restrict__ WpT,
        const float* __restrict__ bp, const float* __restrict__ lg,
        const float* __restrict__ lb, float* __restrict__ xres,
        bf16* __restrict__ xresb) {
    __shared__ short sA[32 * 40];
    __shared__ float uC[32 * 264];      // union: sW (20 KB) overlays C (33 KB)
    short* sW = (short*)uC;
    __shared__ float sm_mean[32], sm_invs[32];
    int nb = blockIdx.x * 32;
    int lane = threadIdx.x & 63, tn = threadIdx.x >> 6;
#pragma unroll
    for (int i = 0; i < 8; i++) {
        int r = tn * 8 + i;
        int n = nb + r;
        float s = 0.f, q = 0.f;
        if (n < N_NODES) {
#pragma unroll
            for (int j = 0; j < 8; j++) {
                float v = x[(size_t)n * DIN + lane + j * 64];
                s += v; q += v * v;
            }
        }
        s = wsum64(s); q = wsum64(q);
        float m = s * (1.0f / DIN);
        float var = q * (1.0f / DIN) - m * m;
        if (lane == 0) { sm_mean[r] = m; sm_invs[r] = rsqrtf(var + 1e-5f); }
    }
    __syncthreads();
    f4v acc[2][4] = {};
    for (int c = 0; c < 16; c++) {
        int t = threadIdx.x;
        if (t < 128) {
            int r = t >> 2, part = t & 3;
            int n = nb + r;
            short tmp[8];
            if (n < N_NODES) {
                int k = c * 32 + part * 8;
                float mm = sm_mean[r], is = sm_invs[r];
#pragma unroll
                for (int jj = 0; jj < 8; jj++) {
                    float v = (x[(size_t)n * DIN + k + jj] - mm) * is * g0[k + jj] + b0[k + jj];
                    tmp[jj] = f2bf(v);
                }
            } else {
#pragma unroll
                for (int jj = 0; jj < 8; jj++) tmp[jj] = 0;
            }
            *(s8v*)(sA + r * 40 + part * 8) = *(s8v*)tmp;
        }
        stage_wt(WpT, c, sW);
        __syncthreads();
        mfma_step(sA, sW, acc);
        __syncthreads();
    }
    dump_c(acc, uC);
    __syncthreads();
    float bp4[4], lg4[4], lb4[4];
#pragma unroll
    for (int j = 0; j < 4; j++) {
        bp4[j] = bp[lane + j * 64];
        lg4[j] = lg[lane + j * 64];
        lb4[j] = lb[lane + j * 64];
    }
#pragma unroll
    for (int i = 0; i < 8; i++) {
        int row = tn * 8 + i;
        float v[4];
#pragma unroll
        for (int j = 0; j < 4; j++) v[j] = gelu_f(uC[row * 264 + lane + j * 64] + bp4[j]);
        float m = wsum64(v[0] + v[1] + v[2] + v[3]) * (1.0f / H);
        float d[4], q = 0.f;
#pragma unroll
        for (int j = 0; j < 4; j++) { d[j] = v[j] - m; q += d[j] * d[j]; }
        float inv = rsqrtf(wsum64(q) * (1.0f / H) + 1e-5f);
        int n = nb + row;
        if (n < N_NODES) {
#pragma unroll
            for (int j = 0; j < 4; j++) {
                float r = d[j] * inv * lg4[j] + lb4[j];
                xres[(size_t)n * H + lane + j * 64] = r;
                xresb[(size_t)n * H + lane + j * 64] = __float2bfloat16(r);
            }
        }
    }
}

// aggb[n] = bf16( sum_{s in nbrs(n)} xresb[s] )
__global__ void k_gather(const int* __restrict__ row, const int* __restrict__ col,
                         const bf16* __restrict__ xresb, bf16* __restrict__ aggb) {
    int n = blockIdx.x, tid = threadIdx.x;
    int i = row[n], e0 = row[n + 1];
    float a = 0.f;
    for (; i + 7 < e0; i += 8) {
        int c0 = col[i], c1 = col[i + 1], c2 = col[i + 2], c3 = col[i + 3];
        int c4 = col[i + 4], c5 = col[i + 5], c6 = col[i + 6], c7 = col[i + 7];
        a += __bfloat162float(xresb[(size_t)c0 * H + tid])
           + __bfloat162float(xresb[(size_t)c1 * H + tid])
           + __bfloat162float(xresb[(size_t)c2 * H + tid])
           + __bfloat162float(xresb[(size_t)c3 * H + tid])
           + __bfloat162float(xresb[(size_t)c4 * H + tid])
           + __bfloat162float(xresb[(size_t)c5 * H + tid])
           + __bfloat162float(xresb[(size_t)c6 * H + tid])
           + __bfloat162float(xresb[(size_t)c7 * H + tid]);
    }
    for (; i < e0; i++) a += __bfloat162float(xresb[(size_t)col[i] * H + tid]);
    aggb[(size_t)n * H + tid] = __float2bfloat16(a);
}

// x1 = LN(gelu(agg@Wrel + xres@Wroot + brel)) + xres ; also x1b bf16
__global__ __launch_bounds__(256) void k_conv(
        const short* __restrict__ aggb, const short* __restrict__ xresbS,
        const float* __restrict__ xres, const short* __restrict__ WrelT,
        const short* __restrict__ WrootT, const float* __restrict__ brel,
        const float* __restrict__ n1g, const float* __restrict__ n1b,
        float* __restrict__ x1, bf16* __restrict__ x1b) {
    __shared__ short sA1[32 * 40];
    __shared__ short sA2[32 * 40];
    __shared__ float uC[32 * 264 + 2048];   // union: sW1+sW2 / C
    short* sW1 = (short*)uC;
    short* sW2 = sW1 + 10240;
    int nb = blockIdx.x * 32;
    int lane = threadIdx.x & 63, tn = threadIdx.x >> 6;
    f4v acc[2][4] = {};
    for (int c = 0; c < 8; c++) {
        stage_a(aggb, nb, c, sA1);
        stage_a(xresbS, nb, c, sA2);
        stage_wt(WrelT, c, sW1);
        stage_wt(WrootT, c, sW2);
        __syncthreads();
        mfma_step(sA1, sW1, acc);
        mfma_step(sA2, sW2, acc);
        __syncthreads();
    }
    dump_c(acc, uC);
    __syncthreads();
    float bb[4], gg[4], nb4[4];
#pragma unroll
    for (int j = 0; j < 4; j++) {
        bb[j] = brel[lane + j * 64];
        gg[j] = n1g[lane + j * 64];
        nb4[j] = n1b[lane + j * 64];
    }
#pragma unroll
    for (int i = 0; i < 8; i++) {
        int row = tn * 8 + i;
        float v[4];
#pragma unroll
        for (int j = 0; j < 4; j++) v[j] = gelu_f(uC[row * 264 + lane + j * 64] + bb[j]);
        float m = wsum64(v[0] + v[1] + v[2] + v[3]) * (1.0f / H);
        float d[4], q = 0.f;
#pragma unroll
        for (int j = 0; j < 4; j++) { d[j] = v[j] - m; q += d[j] * d[j]; }
        float inv = rsqrtf(wsum64(q) * (1.0f / H) + 1e-5f);
        int n = nb + row;
        if (n < N_NODES) {
#pragma unroll
            for (int j = 0; j < 4; j++) {
                size_t idx = (size_t)n * H + lane + j * 64;
                float r = d[j] * inv * gg[j] + nb4[j] + xres[idx];
                x1[idx] = r;
                x1b[idx] = __float2bfloat16(r);
            }
        }
    }
}

// xl = x1@Wl + bl ; xr = x1@Wr + br  (bf16 outs, direct frag stores)
__global__ __launch_bounds__(256) void k_lin2(
        const short* __restrict__ x1b, const short* __restrict__ WlT,
        const short* __restrict__ WrT, const float* __restrict__ bl,
        const float* __restrict__ br, bf16* __restrict__ xlb,
        bf16* __restrict__ xrb) {
    __shared__ short sA[32 * 40];
    __shared__ short sW1[256 * 40];
    __shared__ short sW2[256 * 40];
    int nb = blockIdx.x * 32;
    f4v accL[2][4] = {};
    f4v accR[2][4] = {};
    for (int c = 0; c < 8; c++) {
        stage_a(x1b, nb, c, sA);
        stage_wt(WlT, c, sW1);
        stage_wt(WrT, c, sW2);
        __syncthreads();
        mfma_step(sA, sW1, accL);
        mfma_step(sA, sW2, accR);
        __syncthreads();
    }
    int lane = threadIdx.x & 63, wv = threadIdx.x >> 6;
    int m = lane & 15, quad = lane >> 4;
#pragma unroll
    for (int ctl = 0; ctl < 4; ctl++) {
        int colx = wv * 64 + ctl * 16 + m;
        float blv = bl[colx], brv = br[colx];
#pragma unroll
        for (int r = 0; r < 2; r++)
#pragma unroll
            for (int reg = 0; reg < 4; reg++) {
                int n = nb + r * 16 + quad * 4 + reg;
                if (n < N_NODES) {
                    xlb[(size_t)n * H + colx] = __float2bfloat16(accL[r][ctl][reg] + blv);
                    xrb[(size_t)n * H + colx] = __float2bfloat16(accR[r][ctl][reg] + brv);
                }
            }
    }
}

// fused GATv2 + x2 epilogue
__global__ __launch_bounds__(256, 8) void k_gat(
        const int* __restrict__ row, const int* __restrict__ col,
        const bf16* __restrict__ xl, const bf16* __restrict__ xr,
        const float* __restrict__ att, const float* __restrict__ gatb,
        const float* __restrict__ n2g, const float* __restrict__ n2b,
        const float* __restrict__ x1, bf16* __restrict__ x2b) {
    __shared__ float slog[NHEADS * 128];
    __shared__ float red[8];
    int n = blockIdx.x;
    int tid = threadIdx.x;
    int h = tid >> 6, lane = tid & 63;
    int dc = lane & 3;
    float xr16[16], att16[16];
    {
        const bf16* xrrow = xr + (size_t)n * H + h * DH + dc * 16;
        const float* attrow = att + h * DH + dc * 16;
#pragma unroll
        for (int j = 0; j < 16; j++) {
            xr16[j] = __bfloat162float(xrrow[j]);
            att16[j] = attrow[j];
        }
    }
    int rs = row[n];
    int ec = row[n + 1] - rs + 1;
    float m = -3.4e38f, l = 0.f, acc = 0.f;
    float* myslog = slog + h * 128;
    for (int c0 = 0; c0 < ec; c0 += 128) {
        int cnt = min(128, ec - c0);
        for (int base = 0; base < cnt; base += 16) {
            int ei = base + (lane >> 2);
            bool valid = ei < cnt;
            int g = c0 + ei;
            int s = (valid && g > 0) ? col[rs + g - 1] : n;
            const unsigned* xlr = (const unsigned*)(xl + (size_t)s * H + h * DH + dc * 16);
            float p = 0.f;
#pragma unroll
            for (int jj = 0; jj < 8; jj++) {
                unsigned u = xlr[jj];
                float v0 = __uint_as_float((u & 0xffffu) << 16);
                float v1 = __uint_as_float(u & 0xffff0000u);
                float a0 = v0 + xr16[2 * jj];
                float a1 = v1 + xr16[2 * jj + 1];
                a0 = (a0 > 0.f) ? a0 : 0.2f * a0;
                a1 = (a1 > 0.f) ? a1 : 0.2f * a1;
                p += a0 * att16[2 * jj] + a1 * att16[2 * jj + 1];
            }
            p += __shfl_xor(p, 1, 64);
            p += __shfl_xor(p, 2, 64);
            if (valid && dc == 0) myslog[ei] = p;
        }
        float cm = -3.4e38f;
        for (int i = lane; i < cnt; i += 64) cm = fmaxf(cm, myslog[i]);
#pragma unroll
        for (int o = 32; o > 0; o >>= 1) cm = fmaxf(cm, __shfl_xor(cm, o, 64));
        float nm = fmaxf(m, cm);
        float sc = __expf(m - nm);
        l *= sc; acc *= sc; m = nm;
        for (int i = 0; i < cnt; i += 4) {
#pragma unroll
            for (int k = 0; k < 4; k++) {
                int gi = i + k;
                if (gi < cnt) {
                    float a = __expf(myslog[gi] - m);
                    int g = c0 + gi;
                    int s = (g > 0) ? col[rs + g - 1] : n;
                    float w = __bfloat162float(xl[(size_t)s * H + h * DH + lane]);
                    l += a;
                    acc += a * w;
                }
            }
        }
    }
    float msg = acc / l;
    int off = tid;
    float p = gelu_f(msg + gatb[off]);
    float sm = blk_sum(p, red) * (1.0f / H);
    float dd = p - sm;
    float vv = blk_sum(dd * dd, red) * (1.0f / H);
    float inv = rsqrtf(vv + 1e-5f);
    float r = dd * inv * n2g[off] + n2b[off] + x1[(size_t)n * H + off];
    x2b[(size_t)n * H + off] = __float2bfloat16(r);
}

// gates via MFMA
__global__ __launch_bounds__(256) void k_gates(
        const short* __restrict__ x2b, const short* __restrict__ Wg2aT,
        const short* __restrict__ Wg1aT, const float* __restrict__ bg2a,
        const float* __restrict__ Wg2b, const float* __restrict__ bg2b,
        const float* __restrict__ bg1a, const float* __restrict__ Wg1b,
        const float* __restrict__ bg1b, float* __restrict__ gate1,
        float* __restrict__ gate2) {
    __shared__ short sA[32 * 40];
    __shared__ float u[12800];
    short* sW2g = (short*)u;
    short* sW1g = sW2g + 10240;
    float* C2 = u;
    float* C1 = u + 8448;
    int nb = blockIdx.x * 32;
    int lane = threadIdx.x & 63, tn = threadIdx.x >> 6;
    f4v acc2[2][4] = {};
    f4v acc1[2][2] = {};
    for (int c = 0; c < 8; c++) {
        stage_a(x2b, nb, c, sA);
        stage_wt(Wg2aT, c, sW2g);
        stage_wt128(Wg1aT, c, sW1g);
        __syncthreads();
        mfma_step(sA, sW2g, acc2);
        mfma_step128(sA, sW1g, acc1);
        __syncthreads();
    }
    dump_c(acc2, C2);
    dump_c128(acc1, C1);
    __syncthreads();
    float wb2[4], b2[4], wb1[2], b1[2];
#pragma unroll
    for (int j = 0; j < 4; j++) { wb2[j] = Wg2b[lane + j * 64]; b2[j] = bg2a[lane + j * 64]; }
#pragma unroll
    for (int j = 0; j < 2; j++) { wb1[j] = Wg1b[lane + j * 64]; b1[j] = bg1a[lane + j * 64]; }
    float c2c = bg2b[0], c1c = bg1b[0];
#pragma unroll
    for (int i = 0; i < 8; i++) {
        int rowi = tn * 8 + i;
        float s2 = 0.f;
#pragma unroll
        for (int j = 0; j < 4; j++) s2 += tanhf(C2[rowi * 264 + lane + j * 64] + b2[j]) * wb2[j];
        s2 = wsum64(s2);
        float s1 = 0.f;
#pragma unroll
        for (int j = 0; j < 2; j++) s1 += tanhf(C1[rowi * 136 + lane + j * 64] + b1[j]) * wb1[j];
        s1 = wsum64(s1);
        int n = nb + rowi;
        if (lane == 0 && n < N_NODES) { gate2[n] = s2 + c2c; gate1[n] = s1 + c1c; }
    }
}

// per-group pooling (x2 read as bf16)
__global__ void k_group(const int* __restrict__ batch, const bf16* __restrict__ x2b,
                        const float* __restrict__ xres, const float* __restrict__ g1,
                        const float* __restrict__ g2, float* __restrict__ gs1,
                        float* __restrict__ gs2, float* __restrict__ fin) {
    __shared__ float red[8];
    __shared__ int seb[2];
    int g = blockIdx.x >> 2, part = blockIdx.x & 3;
    int tid = threadIdx.x;
    if (tid == 0) {
        seb[0] = lowerb(batch, N_NODES, g);
        seb[1] = lowerb(batch, N_NODES, g + 1);
    }
    __syncthreads();
    int s = seb[0], e = seb[1];
    if (e <= s) return;
    float m1 = -3.4e38f, m2 = -3.4e38f;
    for (int i = s + tid; i < e; i += 256) {
        m1 = fmaxf(m1, g1[i]);
        m2 = fmaxf(m2, g2[i]);
    }
    m1 = blk_max(m1, red);
    m2 = blk_max(m2, red);
    int deg = e - s;
    int q0 = s + deg * part / 4, q1 = s + deg * (part + 1) / 4;
    float s1 = 0.f, s2 = 0.f, e1 = 0.f, e2 = 0.f, gr = 0.f;
    for (int i = q0; i < q1; i++) {
        float w1 = __expf(g1[i] - m1);
        float w2 = __expf(g2[i] - m2);
        float xv = __bfloat162float(x2b[(size_t)i * H + tid]);
        float rv = xres[(size_t)i * H + tid];
        s1 += w1; s2 += w2;
        e1 += w1 * xv; e2 += w2 * xv; gr += rv;
    }
    if (q1 > q0) {
        atomicAdd(&fin[(size_t)g * 768 + tid], e1);
        atomicAdd(&fin[(size_t)g * 768 + 256 + tid], e2);
        atomicAdd(&fin[(size_t)g * 768 + 512 + tid], gr);
        if (tid == 0) { atomicAdd(&gs1[g], s1); atomicAdd(&gs2[g], s2); }
    }
}

// out = gelu([emb1|emb2|gres] @ Wo + bo) * bn  — grid (NG, 8); lane=column,
// 4 waves split K=768 into 192-chunks, LDS-reduce.
__global__ __launch_bounds__(256) void k_final(
        const int* __restrict__ batch, const float* __restrict__ fin,
        const float* __restrict__ gs1, const float* __restrict__ gs2,
        const float* __restrict__ Wo, const float* __restrict__ bo,
        const float* __restrict__ bng, const float* __restrict__ bnb,
        float* __restrict__ out) {
    __shared__ float fl[768];
    __shared__ float part[4][64];
    __shared__ int seb[2];
    int g = blockIdx.x, oc = blockIdx.y;
    int tid = threadIdx.x, lane = tid & 63, wv = tid >> 6;
    if (tid == 0) {
        seb[0] = lowerb(batch, N_NODES, g);
        seb[1] = lowerb(batch, N_NODES, g + 1);
    }
    __syncthreads();
    float c = fmaxf((float)(seb[1] - seb[0]), 1.0f);
    float s1 = gs1[g], s2 = gs2[g];
    fl[tid]       = (s1 > 0.f) ? fin[(size_t)g * 768 + tid] / s1 : 0.f;
    fl[256 + tid] = (s2 > 0.f) ? fin[(size_t)g * 768 + 256 + tid] / s2 : 0.f;
    fl[512 + tid] = fin[(size_t)g * 768 + 512 + tid] / c;
    __syncthreads();
    int o = oc * 64 + lane;
    float acc = 0.f;
    int k0 = wv * 192;
    for (int k = k0; k < k0 + 192; k += 8) {
#pragma unroll
        for (int j = 0; j < 8; j++)
            acc += fl[k + j] * Wo[(size_t)(k + j) * OUT_DIM + o];
    }
    part[wv][lane] = acc;
    __syncthreads();
    if (wv == 0) {
        float t = part[0][lane] + part[1][lane] + part[2][lane] + part[3][lane] + bo[o];
        float val = gelu_f(t);
        out[(size_t)g * OUT_DIM + o] = val * 0.9999950000374997f * bng[o] + bnb[o];
    }
}

extern "C" void kernel_launch(void* const* d_in, const int* in_sizes, int n_in,
                              void* d_out, int out_size, void* d_ws, size_t ws_size,
                              hipStream_t stream) {
    const float* x     = (const float*)d_in[0];
    const int*   ei    = (const int*)d_in[1];
    const int*   batch = (const int*)d_in[2];
    const float* ln_in_g = (const float*)d_in[3];
    const float* ln_in_b = (const float*)d_in[4];
    const float* Wp    = (const float*)d_in[5];
    const float* bp    = (const float*)d_in[6];
    const float* lnp_g = (const float*)d_in[7];
    const float* lnp_b = (const float*)d_in[8];
    const float* Wrel  = (const float*)d_in[9];
    const float* brel  = (const float*)d_in[10];
    const float* Wroot = (const float*)d_in[11];
    const float* n1_g  = (const float*)d_in[12];
    const float* n1_b  = (const float*)d_in[13];
    const float* Wl    = (const float*)d_in[14];
    const float* bl    = (const float*)d_in[15];
    const float* Wr    = (const float*)d_in[16];
    const float* br    = (const float*)d_in[17];
    const float* att   = (const float*)d_in[18];
    const float* gat_b = (const float*)d_in[19];
    const float* n2_g  = (const float*)d_in[20];
    const float* n2_b  = (const float*)d_in[21];
    const float* Wg1a  = (const float*)d_in[22];
    const float* bg1a  = (const float*)d_in[23];
    const float* Wg1b  = (const float*)d_in[24];
    const float* bg1b  = (const float*)d_in[25];
    const float* Wg2a  = (const float*)d_in[26];
    const float* bg2a  = (const float*)d_in[27];
    const float* Wg2b  = (const float*)d_in[28];
    const float* bg2b  = (const float*)d_in[29];
    const float* Wo    = (const float*)d_in[30];
    const float* bo    = (const float*)d_in[31];
    const float* bn_g  = (const float*)d_in[32];
    const float* bn_b  = (const float*)d_in[33];

    float* ws = (float*)d_ws;
    int* wsi = (int*)d_ws;
    const int* src = ei;
    const int* dst = ei + N_EDGES;
    int* cur = wsi + IOFF_CUR;
    int* row = wsi + IOFF_ROW;
    int* col = wsi + IOFF_COL;
    short* WpT    = (short*)(ws + OFF_WPT);
    short* WrelT  = (short*)(ws + OFF_WRELT);
    short* WrootT = (short*)(ws + OFF_WROOTT);
    short* WlT    = (short*)(ws + OFF_WLT);
    short* WrT    = (short*)(ws + OFF_WRT);
    short* Wg2aT  = (short*)(ws + OFF_WG2AT);
    short* Wg1aT  = (short*)(ws + OFF_WG1AT);
    bf16* xlb   = (bf16*)(ws + OFF_XLB);
    bf16* xrb   = (bf16*)(ws + OFF_XRB);
    bf16* xresb = (bf16*)(ws + OFF_XRESB);
    bf16* aggb  = (bf16*)(ws + OFF_AGGB);
    bf16* x1b   = (bf16*)(ws + OFF_X1B);
    bf16* x2b   = (bf16*)(ws + OFF_X2B);
    const int GB32 = (N_NODES + 31) / 32;  // 313

    hipMemsetAsync(cur, 0, N_NODES * sizeof(int), stream);
    hipMemsetAsync(ws + OFF_GS1, 0, (128 + (size_t)NG * 768) * sizeof(float), stream);
    k_count<<<(N_EDGES + 255) / 256, 256, 0, stream>>>(dst, cur);
    k_scan<<<1, 1024, 0, stream>>>(cur, row);
    hipMemsetAsync(cur, 0, N_NODES * sizeof(int), stream);
    k_fill<<<(N_EDGES + 255) / 256, 256, 0, stream>>>(src, dst, row, cur, col);

    k_twall<<<dim3(16, 4, 7), 256, 0, stream>>>(Wp, Wrel, Wroot, Wl, Wr, Wg2a, Wg1a,
                                                WpT, WrelT, WrootT, WlT, WrT, Wg2aT,
                                                Wg1aT);
    k_proj<<<GB32, 256, 0, stream>>>(x, ln_in_g, ln_in_b, WpT, bp, lnp_g, lnp_b,
                                     ws + OFF_XRES, xresb);
    k_gather<<<N_NODES, 256, 0, stream>>>(row, col, xresb, aggb);
    k_conv<<<GB32, 256, 0, stream>>>((const short*)aggb, (const short*)xresb,
                                     ws + OFF_XRES, WrelT, WrootT, brel, n1_g, n1_b,
                                     ws + OFF_X1, x1b);
    k_lin2<<<GB32, 256, 0, stream>>>((const short*)x1b, WlT, WrT, bl, br, xlb, xrb);
    k_gat<<<N_NODES, 256, 0, stream>>>(row, col, xlb, xrb, att, gat_b, n2_g, n2_b,
                                       ws + OFF_X1, x2b);
    k_gates<<<GB32, 256, 0, stream>>>((const short*)x2b, Wg2aT, Wg1aT, bg2a, Wg2b,
                                      bg2b, bg1a, Wg1b, bg1b, ws + OFF_G1, ws + OFF_G2);
    k_group<<<NG * 4, 256, 0, stream>>>(batch, x2b, ws + OFF_XRES, ws + OFF_G1,
                                        ws + OFF_G2, ws + OFF_GS1, ws + OFF_GS2,
                                        ws + OFF_FIN);
    k_final<<<dim3(NG, 8), 256, 0, stream>>>(batch, ws + OFF_FIN, ws + OFF_GS1,
                                             ws + OFF_GS2, Wo, bo, bn_g, bn_b,
                                             (float*)d_out);
}